// Round 1
// baseline (837.209 us; speedup 1.0000x reference)
//
#include <hip/hip_runtime.h>
#include <hip/hip_bf16.h>

#define FT 128
#define NH 8
#define TE 32

__device__ __forceinline__ unsigned enc_f32(float f) {
  unsigned u = __float_as_uint(f);
  return (u & 0x80000000u) ? ~u : (u | 0x80000000u);
}
__device__ __forceinline__ float dec_f32(unsigned u) {
  unsigned v = (u & 0x80000000u) ? (u & 0x7FFFFFFFu) : ~u;
  return __uint_as_float(v);
}
__device__ __forceinline__ ushort f2bf(float f) {
  __hip_bfloat16 h = __float2bfloat16(f);
  return *reinterpret_cast<ushort*>(&h);
}

// ---------------- K1: zero [agg | s | m_enc] ----------------
__global__ void k_zero(float* __restrict__ p, size_t n) {
  size_t i = (size_t)blockIdx.x * blockDim.x + threadIdx.x;
  if (i < n) p[i] = 0.0f;
}

// ---------------- K2: per-edge GEMM + logits + segment-max ----------------
// block = 256 threads, TE=32 edges per block.
// thread t: cg = t&31 (cols cg*4..+3), eg = t>>5 (edges eg*4..+3)
__global__ __launch_bounds__(256) void k_edge(
    const float* __restrict__ nft, const float* __restrict__ eft,
    const float* __restrict__ Wp, const float* __restrict__ bp,
    const float* __restrict__ Wa1, const float* __restrict__ at2,
    const int* __restrict__ src, const int* __restrict__ dst,
    ushort* __restrict__ ep, float* __restrict__ aout,
    unsigned* __restrict__ menc, int E)
{
  __shared__ float x[TE][384];      // [hs | eft | hd]  48 KB
  __shared__ float a2s[TE][NH];     // per-(edge,head) a2 partials

  const int t  = threadIdx.x;
  const int e0 = blockIdx.x * TE;

  // ---- stage: 8 threads per edge, each loads 4 float4 per segment ----
  {
    int ei = t >> 3, l8 = t & 7;
    int e = e0 + ei;
    if (e < E) {
      int se = src[e], de = dst[e];
      const float* hs = nft + (size_t)se * FT;
      const float* ef = eft + (size_t)e  * FT;
      const float* hd = nft + (size_t)de * FT;
      #pragma unroll
      for (int j = 0; j < 4; ++j) {
        int c = (l8 + 8 * j) * 4;
        *(float4*)&x[ei][c]       = *(const float4*)&hs[c];
        *(float4*)&x[ei][128 + c] = *(const float4*)&ef[c];
        *(float4*)&x[ei][256 + c] = *(const float4*)&hd[c];
      }
    } else {
      float4 z = make_float4(0.f, 0.f, 0.f, 0.f);
      #pragma unroll
      for (int j = 0; j < 4; ++j) {
        int c = (l8 + 8 * j) * 4;
        *(float4*)&x[ei][c]       = z;
        *(float4*)&x[ei][128 + c] = z;
        *(float4*)&x[ei][256 + c] = z;
      }
    }
  }
  ((float*)a2s)[t] = 0.0f;   // TE*NH == 256
  __syncthreads();

  const int cg = t & 31;
  const int eg = t >> 5;
  const float* wp = Wp + cg * 4;

  float acc[4][4];
  #pragma unroll
  for (int i = 0; i < 4; ++i)
    #pragma unroll
    for (int j = 0; j < 4; ++j) acc[i][j] = 0.0f;

  for (int k = 0; k < 384; k += 4) {
    float4 w0 = *(const float4*)&wp[(size_t)(k + 0) * FT];
    float4 w1 = *(const float4*)&wp[(size_t)(k + 1) * FT];
    float4 w2 = *(const float4*)&wp[(size_t)(k + 2) * FT];
    float4 w3 = *(const float4*)&wp[(size_t)(k + 3) * FT];
    #pragma unroll
    for (int i = 0; i < 4; ++i) {
      float4 xv = *(const float4*)&x[eg * 4 + i][k];
      acc[i][0] = fmaf(xv.x, w0.x, fmaf(xv.y, w1.x, fmaf(xv.z, w2.x, fmaf(xv.w, w3.x, acc[i][0]))));
      acc[i][1] = fmaf(xv.x, w0.y, fmaf(xv.y, w1.y, fmaf(xv.z, w2.y, fmaf(xv.w, w3.y, acc[i][1]))));
      acc[i][2] = fmaf(xv.x, w0.z, fmaf(xv.y, w1.z, fmaf(xv.z, w2.z, fmaf(xv.w, w3.z, acc[i][2]))));
      acc[i][3] = fmaf(xv.x, w0.w, fmaf(xv.y, w1.w, fmaf(xv.z, w2.w, fmaf(xv.w, w3.w, acc[i][3]))));
    }
  }

  // ---- bias, store epaths (bf16), a2 partials ----
  float4 bpv = *(const float4*)&bp[cg * 4];
  float4 a2v = *(const float4*)&at2[cg * 4];
  int h = cg >> 2;
  #pragma unroll
  for (int i = 0; i < 4; ++i) {
    int e = e0 + eg * 4 + i;
    float p0 = acc[i][0] + bpv.x;
    float p1 = acc[i][1] + bpv.y;
    float p2 = acc[i][2] + bpv.z;
    float p3 = acc[i][3] + bpv.w;
    float partial = p0 * a2v.x + p1 * a2v.y + p2 * a2v.z + p3 * a2v.w;
    if (e < E) {
      ushort4 pk;
      pk.x = f2bf(p0); pk.y = f2bf(p1); pk.z = f2bf(p2); pk.w = f2bf(p3);
      *(ushort4*)&ep[(size_t)e * FT + cg * 4] = pk;
      atomicAdd(&a2s[eg * 4 + i][h], partial);
    }
  }
  __syncthreads();

  // ---- a1 + finalize logits, segment-max via encoded uint atomicMax ----
  {
    int ei = t >> 3, hh = t & 7;
    int e = e0 + ei;
    if (e < E) {
      float a1 = 0.0f;
      for (int k = 0; k < FT; ++k) a1 = fmaf(x[ei][k], Wa1[k * NH + hh], a1);
      float av = a1 + a2s[ei][hh];
      float lv = av > 0.0f ? av : 0.01f * av;
      aout[(size_t)e * NH + hh] = lv;
      atomicMax(&menc[(size_t)dst[e] * NH + hh], enc_f32(lv));
    }
  }
}

// ---------------- K3: decode segment-max ----------------
__global__ void k_decode(unsigned* __restrict__ m, int n) {
  int i = blockIdx.x * 256 + threadIdx.x;
  if (i < n) {
    float f = dec_f32(m[i]);
    if (!isfinite(f)) f = 0.0f;
    ((float*)m)[i] = f;
  }
}

// ---------------- K4: exp + weighted scatter (unnormalized) ----------------
// one wave per edge; lane l handles cols 2l, 2l+1
__global__ __launch_bounds__(256) void k_scatter(
    const ushort* __restrict__ ep, const float* __restrict__ aout,
    const float* __restrict__ m, const int* __restrict__ dst,
    float* __restrict__ s, float* __restrict__ agg, int E)
{
  int gid = blockIdx.x * 256 + threadIdx.x;
  int e = gid >> 6;
  int l = gid & 63;
  if (e >= E) return;
  int d = dst[e];
  int h = l >> 3;
  float av = aout[(size_t)e * NH + h];
  float mv = m[(size_t)d * NH + h];
  float ev = expf(av - mv);
  unsigned pk = *(const unsigned*)&ep[(size_t)e * FT + l * 2];
  float p0 = __uint_as_float(pk << 16);
  float p1 = __uint_as_float(pk & 0xFFFF0000u);
  atomicAdd(&agg[(size_t)d * FT + l * 2],     ev * p0);
  atomicAdd(&agg[(size_t)d * FT + l * 2 + 1], ev * p1);
  if ((l & 7) == 0) atomicAdd(&s[(size_t)d * NH + h], ev);
}

// ---------------- K5: out = relu(agg/s + nft) ----------------
__global__ void k_final(const float* __restrict__ agg, const float* __restrict__ s,
                        const float* __restrict__ nft, float* __restrict__ out, int total) {
  int i = blockIdx.x * 256 + threadIdx.x;
  if (i >= total) return;
  int n = i >> 7, c = i & 127, h = c >> 4;
  float sv = s[(size_t)n * NH + h];
  float v = sv > 0.0f ? agg[i] / sv : 0.0f;
  v += nft[i];
  out[i] = v > 0.0f ? v : 0.0f;
}

extern "C" void kernel_launch(void* const* d_in, const int* in_sizes, int n_in,
                              void* d_out, int out_size, void* d_ws, size_t ws_size,
                              hipStream_t stream) {
  const float* nft = (const float*)d_in[0];
  const float* eft = (const float*)d_in[1];
  const float* Wp  = (const float*)d_in[2];
  const float* bp  = (const float*)d_in[3];
  const float* Wa1 = (const float*)d_in[4];
  const float* at2 = (const float*)d_in[5];
  const int*   src = (const int*)d_in[6];
  const int*   dst = (const int*)d_in[7];
  const int N = in_sizes[0] / FT;
  const int E = in_sizes[6];

  char* ws = (char*)d_ws;
  size_t off = 0;
  ushort* ep = (ushort*)(ws + off);   off += (size_t)E * FT * sizeof(ushort);
  off = (off + 255) & ~(size_t)255;
  float* aout = (float*)(ws + off);   off += (size_t)E * NH * sizeof(float);
  off = (off + 255) & ~(size_t)255;
  // agg | s | m_enc contiguous so one zero kernel covers all
  float* agg = (float*)(ws + off);    off += (size_t)N * FT * sizeof(float);
  float* sden = (float*)(ws + off);   off += (size_t)N * NH * sizeof(float);
  unsigned* menc = (unsigned*)(ws + off); off += (size_t)N * NH * sizeof(float);

  size_t zn = (size_t)N * (FT + 2 * NH);
  k_zero<<<(int)((zn + 255) / 256), 256, 0, stream>>>(agg, zn);

  k_edge<<<(E + TE - 1) / TE, 256, 0, stream>>>(nft, eft, Wp, bp, Wa1, at2,
                                                src, dst, ep, aout, menc, E);

  k_decode<<<(N * NH + 255) / 256, 256, 0, stream>>>(menc, N * NH);

  k_scatter<<<(E + 3) / 4, 256, 0, stream>>>(ep, aout, (const float*)menc, dst,
                                             sden, agg, E);

  k_final<<<(N * FT + 255) / 256, 256, 0, stream>>>(agg, sden, nft, (float*)d_out,
                                                    N * FT);
}

// Round 2
// 531.766 us; speedup vs baseline: 1.5744x; 1.5744x over previous
//
#include <hip/hip_runtime.h>
#include <hip/hip_bf16.h>

#define FT 128
#define NH 8

typedef short bf16x8 __attribute__((ext_vector_type(8)));
typedef float f32x4 __attribute__((ext_vector_type(4)));

__device__ __forceinline__ unsigned enc_f32(float f) {
  unsigned u = __float_as_uint(f);
  return (u & 0x80000000u) ? ~u : (u | 0x80000000u);
}
__device__ __forceinline__ float dec_f32(unsigned u) {
  unsigned v = (u & 0x80000000u) ? (u & 0x7FFFFFFFu) : ~u;
  return __uint_as_float(v);
}
__device__ __forceinline__ ushort f2bf(float f) {
  __hip_bfloat16 h = __float2bfloat16(f);
  return *reinterpret_cast<ushort*>(&h);
}

// ---------------- K0: zero [agg | s | m_enc] ----------------
__global__ void k_zero(float* __restrict__ p, size_t n) {
  size_t i = (size_t)blockIdx.x * blockDim.x + threadIdx.x;
  if (i < n) p[i] = 0.0f;
}

// ---------------- prep: W_path fp32 [384][128] -> Wt bf16 [128][384] (transposed) ----
__global__ void k_prep_w(const float* __restrict__ Wp, ushort* __restrict__ Wt) {
  int i = blockIdx.x * 256 + threadIdx.x;
  if (i < 384 * 128) {
    int k = i >> 7, c = i & 127;
    Wt[(size_t)c * 384 + k] = f2bf(Wp[i]);
  }
}

// ---------------- prep: a1n[node][h] = nft[node] . Wa1[:,h] ----------------
__global__ __launch_bounds__(256) void k_prep_a1(
    const float* __restrict__ nft, const float* __restrict__ Wa1,
    float* __restrict__ a1n, int N)
{
  __shared__ float w[FT * NH];
  int t = threadIdx.x;
  for (int i = t; i < FT * NH; i += 256) w[i] = Wa1[i];
  __syncthreads();
  int i = blockIdx.x * 256 + t;
  if (i >= N * NH) return;
  int node = i >> 3, h = i & 7;
  const float* xr = nft + (size_t)node * FT;
  float a = 0.0f;
  for (int k = 0; k < FT; k += 4) {
    float4 xv = *(const float4*)&xr[k];
    a = fmaf(xv.x, w[(k + 0) * NH + h], a);
    a = fmaf(xv.y, w[(k + 1) * NH + h], a);
    a = fmaf(xv.z, w[(k + 2) * NH + h], a);
    a = fmaf(xv.w, w[(k + 3) * NH + h], a);
  }
  a1n[i] = a;
}

// ---------------- K2: MFMA edge GEMM + logits + segment-max ----------------
// 256 threads = 4 waves; block computes 64 edges x 128 cols; K=384.
// Wave w: cols [w*32, w*32+32) (2 N-tiles = heads 2w,2w+1), all 64 edges (4 M-tiles).
__global__ __launch_bounds__(256) void k_edge_mfma(
    const float* __restrict__ nft, const float* __restrict__ eft,
    const ushort* __restrict__ Wt, const float* __restrict__ bp,
    const float* __restrict__ at2, const float* __restrict__ a1n,
    const int* __restrict__ src, const int* __restrict__ dst,
    ushort* __restrict__ ep, float* __restrict__ aout,
    unsigned* __restrict__ menc, int E)
{
  __shared__ ushort x[64][388];   // bf16 [hs|eft|hd], pad +4 (row stride 776B ~ 2-way)
  __shared__ int sS[64], sD[64];

  const int t = threadIdx.x;
  const int e0 = blockIdx.x * 64;

  // ---- stage: 4 threads per edge, fp32 gather -> bf16 LDS ----
  {
    int ei = t >> 2, q = t & 3;
    int e = min(e0 + ei, E - 1);
    int se = src[e], de = dst[e];
    if (q == 0) { sS[ei] = se; sD[ei] = de; }
    const float* hs = nft + (size_t)se * FT;
    const float* ef = eft + (size_t)e * FT;
    const float* hd = nft + (size_t)de * FT;
    #pragma unroll
    for (int jj = 0; jj < 8; ++jj) {
      int c = (q + 4 * jj) * 4;          // 0..124
      float4 v0 = *(const float4*)&hs[c];
      float4 v1 = *(const float4*)&ef[c];
      float4 v2 = *(const float4*)&hd[c];
      ushort4 b0, b1, b2;
      b0.x = f2bf(v0.x); b0.y = f2bf(v0.y); b0.z = f2bf(v0.z); b0.w = f2bf(v0.w);
      b1.x = f2bf(v1.x); b1.y = f2bf(v1.y); b1.z = f2bf(v1.z); b1.w = f2bf(v1.w);
      b2.x = f2bf(v2.x); b2.y = f2bf(v2.y); b2.z = f2bf(v2.z); b2.w = f2bf(v2.w);
      *(ushort4*)&x[ei][c]       = b0;
      *(ushort4*)&x[ei][128 + c] = b1;
      *(ushort4*)&x[ei][256 + c] = b2;
    }
  }
  __syncthreads();

  const int w  = t >> 6;
  const int l  = t & 63;
  const int lr = l & 15;     // col-within-tile (B/C) or row-within-tile (A)
  const int lk = l >> 4;     // k-block 0..3

  f32x4 acc[4][2];
  #pragma unroll
  for (int m = 0; m < 4; ++m) { acc[m][0] = 0.0f; acc[m][1] = 0.0f; }

  // B base: col = w*32 + ntl*16 + lr; elem offset lk*8
  const ushort* wt0 = Wt + ((size_t)(w * 32 + lr) * 384 + lk * 8);

  for (int ks = 0; ks < 12; ++ks) {
    bf16x8 b0 = *(const bf16x8*)(wt0 + ks * 32);
    bf16x8 b1 = *(const bf16x8*)(wt0 + 16 * 384 + ks * 32);
    int kb = ks * 32 + lk * 8;
    #pragma unroll
    for (int m = 0; m < 4; ++m) {
      bf16x8 a = *(const bf16x8*)&x[m * 16 + lr][kb];
      acc[m][0] = __builtin_amdgcn_mfma_f32_16x16x32_bf16(a, b0, acc[m][0], 0, 0, 0);
      acc[m][1] = __builtin_amdgcn_mfma_f32_16x16x32_bf16(a, b1, acc[m][1], 0, 0, 0);
    }
  }

  // ---- epilogue: bias, ep store (bf16), a2 reduce, logits + segment max ----
  const int rquad = lk * 4;   // C row base: (lane>>4)*4
  #pragma unroll
  for (int ntl = 0; ntl < 2; ++ntl) {
    int col  = w * 32 + ntl * 16 + lr;
    int head = w * 2 + ntl;
    float bpv = bp[col];
    float a2v = at2[col];
    #pragma unroll
    for (int m = 0; m < 4; ++m) {
      f32x4 c = acc[m][ntl];
      float p0 = c[0] + bpv, p1 = c[1] + bpv, p2 = c[2] + bpv, p3 = c[3] + bpv;
      int rb = m * 16 + rquad;           // row (edge-in-block) base for reg 0
      int eb = e0 + rb;
      if (eb + 3 < E) {
        ep[(size_t)(eb + 0) * FT + col] = f2bf(p0);
        ep[(size_t)(eb + 1) * FT + col] = f2bf(p1);
        ep[(size_t)(eb + 2) * FT + col] = f2bf(p2);
        ep[(size_t)(eb + 3) * FT + col] = f2bf(p3);
      } else {
        if (eb + 0 < E) ep[(size_t)(eb + 0) * FT + col] = f2bf(p0);
        if (eb + 1 < E) ep[(size_t)(eb + 1) * FT + col] = f2bf(p1);
        if (eb + 2 < E) ep[(size_t)(eb + 2) * FT + col] = f2bf(p2);
        if (eb + 3 < E) ep[(size_t)(eb + 3) * FT + col] = f2bf(p3);
      }
      // a2 partials: reduce across the 16 cols of this head
      float s0 = p0 * a2v, s1 = p1 * a2v, s2 = p2 * a2v, s3 = p3 * a2v;
      #pragma unroll
      for (int off = 1; off < 16; off <<= 1) {
        s0 += __shfl_xor(s0, off);
        s1 += __shfl_xor(s1, off);
        s2 += __shfl_xor(s2, off);
        s3 += __shfl_xor(s3, off);
      }
      if (lr == 0) {
        float sa[4] = {s0, s1, s2, s3};
        #pragma unroll
        for (int r = 0; r < 4; ++r) {
          int row = rb + r;
          int e = e0 + row;
          if (e < E) {
            float av = a1n[(size_t)sS[row] * NH + head] + sa[r];
            float lv = av > 0.0f ? av : 0.01f * av;
            aout[(size_t)e * NH + head] = lv;
            atomicMax(&menc[(size_t)sD[row] * NH + head], enc_f32(lv));
          }
        }
      }
    }
  }
}

// ---------------- K3: decode segment-max ----------------
__global__ void k_decode(unsigned* __restrict__ m, int n) {
  int i = blockIdx.x * 256 + threadIdx.x;
  if (i < n) {
    float f = dec_f32(m[i]);
    if (!isfinite(f)) f = 0.0f;
    ((float*)m)[i] = f;
  }
}

// ---------------- K4: exp + weighted scatter (unnormalized) ----------------
__global__ __launch_bounds__(256) void k_scatter(
    const ushort* __restrict__ ep, const float* __restrict__ aout,
    const float* __restrict__ m, const int* __restrict__ dst,
    float* __restrict__ s, float* __restrict__ agg, int E)
{
  int gid = blockIdx.x * 256 + threadIdx.x;
  int e = gid >> 6;
  int l = gid & 63;
  if (e >= E) return;
  int d = dst[e];
  int h = l >> 3;
  float av = aout[(size_t)e * NH + h];
  float mv = m[(size_t)d * NH + h];
  float ev = expf(av - mv);
  unsigned pk = *(const unsigned*)&ep[(size_t)e * FT + l * 2];
  float p0 = __uint_as_float(pk << 16);
  float p1 = __uint_as_float(pk & 0xFFFF0000u);
  atomicAdd(&agg[(size_t)d * FT + l * 2],     ev * p0);
  atomicAdd(&agg[(size_t)d * FT + l * 2 + 1], ev * p1);
  if ((l & 7) == 0) atomicAdd(&s[(size_t)d * NH + h], ev);
}

// ---------------- K5: out = relu(agg/s + nft) ----------------
__global__ void k_final(const float* __restrict__ agg, const float* __restrict__ s,
                        const float* __restrict__ nft, float* __restrict__ out, int total) {
  int i = blockIdx.x * 256 + threadIdx.x;
  if (i >= total) return;
  int n = i >> 7, c = i & 127, h = c >> 4;
  float sv = s[(size_t)n * NH + h];
  float v = sv > 0.0f ? agg[i] / sv : 0.0f;
  v += nft[i];
  out[i] = v > 0.0f ? v : 0.0f;
}

extern "C" void kernel_launch(void* const* d_in, const int* in_sizes, int n_in,
                              void* d_out, int out_size, void* d_ws, size_t ws_size,
                              hipStream_t stream) {
  const float* nft = (const float*)d_in[0];
  const float* eft = (const float*)d_in[1];
  const float* Wp  = (const float*)d_in[2];
  const float* bp  = (const float*)d_in[3];
  const float* Wa1 = (const float*)d_in[4];
  const float* at2 = (const float*)d_in[5];
  const int*   src = (const int*)d_in[6];
  const int*   dst = (const int*)d_in[7];
  const int N = in_sizes[0] / FT;
  const int E = in_sizes[6];

  char* ws = (char*)d_ws;
  size_t off = 0;
  ushort* ep = (ushort*)(ws + off);   off += (size_t)E * FT * sizeof(ushort);
  off = (off + 255) & ~(size_t)255;
  float* aout = (float*)(ws + off);   off += (size_t)E * NH * sizeof(float);
  off = (off + 255) & ~(size_t)255;
  float* agg = (float*)(ws + off);    off += (size_t)N * FT * sizeof(float);
  float* sden = (float*)(ws + off);   off += (size_t)N * NH * sizeof(float);
  unsigned* menc = (unsigned*)(ws + off); off += (size_t)N * NH * sizeof(float);
  off = (off + 255) & ~(size_t)255;
  ushort* Wt = (ushort*)(ws + off);   off += (size_t)128 * 384 * sizeof(ushort);
  off = (off + 255) & ~(size_t)255;
  float* a1n = (float*)(ws + off);    off += (size_t)N * NH * sizeof(float);

  size_t zn = (size_t)N * (FT + 2 * NH);
  k_zero<<<(int)((zn + 255) / 256), 256, 0, stream>>>(agg, zn);

  k_prep_w<<<(384 * 128 + 255) / 256, 256, 0, stream>>>(Wp, Wt);
  k_prep_a1<<<(N * NH + 255) / 256, 256, 0, stream>>>(nft, Wa1, a1n, N);

  k_edge_mfma<<<(E + 63) / 64, 256, 0, stream>>>(nft, eft, Wt, bp, at2, a1n,
                                                 src, dst, ep, aout, menc, E);

  k_decode<<<(N * NH + 255) / 256, 256, 0, stream>>>(menc, N * NH);

  k_scatter<<<(E + 3) / 4, 256, 0, stream>>>(ep, aout, (const float*)menc, dst,
                                             sden, agg, E);

  k_final<<<(N * FT + 255) / 256, 256, 0, stream>>>(agg, sden, nft, (float*)d_out,
                                                    N * FT);
}

// Round 3
// 314.213 us; speedup vs baseline: 2.6645x; 1.6924x over previous
//
#include <hip/hip_runtime.h>
#include <hip/hip_bf16.h>

#define FT 128
#define NH 8

typedef short bf16x8 __attribute__((ext_vector_type(8)));
typedef float f32x4 __attribute__((ext_vector_type(4)));

__device__ __forceinline__ ushort f2bf(float f) {
  __hip_bfloat16 h = __float2bfloat16(f);
  return *reinterpret_cast<ushort*>(&h);
}

// ---------------- zero int buffer ----------------
__global__ void k_zero_i(int* __restrict__ p, int n) {
  int i = blockIdx.x * 256 + threadIdx.x;
  if (i < n) p[i] = 0;
}

// ---------------- CSR build: histogram ----------------
__global__ void k_hist(const int* __restrict__ dst, int* __restrict__ cnt, int E) {
  int e = blockIdx.x * 256 + threadIdx.x;
  if (e < E) atomicAdd(&cnt[dst[e]], 1);
}

// ---------------- CSR build: single-block exclusive scan ----------------
__global__ __launch_bounds__(1024) void k_scan(const int* __restrict__ cnt,
                                               int* __restrict__ ptr,
                                               int* __restrict__ cur, int N) {
  __shared__ int buf[1024];
  __shared__ int carry;
  int t = threadIdx.x;
  if (t == 0) carry = 0;
  __syncthreads();
  for (int base = 0; base < N; base += 1024) {
    int v = (base + t < N) ? cnt[base + t] : 0;
    buf[t] = v;
    __syncthreads();
    #pragma unroll
    for (int off = 1; off < 1024; off <<= 1) {
      int x = (t >= off) ? buf[t - off] : 0;
      __syncthreads();
      buf[t] += x;
      __syncthreads();
    }
    int exc = carry + buf[t] - v;
    if (base + t < N) { ptr[base + t] = exc; cur[base + t] = exc; }
    __syncthreads();
    if (t == 0) carry += buf[1023];
    __syncthreads();
  }
  if (t == 0) ptr[N] = carry;
}

// ---------------- CSR build: fill sorted edge ids ----------------
__global__ void k_fill(const int* __restrict__ dst, int* __restrict__ cur,
                       int* __restrict__ sorted, int E) {
  int e = blockIdx.x * 256 + threadIdx.x;
  if (e < E) {
    int p = atomicAdd(&cur[dst[e]], 1);
    sorted[p] = e;
  }
}

// ---------------- prep: W_path fp32 [384][128] -> Wt bf16 [128][384] (transposed) ----
__global__ void k_prep_w(const float* __restrict__ Wp, ushort* __restrict__ Wt) {
  int i = blockIdx.x * 256 + threadIdx.x;
  if (i < 384 * 128) {
    int k = i >> 7, c = i & 127;
    Wt[(size_t)c * 384 + k] = f2bf(Wp[i]);
  }
}

// ---------------- prep: a1n[node][h] = nft[node] . Wa1[:,h] ----------------
__global__ __launch_bounds__(256) void k_prep_a1(
    const float* __restrict__ nft, const float* __restrict__ Wa1,
    float* __restrict__ a1n, int N)
{
  __shared__ float w[FT * NH];
  int t = threadIdx.x;
  for (int i = t; i < FT * NH; i += 256) w[i] = Wa1[i];
  __syncthreads();
  int i = blockIdx.x * 256 + t;
  if (i >= N * NH) return;
  int node = i >> 3, h = i & 7;
  const float* xr = nft + (size_t)node * FT;
  float a = 0.0f;
  for (int k = 0; k < FT; k += 4) {
    float4 xv = *(const float4*)&xr[k];
    a = fmaf(xv.x, w[(k + 0) * NH + h], a);
    a = fmaf(xv.y, w[(k + 1) * NH + h], a);
    a = fmaf(xv.z, w[(k + 2) * NH + h], a);
    a = fmaf(xv.w, w[(k + 3) * NH + h], a);
  }
  a1n[i] = a;
}

// ---------------- K2: MFMA edge GEMM + logits ----------------
// 256 threads = 4 waves; block computes 64 edges x 128 cols; K=384.
__global__ __launch_bounds__(256) void k_edge_mfma(
    const float* __restrict__ nft, const float* __restrict__ eft,
    const ushort* __restrict__ Wt, const float* __restrict__ bp,
    const float* __restrict__ at2, const float* __restrict__ a1n,
    const int* __restrict__ src, const int* __restrict__ dst,
    ushort* __restrict__ ep, float* __restrict__ aout, int E)
{
  __shared__ ushort x[64][388];   // bf16 [hs|eft|hd], pad +4
  __shared__ int sS[64];

  const int t = threadIdx.x;
  const int e0 = blockIdx.x * 64;

  // ---- stage: 4 threads per edge, fp32 gather -> bf16 LDS ----
  {
    int ei = t >> 2, q = t & 3;
    int e = min(e0 + ei, E - 1);
    int se = src[e], de = dst[e];
    if (q == 0) sS[ei] = se;
    const float* hs = nft + (size_t)se * FT;
    const float* ef = eft + (size_t)e * FT;
    const float* hd = nft + (size_t)de * FT;
    #pragma unroll
    for (int jj = 0; jj < 8; ++jj) {
      int c = (q + 4 * jj) * 4;          // 0..124
      float4 v0 = *(const float4*)&hs[c];
      float4 v1 = *(const float4*)&ef[c];
      float4 v2 = *(const float4*)&hd[c];
      ushort4 b0, b1, b2;
      b0.x = f2bf(v0.x); b0.y = f2bf(v0.y); b0.z = f2bf(v0.z); b0.w = f2bf(v0.w);
      b1.x = f2bf(v1.x); b1.y = f2bf(v1.y); b1.z = f2bf(v1.z); b1.w = f2bf(v1.w);
      b2.x = f2bf(v2.x); b2.y = f2bf(v2.y); b2.z = f2bf(v2.z); b2.w = f2bf(v2.w);
      *(ushort4*)&x[ei][c]       = b0;
      *(ushort4*)&x[ei][128 + c] = b1;
      *(ushort4*)&x[ei][256 + c] = b2;
    }
  }
  __syncthreads();

  const int w  = t >> 6;
  const int l  = t & 63;
  const int lr = l & 15;
  const int lk = l >> 4;

  f32x4 acc[4][2];
  #pragma unroll
  for (int m = 0; m < 4; ++m) { acc[m][0] = 0.0f; acc[m][1] = 0.0f; }

  const ushort* wt0 = Wt + ((size_t)(w * 32 + lr) * 384 + lk * 8);

  for (int ks = 0; ks < 12; ++ks) {
    bf16x8 b0 = *(const bf16x8*)(wt0 + ks * 32);
    bf16x8 b1 = *(const bf16x8*)(wt0 + 16 * 384 + ks * 32);
    int kb = ks * 32 + lk * 8;
    #pragma unroll
    for (int m = 0; m < 4; ++m) {
      bf16x8 a = *(const bf16x8*)&x[m * 16 + lr][kb];
      acc[m][0] = __builtin_amdgcn_mfma_f32_16x16x32_bf16(a, b0, acc[m][0], 0, 0, 0);
      acc[m][1] = __builtin_amdgcn_mfma_f32_16x16x32_bf16(a, b1, acc[m][1], 0, 0, 0);
    }
  }

  // ---- epilogue: bias, ep store (bf16), a2 reduce, logits ----
  const int rquad = lk * 4;
  #pragma unroll
  for (int ntl = 0; ntl < 2; ++ntl) {
    int col  = w * 32 + ntl * 16 + lr;
    int head = w * 2 + ntl;
    float bpv = bp[col];
    float a2v = at2[col];
    #pragma unroll
    for (int m = 0; m < 4; ++m) {
      f32x4 c = acc[m][ntl];
      float p0 = c[0] + bpv, p1 = c[1] + bpv, p2 = c[2] + bpv, p3 = c[3] + bpv;
      int rb = m * 16 + rquad;
      int eb = e0 + rb;
      if (eb + 3 < E) {
        ep[(size_t)(eb + 0) * FT + col] = f2bf(p0);
        ep[(size_t)(eb + 1) * FT + col] = f2bf(p1);
        ep[(size_t)(eb + 2) * FT + col] = f2bf(p2);
        ep[(size_t)(eb + 3) * FT + col] = f2bf(p3);
      } else {
        if (eb + 0 < E) ep[(size_t)(eb + 0) * FT + col] = f2bf(p0);
        if (eb + 1 < E) ep[(size_t)(eb + 1) * FT + col] = f2bf(p1);
        if (eb + 2 < E) ep[(size_t)(eb + 2) * FT + col] = f2bf(p2);
        if (eb + 3 < E) ep[(size_t)(eb + 3) * FT + col] = f2bf(p3);
      }
      float s0 = p0 * a2v, s1 = p1 * a2v, s2 = p2 * a2v, s3 = p3 * a2v;
      #pragma unroll
      for (int off = 1; off < 16; off <<= 1) {
        s0 += __shfl_xor(s0, off);
        s1 += __shfl_xor(s1, off);
        s2 += __shfl_xor(s2, off);
        s3 += __shfl_xor(s3, off);
      }
      if (lr == 0) {
        float sa[4] = {s0, s1, s2, s3};
        #pragma unroll
        for (int r = 0; r < 4; ++r) {
          int row = rb + r;
          int e = e0 + row;
          if (e < E) {
            float av = a1n[(size_t)sS[row] * NH + head] + sa[r];
            float lv = av > 0.0f ? av : 0.01f * av;
            aout[(size_t)e * NH + head] = lv;
          }
        }
      }
    }
  }
}

// ---------------- K4: wave-per-node gather aggregate + residual + relu ----------------
// lane l: output cols 2l, 2l+1 (head l>>3); phase-1 max uses (eslot=l>>3, h=l&7)
__global__ __launch_bounds__(256) void k_aggregate(
    const ushort* __restrict__ ep, const float* __restrict__ aout,
    const int* __restrict__ ptr, const int* __restrict__ sorted,
    const float* __restrict__ nft, float* __restrict__ out, int N)
{
  int wid = (blockIdx.x * 256 + threadIdx.x) >> 6;
  int l = threadIdx.x & 63;
  if (wid >= N) return;
  int beg = ptr[wid], end = ptr[wid + 1];

  // phase 1: per-head max of logits
  {
    int h = l & 7, es = l >> 3;
    float m = -INFINITY;
    for (int i = beg + es; i < end; i += 8)
      m = fmaxf(m, aout[(size_t)sorted[i] * NH + h]);
    m = fmaxf(m, __shfl_xor(m, 8));
    m = fmaxf(m, __shfl_xor(m, 16));
    m = fmaxf(m, __shfl_xor(m, 32));
    // hand each lane the max for the head that owns its output cols
    float mh = __shfl(m, l >> 3);

    // phase 2: exp + weighted accumulate (2 cols per lane)
    int hh = l >> 3;
    float acc0 = 0.0f, acc1 = 0.0f, s = 0.0f;
    for (int i = beg; i < end; ++i) {
      int e = sorted[i];
      float av = aout[(size_t)e * NH + hh];
      float ev = expf(av - mh);
      s += ev;
      unsigned pk = *(const unsigned*)&ep[(size_t)e * FT + l * 2];
      float p0 = __uint_as_float(pk << 16);
      float p1 = __uint_as_float(pk & 0xFFFF0000u);
      acc0 = fmaf(ev, p0, acc0);
      acc1 = fmaf(ev, p1, acc1);
    }
    float inv = s > 0.0f ? 1.0f / s : 0.0f;
    float2 nv = *(const float2*)&nft[(size_t)wid * FT + l * 2];
    float v0 = acc0 * inv + nv.x;
    float v1 = acc1 * inv + nv.y;
    float2 ov;
    ov.x = v0 > 0.0f ? v0 : 0.0f;
    ov.y = v1 > 0.0f ? v1 : 0.0f;
    *(float2*)&out[(size_t)wid * FT + l * 2] = ov;
  }
}

extern "C" void kernel_launch(void* const* d_in, const int* in_sizes, int n_in,
                              void* d_out, int out_size, void* d_ws, size_t ws_size,
                              hipStream_t stream) {
  const float* nft = (const float*)d_in[0];
  const float* eft = (const float*)d_in[1];
  const float* Wp  = (const float*)d_in[2];
  const float* bp  = (const float*)d_in[3];
  const float* Wa1 = (const float*)d_in[4];
  const float* at2 = (const float*)d_in[5];
  const int*   src = (const int*)d_in[6];
  const int*   dst = (const int*)d_in[7];
  const int N = in_sizes[0] / FT;
  const int E = in_sizes[6];

  char* ws = (char*)d_ws;
  size_t off = 0;
  ushort* ep = (ushort*)(ws + off);   off += (size_t)E * FT * sizeof(ushort);
  off = (off + 255) & ~(size_t)255;
  float* aout = (float*)(ws + off);   off += (size_t)E * NH * sizeof(float);
  off = (off + 255) & ~(size_t)255;
  ushort* Wt = (ushort*)(ws + off);   off += (size_t)128 * 384 * sizeof(ushort);
  off = (off + 255) & ~(size_t)255;
  float* a1n = (float*)(ws + off);    off += (size_t)N * NH * sizeof(float);
  off = (off + 255) & ~(size_t)255;
  int* cnt = (int*)(ws + off);        off += (size_t)N * sizeof(int);
  int* ptr = (int*)(ws + off);        off += (size_t)(N + 1) * sizeof(int);
  int* cur = (int*)(ws + off);        off += (size_t)N * sizeof(int);
  int* sorted = (int*)(ws + off);     off += (size_t)E * sizeof(int);

  // CSR build
  k_zero_i<<<(N + 255) / 256, 256, 0, stream>>>(cnt, N);
  k_hist<<<(E + 255) / 256, 256, 0, stream>>>(dst, cnt, E);
  k_scan<<<1, 1024, 0, stream>>>(cnt, ptr, cur, N);
  k_fill<<<(E + 255) / 256, 256, 0, stream>>>(dst, cur, sorted, E);

  // prep
  k_prep_w<<<(384 * 128 + 255) / 256, 256, 0, stream>>>(Wp, Wt);
  k_prep_a1<<<(N * NH + 255) / 256, 256, 0, stream>>>(nft, Wa1, a1n, N);

  // edge GEMM + logits
  k_edge_mfma<<<(E + 63) / 64, 256, 0, stream>>>(nft, eft, Wt, bp, at2, a1n,
                                                 src, dst, ep, aout, E);

  // aggregate + residual + relu
  k_aggregate<<<(N * 64 + 255) / 256, 256, 0, stream>>>(ep, aout, ptr, sorted,
                                                        nft, (float*)d_out, N);
}

// Round 4
// 290.670 us; speedup vs baseline: 2.8803x; 1.0810x over previous
//
#include <hip/hip_runtime.h>
#include <hip/hip_bf16.h>

#define FT 128
#define NH 8

typedef short bf16x8 __attribute__((ext_vector_type(8)));
typedef ushort u16x8 __attribute__((ext_vector_type(8)));
typedef float f32x4 __attribute__((ext_vector_type(4)));

__device__ __forceinline__ ushort f2bf(float f) {
  __hip_bfloat16 h = __float2bfloat16(f);
  return *reinterpret_cast<ushort*>(&h);
}
__device__ __forceinline__ float bf2f(ushort u) {
  return __uint_as_float(((unsigned)u) << 16);
}

// ---------------- zero int buffer ----------------
__global__ void k_zero_i(int* __restrict__ p, int n) {
  int i = blockIdx.x * 256 + threadIdx.x;
  if (i < n) p[i] = 0;
}

// ---------------- CSR build: histogram ----------------
__global__ void k_hist(const int* __restrict__ dst, int* __restrict__ cnt, int E) {
  int e = blockIdx.x * 256 + threadIdx.x;
  if (e < E) atomicAdd(&cnt[dst[e]], 1);
}

// ---------------- CSR build: single-block exclusive scan ----------------
__global__ __launch_bounds__(1024) void k_scan(const int* __restrict__ cnt,
                                               int* __restrict__ ptr,
                                               int* __restrict__ cur, int N) {
  __shared__ int buf[1024];
  __shared__ int carry;
  int t = threadIdx.x;
  if (t == 0) carry = 0;
  __syncthreads();
  for (int base = 0; base < N; base += 1024) {
    int v = (base + t < N) ? cnt[base + t] : 0;
    buf[t] = v;
    __syncthreads();
    #pragma unroll
    for (int off = 1; off < 1024; off <<= 1) {
      int x = (t >= off) ? buf[t - off] : 0;
      __syncthreads();
      buf[t] += x;
      __syncthreads();
    }
    int exc = carry + buf[t] - v;
    if (base + t < N) { ptr[base + t] = exc; cur[base + t] = exc; }
    __syncthreads();
    if (t == 0) carry += buf[1023];
    __syncthreads();
  }
  if (t == 0) ptr[N] = carry;
}

// ---------------- CSR build: fill sorted edge ids ----------------
__global__ void k_fill(const int* __restrict__ dst, int* __restrict__ cur,
                       int* __restrict__ sorted, int E) {
  int e = blockIdx.x * 256 + threadIdx.x;
  if (e < E) {
    int p = atomicAdd(&cur[dst[e]], 1);
    sorted[p] = e;
  }
}

// ---------------- prep: split W_path into Wt1 [128][128] and WtN [256][128] (bf16, B-layout) ----
// Wt1[c][k]  = Wp[(128+k)*128 + c]                  (eft part, transposed)
// WtN[c][k]  = c<128 ? Wp[k*128+c] : Wp[(256+k)*128 + (c-128)]   ([W0|W2] transposed)
__global__ void k_prep_w(const float* __restrict__ Wp, ushort* __restrict__ Wt1,
                         ushort* __restrict__ WtN) {
  int i = blockIdx.x * 256 + threadIdx.x;
  if (i < 128 * 128) {
    int c = i >> 7, k = i & 127;
    Wt1[i] = f2bf(Wp[(size_t)(128 + k) * 128 + c]);
  } else if (i < 384 * 128) {
    int j = i - 128 * 128;
    int c = j >> 7, k = j & 127;
    float v = (c < 128) ? Wp[(size_t)k * 128 + c]
                        : Wp[(size_t)(256 + k) * 128 + (c - 128)];
    WtN[j] = f2bf(v);
  }
}

// ---------------- prep: a1n[node][h] = nft[node] . Wa1[:,h] ----------------
__global__ __launch_bounds__(256) void k_prep_a1(
    const float* __restrict__ nft, const float* __restrict__ Wa1,
    float* __restrict__ a1n, int N)
{
  __shared__ float w[FT * NH];
  int t = threadIdx.x;
  for (int i = t; i < FT * NH; i += 256) w[i] = Wa1[i];
  __syncthreads();
  int i = blockIdx.x * 256 + t;
  if (i >= N * NH) return;
  int node = i >> 3, h = i & 7;
  const float* xr = nft + (size_t)node * FT;
  float a = 0.0f;
  for (int k = 0; k < FT; k += 4) {
    float4 xv = *(const float4*)&xr[k];
    a = fmaf(xv.x, w[(k + 0) * NH + h], a);
    a = fmaf(xv.y, w[(k + 1) * NH + h], a);
    a = fmaf(xv.z, w[(k + 2) * NH + h], a);
    a = fmaf(xv.w, w[(k + 3) * NH + h], a);
  }
  a1n[i] = a;
}

// ---------------- node GEMM: nsAll[n][0:128]=nft@W0, [128:256]=nft@W2 ----------------
// 256 thr = 4 waves; 64 nodes/block; wave w -> cols w*64..w*64+63 (4 ntl); K=128.
__global__ __launch_bounds__(256) void k_node_mfma(
    const float* __restrict__ nft, const ushort* __restrict__ WtN,
    ushort* __restrict__ nsAll, int N)
{
  __shared__ ushort x[64][136];
  const int t = threadIdx.x;
  const int n0 = blockIdx.x * 64;

  {
    int ei = t >> 2, q = t & 3;
    int n = min(n0 + ei, N - 1);
    const float* xr = nft + (size_t)n * FT;
    #pragma unroll
    for (int j = 0; j < 4; ++j) {
      int c = q * 32 + j * 8;
      float4 u = *(const float4*)&xr[c];
      float4 v = *(const float4*)&xr[c + 4];
      u16x8 pk;
      pk[0] = f2bf(u.x); pk[1] = f2bf(u.y); pk[2] = f2bf(u.z); pk[3] = f2bf(u.w);
      pk[4] = f2bf(v.x); pk[5] = f2bf(v.y); pk[6] = f2bf(v.z); pk[7] = f2bf(v.w);
      *(u16x8*)&x[ei][c] = pk;
    }
  }
  __syncthreads();

  const int w  = t >> 6;
  const int l  = t & 63;
  const int lr = l & 15;
  const int lk = l >> 4;

  bf16x8 breg[4][4];
  const ushort* wb = WtN + ((size_t)(w * 64 + lr) * 128 + lk * 8);
  #pragma unroll
  for (int ntl = 0; ntl < 4; ++ntl)
    #pragma unroll
    for (int ks = 0; ks < 4; ++ks)
      breg[ks][ntl] = *(const bf16x8*)(wb + (size_t)ntl * 16 * 128 + ks * 32);

  f32x4 acc[4][4];
  #pragma unroll
  for (int m = 0; m < 4; ++m)
    #pragma unroll
    for (int ntl = 0; ntl < 4; ++ntl) acc[m][ntl] = 0.0f;

  #pragma unroll
  for (int ks = 0; ks < 4; ++ks) {
    int kb = ks * 32 + lk * 8;
    #pragma unroll
    for (int m = 0; m < 4; ++m) {
      bf16x8 a = *(const bf16x8*)&x[m * 16 + lr][kb];
      #pragma unroll
      for (int ntl = 0; ntl < 4; ++ntl)
        acc[m][ntl] = __builtin_amdgcn_mfma_f32_16x16x32_bf16(a, breg[ks][ntl], acc[m][ntl], 0, 0, 0);
    }
  }

  #pragma unroll
  for (int ntl = 0; ntl < 4; ++ntl) {
    int col = w * 64 + ntl * 16 + lr;
    #pragma unroll
    for (int m = 0; m < 4; ++m) {
      int rb = m * 16 + lk * 4;
      f32x4 c = acc[m][ntl];
      #pragma unroll
      for (int r = 0; r < 4; ++r) {
        int node = n0 + rb + r;
        if (node < N) nsAll[(size_t)node * 256 + col] = f2bf(c[r]);
      }
    }
  }
}

// ---------------- edge GEMM: eft@W1 + ns0[src] + ns2[dst] + b; logits ----------------
// 256 thr = 4 waves; 64 edges/block; wave w -> cols w*32..+31 (heads 2w,2w+1); K=128.
__global__ __launch_bounds__(256) void k_edge_mfma(
    const float* __restrict__ eft, const ushort* __restrict__ Wt1,
    const ushort* __restrict__ nsAll, const float* __restrict__ bp,
    const float* __restrict__ at2, const float* __restrict__ a1n,
    const int* __restrict__ src, const int* __restrict__ dst,
    ushort* __restrict__ ep, float* __restrict__ aout, int E)
{
  __shared__ ushort x[64][136];     // eft tile bf16
  __shared__ ushort nsum[64][136];  // ns0[src]+ns2[dst] bf16
  __shared__ int sS[64];

  const int t = threadIdx.x;
  const int e0 = blockIdx.x * 64;

  // ---- stage ----
  {
    int ei = t >> 2, q = t & 3;
    int e = min(e0 + ei, E - 1);
    int se = src[e], de = dst[e];
    if (q == 0) sS[ei] = se;
    const float* ef = eft + (size_t)e * FT;
    const ushort* r0 = nsAll + (size_t)se * 256 + q * 32;
    const ushort* r2 = nsAll + (size_t)de * 256 + 128 + q * 32;
    #pragma unroll
    for (int j = 0; j < 4; ++j) {
      int c = q * 32 + j * 8;
      float4 u = *(const float4*)&ef[c];
      float4 v = *(const float4*)&ef[c + 4];
      u16x8 pk;
      pk[0] = f2bf(u.x); pk[1] = f2bf(u.y); pk[2] = f2bf(u.z); pk[3] = f2bf(u.w);
      pk[4] = f2bf(v.x); pk[5] = f2bf(v.y); pk[6] = f2bf(v.z); pk[7] = f2bf(v.w);
      *(u16x8*)&x[ei][c] = pk;

      u16x8 a0 = *(const u16x8*)(r0 + j * 8);
      u16x8 a2 = *(const u16x8*)(r2 + j * 8);
      u16x8 sm;
      #pragma unroll
      for (int z = 0; z < 8; ++z) sm[z] = f2bf(bf2f(a0[z]) + bf2f(a2[z]));
      *(u16x8*)&nsum[ei][c] = sm;
    }
  }
  __syncthreads();

  const int w  = t >> 6;
  const int l  = t & 63;
  const int lr = l & 15;
  const int lk = l >> 4;

  bf16x8 breg[4][2];
  const ushort* wb = Wt1 + ((size_t)(w * 32 + lr) * 128 + lk * 8);
  #pragma unroll
  for (int ks = 0; ks < 4; ++ks) {
    breg[ks][0] = *(const bf16x8*)(wb + ks * 32);
    breg[ks][1] = *(const bf16x8*)(wb + 16 * 128 + ks * 32);
  }

  f32x4 acc[4][2];
  #pragma unroll
  for (int m = 0; m < 4; ++m) { acc[m][0] = 0.0f; acc[m][1] = 0.0f; }

  #pragma unroll
  for (int ks = 0; ks < 4; ++ks) {
    int kb = ks * 32 + lk * 8;
    #pragma unroll
    for (int m = 0; m < 4; ++m) {
      bf16x8 a = *(const bf16x8*)&x[m * 16 + lr][kb];
      acc[m][0] = __builtin_amdgcn_mfma_f32_16x16x32_bf16(a, breg[ks][0], acc[m][0], 0, 0, 0);
      acc[m][1] = __builtin_amdgcn_mfma_f32_16x16x32_bf16(a, breg[ks][1], acc[m][1], 0, 0, 0);
    }
  }

  // ---- epilogue ----
  #pragma unroll
  for (int ntl = 0; ntl < 2; ++ntl) {
    int col  = w * 32 + ntl * 16 + lr;
    int head = w * 2 + ntl;
    float bpv = bp[col];
    float a2v = at2[col];
    #pragma unroll
    for (int m = 0; m < 4; ++m) {
      f32x4 c = acc[m][ntl];
      int rb = m * 16 + lk * 4;
      float p0 = c[0] + bpv + bf2f(nsum[rb + 0][col]);
      float p1 = c[1] + bpv + bf2f(nsum[rb + 1][col]);
      float p2 = c[2] + bpv + bf2f(nsum[rb + 2][col]);
      float p3 = c[3] + bpv + bf2f(nsum[rb + 3][col]);
      int eb = e0 + rb;
      if (eb + 3 < E) {
        ep[(size_t)(eb + 0) * FT + col] = f2bf(p0);
        ep[(size_t)(eb + 1) * FT + col] = f2bf(p1);
        ep[(size_t)(eb + 2) * FT + col] = f2bf(p2);
        ep[(size_t)(eb + 3) * FT + col] = f2bf(p3);
      } else {
        if (eb + 0 < E) ep[(size_t)(eb + 0) * FT + col] = f2bf(p0);
        if (eb + 1 < E) ep[(size_t)(eb + 1) * FT + col] = f2bf(p1);
        if (eb + 2 < E) ep[(size_t)(eb + 2) * FT + col] = f2bf(p2);
        if (eb + 3 < E) ep[(size_t)(eb + 3) * FT + col] = f2bf(p3);
      }
      float s0 = p0 * a2v, s1 = p1 * a2v, s2 = p2 * a2v, s3 = p3 * a2v;
      #pragma unroll
      for (int off = 1; off < 16; off <<= 1) {
        s0 += __shfl_xor(s0, off);
        s1 += __shfl_xor(s1, off);
        s2 += __shfl_xor(s2, off);
        s3 += __shfl_xor(s3, off);
      }
      if (lr == 0) {
        float sa[4] = {s0, s1, s2, s3};
        #pragma unroll
        for (int r = 0; r < 4; ++r) {
          int e = e0 + rb + r;
          if (e < E) {
            float av = a1n[(size_t)sS[rb + r] * NH + head] + sa[r];
            float lv = av > 0.0f ? av : 0.01f * av;
            aout[(size_t)e * NH + head] = lv;
          }
        }
      }
    }
  }
}

// ---------------- aggregate: wave-per-node, softmax + weighted sum + relu ----------------
__global__ __launch_bounds__(256) void k_aggregate(
    const ushort* __restrict__ ep, const float* __restrict__ aout,
    const int* __restrict__ ptr, const int* __restrict__ sorted,
    const float* __restrict__ nft, float* __restrict__ out, int N)
{
  int wid = (blockIdx.x * 256 + threadIdx.x) >> 6;
  int l = threadIdx.x & 63;
  if (wid >= N) return;
  int beg = ptr[wid], end = ptr[wid + 1];

  int h = l & 7, es = l >> 3;
  float m = -INFINITY;
  for (int i = beg + es; i < end; i += 8)
    m = fmaxf(m, aout[(size_t)sorted[i] * NH + h]);
  m = fmaxf(m, __shfl_xor(m, 8));
  m = fmaxf(m, __shfl_xor(m, 16));
  m = fmaxf(m, __shfl_xor(m, 32));
  float mh = __shfl(m, l >> 3);

  int hh = l >> 3;
  float acc0 = 0.0f, acc1 = 0.0f, s = 0.0f;
  for (int i = beg; i < end; ++i) {
    int e = sorted[i];
    float av = aout[(size_t)e * NH + hh];
    float ev = expf(av - mh);
    s += ev;
    unsigned pk = *(const unsigned*)&ep[(size_t)e * FT + l * 2];
    float p0 = __uint_as_float(pk << 16);
    float p1 = __uint_as_float(pk & 0xFFFF0000u);
    acc0 = fmaf(ev, p0, acc0);
    acc1 = fmaf(ev, p1, acc1);
  }
  float inv = s > 0.0f ? 1.0f / s : 0.0f;
  float2 nv = *(const float2*)&nft[(size_t)wid * FT + l * 2];
  float v0 = acc0 * inv + nv.x;
  float v1 = acc1 * inv + nv.y;
  float2 ov;
  ov.x = v0 > 0.0f ? v0 : 0.0f;
  ov.y = v1 > 0.0f ? v1 : 0.0f;
  *(float2*)&out[(size_t)wid * FT + l * 2] = ov;
}

extern "C" void kernel_launch(void* const* d_in, const int* in_sizes, int n_in,
                              void* d_out, int out_size, void* d_ws, size_t ws_size,
                              hipStream_t stream) {
  const float* nft = (const float*)d_in[0];
  const float* eft = (const float*)d_in[1];
  const float* Wp  = (const float*)d_in[2];
  const float* bp  = (const float*)d_in[3];
  const float* Wa1 = (const float*)d_in[4];
  const float* at2 = (const float*)d_in[5];
  const int*   src = (const int*)d_in[6];
  const int*   dst = (const int*)d_in[7];
  const int N = in_sizes[0] / FT;
  const int E = in_sizes[6];

  char* ws = (char*)d_ws;
  size_t off = 0;
  ushort* ep = (ushort*)(ws + off);   off += (size_t)E * FT * sizeof(ushort);
  off = (off + 255) & ~(size_t)255;
  float* aout = (float*)(ws + off);   off += (size_t)E * NH * sizeof(float);
  off = (off + 255) & ~(size_t)255;
  ushort* Wt1 = (ushort*)(ws + off);  off += (size_t)128 * 128 * sizeof(ushort);
  ushort* WtN = (ushort*)(ws + off);  off += (size_t)256 * 128 * sizeof(ushort);
  off = (off + 255) & ~(size_t)255;
  float* a1n = (float*)(ws + off);    off += (size_t)N * NH * sizeof(float);
  off = (off + 255) & ~(size_t)255;
  ushort* nsAll = (ushort*)(ws + off); off += (size_t)N * 256 * sizeof(ushort);
  off = (off + 255) & ~(size_t)255;
  int* cnt = (int*)(ws + off);        off += (size_t)N * sizeof(int);
  int* ptr = (int*)(ws + off);        off += (size_t)(N + 1) * sizeof(int);
  int* cur = (int*)(ws + off);        off += (size_t)N * sizeof(int);
  int* sorted = (int*)(ws + off);     off += (size_t)E * sizeof(int);

  // CSR build
  k_zero_i<<<(N + 255) / 256, 256, 0, stream>>>(cnt, N);
  k_hist<<<(E + 255) / 256, 256, 0, stream>>>(dst, cnt, E);
  k_scan<<<1, 1024, 0, stream>>>(cnt, ptr, cur, N);
  k_fill<<<(E + 255) / 256, 256, 0, stream>>>(dst, cur, sorted, E);

  // prep
  k_prep_w<<<(384 * 128 + 255) / 256, 256, 0, stream>>>(Wp, Wt1, WtN);
  k_prep_a1<<<(N * NH + 255) / 256, 256, 0, stream>>>(nft, Wa1, a1n, N);
  k_node_mfma<<<(N + 63) / 64, 256, 0, stream>>>(nft, WtN, nsAll, N);

  // edge GEMM + logits
  k_edge_mfma<<<(E + 63) / 64, 256, 0, stream>>>(eft, Wt1, nsAll, bp, at2, a1n,
                                                 src, dst, ep, aout, E);

  // aggregate + residual + relu
  k_aggregate<<<(N * 64 + 255) / 256, 256, 0, stream>>>(ep, aout, ptr, sorted,
                                                        nft, (float*)d_out, N);
}

// Round 5
// 243.909 us; speedup vs baseline: 3.4325x; 1.1917x over previous
//
#include <hip/hip_runtime.h>
#include <hip/hip_bf16.h>

#define FT 128
#define NH 8

typedef short bf16x8 __attribute__((ext_vector_type(8)));
typedef ushort u16x8 __attribute__((ext_vector_type(8)));
typedef float f32x4 __attribute__((ext_vector_type(4)));

__device__ __forceinline__ ushort f2bf(float f) {
  __hip_bfloat16 h = __float2bfloat16(f);
  return *reinterpret_cast<ushort*>(&h);
}
__device__ __forceinline__ float bf2f(ushort u) {
  return __uint_as_float(((unsigned)u) << 16);
}

// ---------------- zero int buffer ----------------
__global__ void k_zero_i(int* __restrict__ p, int n) {
  int i = blockIdx.x * 256 + threadIdx.x;
  if (i < n) p[i] = 0;
}

// ---------------- CSR build: histogram ----------------
__global__ void k_hist(const int* __restrict__ dst, int* __restrict__ cnt, int E) {
  int e = blockIdx.x * 256 + threadIdx.x;
  if (e < E) atomicAdd(&cnt[dst[e]], 1);
}

// ---------------- CSR build: single-block exclusive scan ----------------
__global__ __launch_bounds__(1024) void k_scan(const int* __restrict__ cnt,
                                               int* __restrict__ ptr,
                                               int* __restrict__ cur, int N) {
  __shared__ int buf[1024];
  __shared__ int carry;
  int t = threadIdx.x;
  if (t == 0) carry = 0;
  __syncthreads();
  for (int base = 0; base < N; base += 1024) {
    int v = (base + t < N) ? cnt[base + t] : 0;
    buf[t] = v;
    __syncthreads();
    #pragma unroll
    for (int off = 1; off < 1024; off <<= 1) {
      int x = (t >= off) ? buf[t - off] : 0;
      __syncthreads();
      buf[t] += x;
      __syncthreads();
    }
    int exc = carry + buf[t] - v;
    if (base + t < N) { ptr[base + t] = exc; cur[base + t] = exc; }
    __syncthreads();
    if (t == 0) carry += buf[1023];
    __syncthreads();
  }
  if (t == 0) ptr[N] = carry;
}

// ---------------- CSR build: fill sorted edge ids + sorted src ----------------
__global__ void k_fill(const int* __restrict__ dst, const int* __restrict__ src,
                       int* __restrict__ cur, int* __restrict__ sorted,
                       int* __restrict__ srcS, int E) {
  int e = blockIdx.x * 256 + threadIdx.x;
  if (e < E) {
    int p = atomicAdd(&cur[dst[e]], 1);
    sorted[p] = e;
    srcS[p] = src[e];
  }
}

// ---------------- prep: split W_path into Wt1 [128][128] and WtN [256][128] (bf16, B-layout) ----
__global__ void k_prep_w(const float* __restrict__ Wp, ushort* __restrict__ Wt1,
                         ushort* __restrict__ WtN) {
  int i = blockIdx.x * 256 + threadIdx.x;
  if (i < 128 * 128) {
    int c = i >> 7, k = i & 127;
    Wt1[i] = f2bf(Wp[(size_t)(128 + k) * 128 + c]);
  } else if (i < 384 * 128) {
    int j = i - 128 * 128;
    int c = j >> 7, k = j & 127;
    float v = (c < 128) ? Wp[(size_t)k * 128 + c]
                        : Wp[(size_t)(256 + k) * 128 + (c - 128)];
    WtN[j] = f2bf(v);
  }
}

// ---------------- prep: cb[h] = sum_j bp[16h+j]*at2[16h+j] ----------------
__global__ void k_prep_cb(const float* __restrict__ bp, const float* __restrict__ at2,
                          float* __restrict__ cb) {
  int h = threadIdx.x;
  if (h < NH) {
    float s = 0.0f;
    #pragma unroll
    for (int j = 0; j < 16; ++j) s += bp[h * 16 + j] * at2[h * 16 + j];
    cb[h] = s;
  }
}

// ---------------- prep: a1c0[n][h] = nft[n].Wa1[:,h] + c0n[n][h]  (AFTER k_node) ----
__global__ __launch_bounds__(256) void k_prep_a1(
    const float* __restrict__ nft, const float* __restrict__ Wa1,
    const float* __restrict__ c0n, float* __restrict__ a1c0, int N)
{
  __shared__ float w[FT * NH];
  int t = threadIdx.x;
  for (int i = t; i < FT * NH; i += 256) w[i] = Wa1[i];
  __syncthreads();
  int i = blockIdx.x * 256 + t;
  if (i >= N * NH) return;
  int node = i >> 3, h = i & 7;
  const float* xr = nft + (size_t)node * FT;
  float a = 0.0f;
  for (int k = 0; k < FT; k += 4) {
    float4 xv = *(const float4*)&xr[k];
    a = fmaf(xv.x, w[(k + 0) * NH + h], a);
    a = fmaf(xv.y, w[(k + 1) * NH + h], a);
    a = fmaf(xv.z, w[(k + 2) * NH + h], a);
    a = fmaf(xv.w, w[(k + 3) * NH + h], a);
  }
  a1c0[i] = a + c0n[i];
}

// ---------------- node GEMM: nsAll = nft@[W0|W2] bf16; c0n/c2n = (ns.*at2) head-sums fp32 ----
__global__ __launch_bounds__(256) void k_node_mfma(
    const float* __restrict__ nft, const ushort* __restrict__ WtN,
    const float* __restrict__ at2, ushort* __restrict__ nsAll,
    float* __restrict__ c0n, float* __restrict__ c2n, int N)
{
  __shared__ ushort x[64][136];
  const int t = threadIdx.x;
  const int n0 = blockIdx.x * 64;

  {
    int ei = t >> 2, q = t & 3;
    int n = min(n0 + ei, N - 1);
    const float* xr = nft + (size_t)n * FT;
    #pragma unroll
    for (int j = 0; j < 4; ++j) {
      int c = q * 32 + j * 8;
      float4 u = *(const float4*)&xr[c];
      float4 v = *(const float4*)&xr[c + 4];
      u16x8 pk;
      pk[0] = f2bf(u.x); pk[1] = f2bf(u.y); pk[2] = f2bf(u.z); pk[3] = f2bf(u.w);
      pk[4] = f2bf(v.x); pk[5] = f2bf(v.y); pk[6] = f2bf(v.z); pk[7] = f2bf(v.w);
      *(u16x8*)&x[ei][c] = pk;
    }
  }
  __syncthreads();

  const int w  = t >> 6;
  const int l  = t & 63;
  const int lr = l & 15;
  const int lk = l >> 4;

  bf16x8 breg[4][4];
  const ushort* wb = WtN + ((size_t)(w * 64 + lr) * 128 + lk * 8);
  #pragma unroll
  for (int ntl = 0; ntl < 4; ++ntl)
    #pragma unroll
    for (int ks = 0; ks < 4; ++ks)
      breg[ks][ntl] = *(const bf16x8*)(wb + (size_t)ntl * 16 * 128 + ks * 32);

  f32x4 acc[4][4];
  #pragma unroll
  for (int m = 0; m < 4; ++m)
    #pragma unroll
    for (int ntl = 0; ntl < 4; ++ntl) acc[m][ntl] = 0.0f;

  #pragma unroll
  for (int ks = 0; ks < 4; ++ks) {
    int kb = ks * 32 + lk * 8;
    #pragma unroll
    for (int m = 0; m < 4; ++m) {
      bf16x8 a = *(const bf16x8*)&x[m * 16 + lr][kb];
      #pragma unroll
      for (int ntl = 0; ntl < 4; ++ntl)
        acc[m][ntl] = __builtin_amdgcn_mfma_f32_16x16x32_bf16(a, breg[ks][ntl], acc[m][ntl], 0, 0, 0);
    }
  }

  #pragma unroll
  for (int ntl = 0; ntl < 4; ++ntl) {
    int col = w * 64 + ntl * 16 + lr;
    int hcol = col & 127;
    int head = hcol >> 4;
    float a2v = at2[hcol];
    float* cdst = (col < 128) ? c0n : c2n;
    #pragma unroll
    for (int m = 0; m < 4; ++m) {
      int rb = m * 16 + lk * 4;
      f32x4 c = acc[m][ntl];
      float s0 = c[0] * a2v, s1 = c[1] * a2v, s2 = c[2] * a2v, s3 = c[3] * a2v;
      #pragma unroll
      for (int off = 1; off < 16; off <<= 1) {
        s0 += __shfl_xor(s0, off);
        s1 += __shfl_xor(s1, off);
        s2 += __shfl_xor(s2, off);
        s3 += __shfl_xor(s3, off);
      }
      #pragma unroll
      for (int r = 0; r < 4; ++r) {
        int node = n0 + rb + r;
        if (node < N) nsAll[(size_t)node * 256 + col] = f2bf(c[r]);
      }
      if (lr == 0) {
        float sa[4] = {s0, s1, s2, s3};
        #pragma unroll
        for (int r = 0; r < 4; ++r) {
          int node = n0 + rb + r;
          if (node < N) cdst[(size_t)node * NH + head] = sa[r];
        }
      }
    }
  }
}

// ---------------- edge GEMM: pure streaming ep = eft@W1 (bf16), ce = ew1.attn2 ----------------
// 512 thr = 8 waves; 128 edges/block; wave: cols (w&3)*32..+31, rows (w>>2)*64..+63.
__global__ __launch_bounds__(512) void k_edge_mfma(
    const float* __restrict__ eft, const ushort* __restrict__ Wt1,
    const float* __restrict__ at2,
    ushort* __restrict__ ep, float* __restrict__ ce, int E)
{
  __shared__ ushort x[128][136];   // A tile bf16; reused for C staging
  __shared__ float ceS[128][NH];

  const int t = threadIdx.x;
  const int e0 = blockIdx.x * 128;

  // ---- stage eft -> bf16 LDS (sequential, coalesced) ----
  {
    int ei = t >> 2, q = t & 3;
    int e = min(e0 + ei, E - 1);
    const float* ef = eft + (size_t)e * FT;
    #pragma unroll
    for (int j = 0; j < 4; ++j) {
      int c = q * 32 + j * 8;
      float4 u = *(const float4*)&ef[c];
      float4 v = *(const float4*)&ef[c + 4];
      u16x8 pk;
      pk[0] = f2bf(u.x); pk[1] = f2bf(u.y); pk[2] = f2bf(u.z); pk[3] = f2bf(u.w);
      pk[4] = f2bf(v.x); pk[5] = f2bf(v.y); pk[6] = f2bf(v.z); pk[7] = f2bf(v.w);
      *(u16x8*)&x[ei][c] = pk;
    }
  }
  __syncthreads();

  const int w  = t >> 6;
  const int l  = t & 63;
  const int lr = l & 15;
  const int lk = l >> 4;
  const int wc = w & 3;        // col group: cols wc*32..+31 (heads 2wc, 2wc+1)
  const int wm = w >> 2;       // row group: rows wm*64..+63

  bf16x8 breg[4][2];
  const ushort* wb = Wt1 + ((size_t)(wc * 32 + lr) * 128 + lk * 8);
  #pragma unroll
  for (int ks = 0; ks < 4; ++ks) {
    breg[ks][0] = *(const bf16x8*)(wb + ks * 32);
    breg[ks][1] = *(const bf16x8*)(wb + 16 * 128 + ks * 32);
  }

  f32x4 acc[4][2];
  #pragma unroll
  for (int m = 0; m < 4; ++m) { acc[m][0] = 0.0f; acc[m][1] = 0.0f; }

  #pragma unroll
  for (int ks = 0; ks < 4; ++ks) {
    int kb = ks * 32 + lk * 8;
    #pragma unroll
    for (int m = 0; m < 4; ++m) {
      bf16x8 a = *(const bf16x8*)&x[wm * 64 + m * 16 + lr][kb];
      acc[m][0] = __builtin_amdgcn_mfma_f32_16x16x32_bf16(a, breg[ks][0], acc[m][0], 0, 0, 0);
      acc[m][1] = __builtin_amdgcn_mfma_f32_16x16x32_bf16(a, breg[ks][1], acc[m][1], 0, 0, 0);
    }
  }

  // ---- ce partials (fp32, no bias: ce = ew1 . attn2_head) ----
  #pragma unroll
  for (int ntl = 0; ntl < 2; ++ntl) {
    int col  = wc * 32 + ntl * 16 + lr;
    int head = wc * 2 + ntl;
    float a2v = at2[col];
    #pragma unroll
    for (int m = 0; m < 4; ++m) {
      f32x4 c = acc[m][ntl];
      float s0 = c[0] * a2v, s1 = c[1] * a2v, s2 = c[2] * a2v, s3 = c[3] * a2v;
      #pragma unroll
      for (int off = 1; off < 16; off <<= 1) {
        s0 += __shfl_xor(s0, off);
        s1 += __shfl_xor(s1, off);
        s2 += __shfl_xor(s2, off);
        s3 += __shfl_xor(s3, off);
      }
      if (lr == 0) {
        int rb = wm * 64 + m * 16 + lk * 4;
        ceS[rb + 0][head] = s0;
        ceS[rb + 1][head] = s1;
        ceS[rb + 2][head] = s2;
        ceS[rb + 3][head] = s3;
      }
    }
  }

  // ---- C staging into x (reuse), then coalesced global stores ----
  __syncthreads();   // all MFMA reads of x done
  #pragma unroll
  for (int ntl = 0; ntl < 2; ++ntl) {
    int col = wc * 32 + ntl * 16 + lr;
    #pragma unroll
    for (int m = 0; m < 4; ++m) {
      int rb = wm * 64 + m * 16 + lk * 4;
      f32x4 c = acc[m][ntl];
      x[rb + 0][col] = f2bf(c[0]);
      x[rb + 1][col] = f2bf(c[1]);
      x[rb + 2][col] = f2bf(c[2]);
      x[rb + 3][col] = f2bf(c[3]);
    }
  }
  __syncthreads();

  {
    int ei = t >> 2, q = t & 3;
    int e = e0 + ei;
    if (e < E) {
      #pragma unroll
      for (int j = 0; j < 4; ++j) {
        u16x8 vv = *(const u16x8*)&x[ei][q * 32 + j * 8];
        *(u16x8*)&ep[(size_t)e * FT + q * 32 + j * 8] = vv;
      }
    }
    if (t < 256) {
      int row = t >> 1, o = (t & 1) * 4;
      int e2 = e0 + row;
      if (e2 < E) *(float4*)&ce[(size_t)e2 * NH + o] = *(const float4*)&ceS[row][o];
    }
  }
}

// ---------------- aggregate: wave-per-node, online softmax, logits recomputed ----------------
// lane l: output cols 2l,2l+1; head hh=l>>3
__global__ __launch_bounds__(256) void k_aggregate(
    const ushort* __restrict__ ep, const ushort* __restrict__ nsAll,
    const float* __restrict__ a1c0, const float* __restrict__ ce,
    const float* __restrict__ c2n, const float* __restrict__ cb,
    const int* __restrict__ ptr, const int* __restrict__ sorted,
    const int* __restrict__ srcS, const float* __restrict__ bp,
    const float* __restrict__ nft, float* __restrict__ out, int N)
{
  int wid = (blockIdx.x * 256 + threadIdx.x) >> 6;
  int l = threadIdx.x & 63;
  if (wid >= N) return;
  int beg = ptr[wid], end = ptr[wid + 1];
  int hh = l >> 3;
  float c2b = c2n[(size_t)wid * NH + hh] + cb[hh];

  float m = -INFINITY, s = 0.0f, a0 = 0.0f, a1 = 0.0f;
  for (int i = beg; i < end; ++i) {
    int e  = sorted[i];
    int se = srcS[i];
    float lin = a1c0[(size_t)se * NH + hh] + ce[(size_t)e * NH + hh] + c2b;
    float lv = lin > 0.0f ? lin : 0.01f * lin;
    float mn = fmaxf(m, lv);
    float corr = __expf(m - mn);
    float ev   = __expf(lv - mn);
    unsigned pe = *(const unsigned*)&ep[(size_t)e * FT + l * 2];
    unsigned pn = *(const unsigned*)&nsAll[(size_t)se * 256 + l * 2];
    float p0 = __uint_as_float(pe << 16) + __uint_as_float(pn << 16);
    float p1 = __uint_as_float(pe & 0xFFFF0000u) + __uint_as_float(pn & 0xFFFF0000u);
    s  = s * corr + ev;
    a0 = a0 * corr + ev * p0;
    a1 = a1 * corr + ev * p1;
    m = mn;
  }

  float2 nv = *(const float2*)&nft[(size_t)wid * FT + l * 2];
  float v0, v1;
  if (s > 0.0f) {
    float inv = 1.0f / s;
    unsigned pn2 = *(const unsigned*)&nsAll[(size_t)wid * 256 + 128 + l * 2];
    float2 bv = *(const float2*)&bp[l * 2];
    v0 = a0 * inv + __uint_as_float(pn2 << 16)         + bv.x + nv.x;
    v1 = a1 * inv + __uint_as_float(pn2 & 0xFFFF0000u) + bv.y + nv.y;
  } else {
    v0 = nv.x; v1 = nv.y;
  }
  float2 ov;
  ov.x = v0 > 0.0f ? v0 : 0.0f;
  ov.y = v1 > 0.0f ? v1 : 0.0f;
  *(float2*)&out[(size_t)wid * FT + l * 2] = ov;
}

extern "C" void kernel_launch(void* const* d_in, const int* in_sizes, int n_in,
                              void* d_out, int out_size, void* d_ws, size_t ws_size,
                              hipStream_t stream) {
  const float* nft = (const float*)d_in[0];
  const float* eft = (const float*)d_in[1];
  const float* Wp  = (const float*)d_in[2];
  const float* bp  = (const float*)d_in[3];
  const float* Wa1 = (const float*)d_in[4];
  const float* at2 = (const float*)d_in[5];
  const int*   src = (const int*)d_in[6];
  const int*   dst = (const int*)d_in[7];
  const int N = in_sizes[0] / FT;
  const int E = in_sizes[6];

  char* ws = (char*)d_ws;
  size_t off = 0;
  ushort* ep = (ushort*)(ws + off);    off += (size_t)E * FT * sizeof(ushort);
  off = (off + 255) & ~(size_t)255;
  float* ce = (float*)(ws + off);      off += (size_t)E * NH * sizeof(float);
  off = (off + 255) & ~(size_t)255;
  ushort* Wt1 = (ushort*)(ws + off);   off += (size_t)128 * 128 * sizeof(ushort);
  ushort* WtN = (ushort*)(ws + off);   off += (size_t)256 * 128 * sizeof(ushort);
  off = (off + 255) & ~(size_t)255;
  float* a1c0 = (float*)(ws + off);    off += (size_t)N * NH * sizeof(float);
  float* c0n = (float*)(ws + off);     off += (size_t)N * NH * sizeof(float);
  float* c2n = (float*)(ws + off);     off += (size_t)N * NH * sizeof(float);
  float* cb = (float*)(ws + off);      off += 256;
  ushort* nsAll = (ushort*)(ws + off); off += (size_t)N * 256 * sizeof(ushort);
  off = (off + 255) & ~(size_t)255;
  int* cnt = (int*)(ws + off);         off += (size_t)N * sizeof(int);
  int* ptr = (int*)(ws + off);         off += (size_t)(N + 1) * sizeof(int);
  int* cur = (int*)(ws + off);         off += (size_t)N * sizeof(int);
  int* sorted = (int*)(ws + off);      off += (size_t)E * sizeof(int);
  int* srcS = (int*)(ws + off);        off += (size_t)E * sizeof(int);

  // CSR build
  k_zero_i<<<(N + 255) / 256, 256, 0, stream>>>(cnt, N);
  k_hist<<<(E + 255) / 256, 256, 0, stream>>>(dst, cnt, E);
  k_scan<<<1, 1024, 0, stream>>>(cnt, ptr, cur, N);
  k_fill<<<(E + 255) / 256, 256, 0, stream>>>(dst, src, cur, sorted, srcS, E);

  // prep
  k_prep_w<<<(384 * 128 + 255) / 256, 256, 0, stream>>>(Wp, Wt1, WtN);
  k_prep_cb<<<1, 64, 0, stream>>>(bp, at2, cb);
  k_node_mfma<<<(N + 63) / 64, 256, 0, stream>>>(nft, WtN, at2, nsAll, c0n, c2n, N);
  k_prep_a1<<<(N * NH + 255) / 256, 256, 0, stream>>>(nft, Wa1, c0n, a1c0, N);

  // streaming edge GEMM
  k_edge_mfma<<<(E + 127) / 128, 512, 0, stream>>>(eft, Wt1, at2, ep, ce, E);

  // aggregate + residual + relu
  k_aggregate<<<(N * 64 + 255) / 256, 256, 0, stream>>>(ep, nsAll, a1c0, ce, c2n,
                                                        cb, ptr, sorted, srcS, bp,
                                                        nft, (float*)d_out, N);
}

// Round 6
// 229.266 us; speedup vs baseline: 3.6517x; 1.0639x over previous
//
#include <hip/hip_runtime.h>
#include <hip/hip_bf16.h>

#define FT 128
#define NH 8

typedef short bf16x8 __attribute__((ext_vector_type(8)));
typedef ushort u16x8 __attribute__((ext_vector_type(8)));
typedef float f32x4 __attribute__((ext_vector_type(4)));

__device__ __forceinline__ ushort f2bf(float f) {
  __hip_bfloat16 h = __float2bfloat16(f);
  return *reinterpret_cast<ushort*>(&h);
}

// ---------------- setup: zero cnt + build Wt1/WtN (bf16 B-layout) + cb ----------------
// Wt1[c][k] = Wp[(128+k)*128+c];  WtN[c][k] = c<128 ? Wp[k*128+c] : Wp[(256+k)*128+(c-128)]
__global__ void k_setup(const float* __restrict__ Wp, const float* __restrict__ bp,
                        const float* __restrict__ at2, ushort* __restrict__ Wt1,
                        ushort* __restrict__ WtN, float* __restrict__ cb,
                        int* __restrict__ cnt, int N) {
  int i = blockIdx.x * 256 + threadIdx.x;
  if (i < N) cnt[i] = 0;
  if (i < 128 * 128) {
    int c = i >> 7, k = i & 127;
    Wt1[i] = f2bf(Wp[(size_t)(128 + k) * 128 + c]);
  }
  if (i < 256 * 128) {
    int c = i >> 7, k = i & 127;
    float v = (c < 128) ? Wp[(size_t)k * 128 + c]
                        : Wp[(size_t)(256 + k) * 128 + (c - 128)];
    WtN[i] = f2bf(v);
  }
  if (i < NH) {
    float s = 0.0f;
    #pragma unroll
    for (int j = 0; j < 16; ++j) s += bp[i * 16 + j] * at2[i * 16 + j];
    cb[i] = s;
  }
}

// ---------------- CSR build: histogram ----------------
__global__ void k_hist(const int* __restrict__ dst, int* __restrict__ cnt, int E) {
  int e = blockIdx.x * 256 + threadIdx.x;
  if (e < E) atomicAdd(&cnt[dst[e]], 1);
}

// ---------------- CSR build: single-block exclusive scan ----------------
__global__ __launch_bounds__(1024) void k_scan(const int* __restrict__ cnt,
                                               int* __restrict__ ptr,
                                               int* __restrict__ cur, int N) {
  __shared__ int buf[1024];
  __shared__ int carry;
  int t = threadIdx.x;
  if (t == 0) carry = 0;
  __syncthreads();
  for (int base = 0; base < N; base += 1024) {
    int v = (base + t < N) ? cnt[base + t] : 0;
    buf[t] = v;
    __syncthreads();
    #pragma unroll
    for (int off = 1; off < 1024; off <<= 1) {
      int x = (t >= off) ? buf[t - off] : 0;
      __syncthreads();
      buf[t] += x;
      __syncthreads();
    }
    int exc = carry + buf[t] - v;
    if (base + t < N) { ptr[base + t] = exc; cur[base + t] = exc; }
    __syncthreads();
    if (t == 0) carry += buf[1023];
    __syncthreads();
  }
  if (t == 0) ptr[N] = carry;
}

// ---------------- CSR build: fill sorted edge ids + sorted src ----------------
__global__ void k_fill(const int* __restrict__ dst, const int* __restrict__ src,
                       int* __restrict__ cur, int* __restrict__ sorted,
                       int* __restrict__ srcS, int E) {
  int e = blockIdx.x * 256 + threadIdx.x;
  if (e < E) {
    int p = atomicAdd(&cur[dst[e]], 1);
    sorted[p] = e;
    srcS[p] = src[e];
  }
}

// ---------------- prep: a1c0[n][h] = nft[n].Wa1[:,h] + c0n[n][h]  (AFTER k_node) ----
__global__ __launch_bounds__(256) void k_prep_a1(
    const float* __restrict__ nft, const float* __restrict__ Wa1,
    const float* __restrict__ c0n, float* __restrict__ a1c0, int N)
{
  __shared__ float w[FT * NH];
  int t = threadIdx.x;
  for (int i = t; i < FT * NH; i += 256) w[i] = Wa1[i];
  __syncthreads();
  int i = blockIdx.x * 256 + t;
  if (i >= N * NH) return;
  int node = i >> 3, h = i & 7;
  const float* xr = nft + (size_t)node * FT;
  float a = 0.0f;
  for (int k = 0; k < FT; k += 4) {
    float4 xv = *(const float4*)&xr[k];
    a = fmaf(xv.x, w[(k + 0) * NH + h], a);
    a = fmaf(xv.y, w[(k + 1) * NH + h], a);
    a = fmaf(xv.z, w[(k + 2) * NH + h], a);
    a = fmaf(xv.w, w[(k + 3) * NH + h], a);
  }
  a1c0[i] = a + c0n[i];
}

// ---------------- node GEMM: nsAll = nft@[W0|W2] bf16; c0n/c2n = (ns.*at2) head-sums fp32 ----
__global__ __launch_bounds__(256) void k_node_mfma(
    const float* __restrict__ nft, const ushort* __restrict__ WtN,
    const float* __restrict__ at2, ushort* __restrict__ nsAll,
    float* __restrict__ c0n, float* __restrict__ c2n, int N)
{
  __shared__ ushort x[64][136];
  const int t = threadIdx.x;
  const int n0 = blockIdx.x * 64;

  {
    int ei = t >> 2, q = t & 3;
    int n = min(n0 + ei, N - 1);
    const float* xr = nft + (size_t)n * FT;
    #pragma unroll
    for (int j = 0; j < 4; ++j) {
      int c = q * 32 + j * 8;
      float4 u = *(const float4*)&xr[c];
      float4 v = *(const float4*)&xr[c + 4];
      u16x8 pk;
      pk[0] = f2bf(u.x); pk[1] = f2bf(u.y); pk[2] = f2bf(u.z); pk[3] = f2bf(u.w);
      pk[4] = f2bf(v.x); pk[5] = f2bf(v.y); pk[6] = f2bf(v.z); pk[7] = f2bf(v.w);
      *(u16x8*)&x[ei][c] = pk;
    }
  }
  __syncthreads();

  const int w  = t >> 6;
  const int l  = t & 63;
  const int lr = l & 15;
  const int lk = l >> 4;

  bf16x8 breg[4][4];
  const ushort* wb = WtN + ((size_t)(w * 64 + lr) * 128 + lk * 8);
  #pragma unroll
  for (int ntl = 0; ntl < 4; ++ntl)
    #pragma unroll
    for (int ks = 0; ks < 4; ++ks)
      breg[ks][ntl] = *(const bf16x8*)(wb + (size_t)ntl * 16 * 128 + ks * 32);

  f32x4 acc[4][4];
  #pragma unroll
  for (int m = 0; m < 4; ++m)
    #pragma unroll
    for (int ntl = 0; ntl < 4; ++ntl) acc[m][ntl] = 0.0f;

  #pragma unroll
  for (int ks = 0; ks < 4; ++ks) {
    int kb = ks * 32 + lk * 8;
    #pragma unroll
    for (int m = 0; m < 4; ++m) {
      bf16x8 a = *(const bf16x8*)&x[m * 16 + lr][kb];
      #pragma unroll
      for (int ntl = 0; ntl < 4; ++ntl)
        acc[m][ntl] = __builtin_amdgcn_mfma_f32_16x16x32_bf16(a, breg[ks][ntl], acc[m][ntl], 0, 0, 0);
    }
  }

  #pragma unroll
  for (int ntl = 0; ntl < 4; ++ntl) {
    int col = w * 64 + ntl * 16 + lr;
    int hcol = col & 127;
    int head = hcol >> 4;
    float a2v = at2[hcol];
    float* cdst = (col < 128) ? c0n : c2n;
    #pragma unroll
    for (int m = 0; m < 4; ++m) {
      int rb = m * 16 + lk * 4;
      f32x4 c = acc[m][ntl];
      float s0 = c[0] * a2v, s1 = c[1] * a2v, s2 = c[2] * a2v, s3 = c[3] * a2v;
      #pragma unroll
      for (int off = 1; off < 16; off <<= 1) {
        s0 += __shfl_xor(s0, off);
        s1 += __shfl_xor(s1, off);
        s2 += __shfl_xor(s2, off);
        s3 += __shfl_xor(s3, off);
      }
      #pragma unroll
      for (int r = 0; r < 4; ++r) {
        int node = n0 + rb + r;
        if (node < N) nsAll[(size_t)node * 256 + col] = f2bf(c[r]);
      }
      if (lr == 0) {
        float sa[4] = {s0, s1, s2, s3};
        #pragma unroll
        for (int r = 0; r < 4; ++r) {
          int node = n0 + rb + r;
          if (node < N) cdst[(size_t)node * NH + head] = sa[r];
        }
      }
    }
  }
}

// ---------------- edge GEMM: pure streaming ep = eft@W1 (bf16), nothing else ----------------
// 512 thr = 8 waves; 128 edges/block; wave: cols (w&3)*32..+31, rows (w>>2)*64..+63.
__global__ __launch_bounds__(512) void k_edge_mfma(
    const float* __restrict__ eft, const ushort* __restrict__ Wt1,
    ushort* __restrict__ ep, int E)
{
  __shared__ ushort x[128][136];   // A tile bf16; reused for C staging

  const int t = threadIdx.x;
  const int e0 = blockIdx.x * 128;

  // ---- stage eft -> bf16 LDS (sequential, coalesced) ----
  {
    int ei = t >> 2, q = t & 3;
    int e = min(e0 + ei, E - 1);
    const float* ef = eft + (size_t)e * FT;
    #pragma unroll
    for (int j = 0; j < 4; ++j) {
      int c = q * 32 + j * 8;
      float4 u = *(const float4*)&ef[c];
      float4 v = *(const float4*)&ef[c + 4];
      u16x8 pk;
      pk[0] = f2bf(u.x); pk[1] = f2bf(u.y); pk[2] = f2bf(u.z); pk[3] = f2bf(u.w);
      pk[4] = f2bf(v.x); pk[5] = f2bf(v.y); pk[6] = f2bf(v.z); pk[7] = f2bf(v.w);
      *(u16x8*)&x[ei][c] = pk;
    }
  }
  __syncthreads();

  const int w  = t >> 6;
  const int l  = t & 63;
  const int lr = l & 15;
  const int lk = l >> 4;
  const int wc = w & 3;        // col group: cols wc*32..+31
  const int wm = w >> 2;       // row group: rows wm*64..+63

  bf16x8 breg[4][2];
  const ushort* wb = Wt1 + ((size_t)(wc * 32 + lr) * 128 + lk * 8);
  #pragma unroll
  for (int ks = 0; ks < 4; ++ks) {
    breg[ks][0] = *(const bf16x8*)(wb + ks * 32);
    breg[ks][1] = *(const bf16x8*)(wb + 16 * 128 + ks * 32);
  }

  f32x4 acc[4][2];
  #pragma unroll
  for (int m = 0; m < 4; ++m) { acc[m][0] = 0.0f; acc[m][1] = 0.0f; }

  #pragma unroll
  for (int ks = 0; ks < 4; ++ks) {
    int kb = ks * 32 + lk * 8;
    #pragma unroll
    for (int m = 0; m < 4; ++m) {
      bf16x8 a = *(const bf16x8*)&x[wm * 64 + m * 16 + lr][kb];
      acc[m][0] = __builtin_amdgcn_mfma_f32_16x16x32_bf16(a, breg[ks][0], acc[m][0], 0, 0, 0);
      acc[m][1] = __builtin_amdgcn_mfma_f32_16x16x32_bf16(a, breg[ks][1], acc[m][1], 0, 0, 0);
    }
  }

  // ---- C staging into x (reuse), then coalesced global stores ----
  __syncthreads();   // all MFMA reads of x done
  #pragma unroll
  for (int ntl = 0; ntl < 2; ++ntl) {
    int col = wc * 32 + ntl * 16 + lr;
    #pragma unroll
    for (int m = 0; m < 4; ++m) {
      int rb = wm * 64 + m * 16 + lk * 4;
      f32x4 c = acc[m][ntl];
      x[rb + 0][col] = f2bf(c[0]);
      x[rb + 1][col] = f2bf(c[1]);
      x[rb + 2][col] = f2bf(c[2]);
      x[rb + 3][col] = f2bf(c[3]);
    }
  }
  __syncthreads();

  {
    int ei = t >> 2, q = t & 3;
    int e = e0 + ei;
    if (e < E) {
      #pragma unroll
      for (int j = 0; j < 4; ++j) {
        u16x8 vv = *(const u16x8*)&x[ei][q * 32 + j * 8];
        *(u16x8*)&ep[(size_t)e * FT + q * 32 + j * 8] = vv;
      }
    }
  }
}

// ---------------- aggregate: wave-per-node, online softmax, inline ce ----------------
// lane l: output cols 2l,2l+1; head hh=l>>3
__global__ __launch_bounds__(256) void k_aggregate(
    const ushort* __restrict__ ep, const ushort* __restrict__ nsAll,
    const float* __restrict__ a1c0, const float* __restrict__ c2n,
    const float* __restrict__ cb, const int* __restrict__ ptr,
    const int* __restrict__ sorted, const int* __restrict__ srcS,
    const float* __restrict__ at2, const float* __restrict__ bp,
    const float* __restrict__ nft, float* __restrict__ out, int N)
{
  int wid = (blockIdx.x * 256 + threadIdx.x) >> 6;
  int l = threadIdx.x & 63;
  if (wid >= N) return;
  int beg = ptr[wid], end = ptr[wid + 1];
  int hh = l >> 3;
  float at0 = at2[l * 2], at1 = at2[l * 2 + 1];
  float c2b = c2n[(size_t)wid * NH + hh] + cb[hh];

  float m = -INFINITY, s = 0.0f, a0 = 0.0f, a1 = 0.0f;
  for (int i = beg; i < end; ++i) {
    int e  = sorted[i];
    int se = srcS[i];
    unsigned pe = *(const unsigned*)&ep[(size_t)e * FT + l * 2];
    unsigned pn = *(const unsigned*)&nsAll[(size_t)se * 256 + l * 2];
    float e0f = __uint_as_float(pe << 16);
    float e1f = __uint_as_float(pe & 0xFFFF0000u);
    float n0f = __uint_as_float(pn << 16);
    float n1f = __uint_as_float(pn & 0xFFFF0000u);
    // ce = ew1 . attn2_head  (butterfly over the head's 8 lanes)
    float ce = e0f * at0 + e1f * at1;
    ce += __shfl_xor(ce, 1);
    ce += __shfl_xor(ce, 2);
    ce += __shfl_xor(ce, 4);
    float lin = a1c0[(size_t)se * NH + hh] + ce + c2b;
    float lv = lin > 0.0f ? lin : 0.01f * lin;
    float mn = fmaxf(m, lv);
    float corr = __expf(m - mn);
    float ev   = __expf(lv - mn);
    s  = s  * corr + ev;
    a0 = a0 * corr + ev * (e0f + n0f);
    a1 = a1 * corr + ev * (e1f + n1f);
    m = mn;
  }

  float2 nv = *(const float2*)&nft[(size_t)wid * FT + l * 2];
  float v0, v1;
  if (s > 0.0f) {
    float inv = 1.0f / s;
    unsigned pn2 = *(const unsigned*)&nsAll[(size_t)wid * 256 + 128 + l * 2];
    float2 bv = *(const float2*)&bp[l * 2];
    v0 = a0 * inv + __uint_as_float(pn2 << 16)         + bv.x + nv.x;
    v1 = a1 * inv + __uint_as_float(pn2 & 0xFFFF0000u) + bv.y + nv.y;
  } else {
    v0 = nv.x; v1 = nv.y;
  }
  float2 ov;
  ov.x = v0 > 0.0f ? v0 : 0.0f;
  ov.y = v1 > 0.0f ? v1 : 0.0f;
  *(float2*)&out[(size_t)wid * FT + l * 2] = ov;
}

extern "C" void kernel_launch(void* const* d_in, const int* in_sizes, int n_in,
                              void* d_out, int out_size, void* d_ws, size_t ws_size,
                              hipStream_t stream) {
  const float* nft = (const float*)d_in[0];
  const float* eft = (const float*)d_in[1];
  const float* Wp  = (const float*)d_in[2];
  const float* bp  = (const float*)d_in[3];
  const float* Wa1 = (const float*)d_in[4];
  const float* at2 = (const float*)d_in[5];
  const int*   src = (const int*)d_in[6];
  const int*   dst = (const int*)d_in[7];
  const int N = in_sizes[0] / FT;
  const int E = in_sizes[6];

  char* ws = (char*)d_ws;
  size_t off = 0;
  ushort* ep = (ushort*)(ws + off);    off += (size_t)E * FT * sizeof(ushort);
  off = (off + 255) & ~(size_t)255;
  ushort* Wt1 = (ushort*)(ws + off);   off += (size_t)128 * 128 * sizeof(ushort);
  ushort* WtN = (ushort*)(ws + off);   off += (size_t)256 * 128 * sizeof(ushort);
  off = (off + 255) & ~(size_t)255;
  float* a1c0 = (float*)(ws + off);    off += (size_t)N * NH * sizeof(float);
  float* c0n = (float*)(ws + off);     off += (size_t)N * NH * sizeof(float);
  float* c2n = (float*)(ws + off);     off += (size_t)N * NH * sizeof(float);
  float* cb = (float*)(ws + off);      off += 256;
  ushort* nsAll = (ushort*)(ws + off); off += (size_t)N * 256 * sizeof(ushort);
  off = (off + 255) & ~(size_t)255;
  int* cnt = (int*)(ws + off);         off += (size_t)N * sizeof(int);
  int* ptr = (int*)(ws + off);         off += (size_t)(N + 1) * sizeof(int);
  int* cur = (int*)(ws + off);         off += (size_t)N * sizeof(int);
  int* sorted = (int*)(ws + off);      off += (size_t)E * sizeof(int);
  int* srcS = (int*)(ws + off);        off += (size_t)E * sizeof(int);

  int setup_n = (256 * 128 > N ? 256 * 128 : N);
  k_setup<<<(setup_n + 255) / 256, 256, 0, stream>>>(Wp, bp, at2, Wt1, WtN, cb, cnt, N);
  k_hist<<<(E + 255) / 256, 256, 0, stream>>>(dst, cnt, E);
  k_scan<<<1, 1024, 0, stream>>>(cnt, ptr, cur, N);
  k_fill<<<(E + 255) / 256, 256, 0, stream>>>(dst, src, cur, sorted, srcS, E);

  k_node_mfma<<<(N + 63) / 64, 256, 0, stream>>>(nft, WtN, at2, nsAll, c0n, c2n, N);
  k_prep_a1<<<(N * NH + 255) / 256, 256, 0, stream>>>(nft, Wa1, c0n, a1c0, N);

  k_edge_mfma<<<(E + 127) / 128, 512, 0, stream>>>(eft, Wt1, ep, E);

  k_aggregate<<<(N * 64 + 255) / 256, 256, 0, stream>>>(ep, nsAll, a1c0, c2n, cb,
                                                        ptr, sorted, srcS, at2, bp,
                                                        nft, (float*)d_out, N);
}

// Round 7
// 195.998 us; speedup vs baseline: 4.2715x; 1.1697x over previous
//
#include <hip/hip_runtime.h>
#include <hip/hip_bf16.h>

#define FT 128
#define NH 8

typedef short bf16x8 __attribute__((ext_vector_type(8)));
typedef ushort u16x8 __attribute__((ext_vector_type(8)));
typedef float f32x4 __attribute__((ext_vector_type(4)));

__device__ __forceinline__ ushort f2bf(float f) {
  __hip_bfloat16 h = __float2bfloat16(f);
  return *reinterpret_cast<ushort*>(&h);
}
__device__ __forceinline__ float bf2f(ushort u) {
  return __uint_as_float(((unsigned)u) << 16);
}

// ---------------- setup: zero cnt + build Wt1/WtN (bf16 B-layout) + cb ----------------
__global__ void k_setup(const float* __restrict__ Wp, const float* __restrict__ bp,
                        const float* __restrict__ at2, ushort* __restrict__ Wt1,
                        ushort* __restrict__ WtN, float* __restrict__ cb,
                        int* __restrict__ cnt, int N) {
  int i = blockIdx.x * 256 + threadIdx.x;
  if (i < N) cnt[i] = 0;
  if (i < 128 * 128) {
    int c = i >> 7, k = i & 127;
    Wt1[i] = f2bf(Wp[(size_t)(128 + k) * 128 + c]);
  }
  if (i < 256 * 128) {
    int c = i >> 7, k = i & 127;
    float v = (c < 128) ? Wp[(size_t)k * 128 + c]
                        : Wp[(size_t)(256 + k) * 128 + (c - 128)];
    WtN[i] = f2bf(v);
  }
  if (i < NH) {
    float s = 0.0f;
    #pragma unroll
    for (int j = 0; j < 16; ++j) s += bp[i * 16 + j] * at2[i * 16 + j];
    cb[i] = s;
  }
}

// ---------------- CSR: histogram ----------------
__global__ void k_hist(const int* __restrict__ dst, int* __restrict__ cnt, int E) {
  int e = blockIdx.x * 256 + threadIdx.x;
  if (e < E) atomicAdd(&cnt[dst[e]], 1);
}

// ---------------- CSR: hierarchical scan ----------------
__global__ void k_scan1(const int* __restrict__ cnt, int* __restrict__ bsum, int N) {
  int i = blockIdx.x * 256 + threadIdx.x;
  int v = (i < N) ? cnt[i] : 0;
  #pragma unroll
  for (int o = 1; o < 64; o <<= 1) v += __shfl_xor(v, o);
  __shared__ int ws[4];
  if ((threadIdx.x & 63) == 0) ws[threadIdx.x >> 6] = v;
  __syncthreads();
  if (threadIdx.x == 0) bsum[blockIdx.x] = ws[0] + ws[1] + ws[2] + ws[3];
}

__global__ __launch_bounds__(1024) void k_scan2(const int* __restrict__ bsum,
                                                int* __restrict__ boff,
                                                int* __restrict__ ptr, int nb, int N) {
  __shared__ int buf[1024];
  int t = threadIdx.x;
  int v = (t < nb) ? bsum[t] : 0;
  buf[t] = v;
  __syncthreads();
  #pragma unroll
  for (int o = 1; o < 1024; o <<= 1) {
    int x = (t >= o) ? buf[t - o] : 0;
    __syncthreads();
    buf[t] += x;
    __syncthreads();
  }
  if (t < nb) boff[t] = buf[t] - v;
  if (t == nb - 1) ptr[N] = buf[t];
}

__global__ void k_scan3(const int* __restrict__ cnt, const int* __restrict__ boff,
                        int* __restrict__ ptr, int* __restrict__ cur, int N) {
  int i = blockIdx.x * 256 + threadIdx.x;
  int v = (i < N) ? cnt[i] : 0;
  int lane = threadIdx.x & 63, wv = threadIdx.x >> 6;
  int s = v;
  #pragma unroll
  for (int o = 1; o < 64; o <<= 1) {
    int x = __shfl_up(s, o);
    if (lane >= o) s += x;
  }
  __shared__ int wsum[4];
  if (lane == 63) wsum[wv] = s;
  __syncthreads();
  int add = 0;
  for (int k = 0; k < wv; ++k) add += wsum[k];
  int exc = boff[blockIdx.x] + add + s - v;
  if (i < N) { ptr[i] = exc; cur[i] = exc; }
}

// ---------------- CSR: fill sorted edge ids + src ----------------
__global__ void k_fill(const int* __restrict__ dst, const int* __restrict__ src,
                       int* __restrict__ cur, int* __restrict__ sorted,
                       int* __restrict__ srcS, int E) {
  int e = blockIdx.x * 256 + threadIdx.x;
  if (e < E) {
    int p = atomicAdd(&cur[dst[e]], 1);
    sorted[p] = e;
    srcS[p] = src[e];
  }
}

// ---------------- prep: a1n[n][h] = nft[n] . Wa1[:,h] ----------------
__global__ __launch_bounds__(256) void k_prep_a1(
    const float* __restrict__ nft, const float* __restrict__ Wa1,
    float* __restrict__ a1n, int N)
{
  __shared__ float w[FT * NH];
  int t = threadIdx.x;
  for (int i = t; i < FT * NH; i += 256) w[i] = Wa1[i];
  __syncthreads();
  int i = blockIdx.x * 256 + t;
  if (i >= N * NH) return;
  int node = i >> 3, h = i & 7;
  const float* xr = nft + (size_t)node * FT;
  float a = 0.0f;
  for (int k = 0; k < FT; k += 4) {
    float4 xv = *(const float4*)&xr[k];
    a = fmaf(xv.x, w[(k + 0) * NH + h], a);
    a = fmaf(xv.y, w[(k + 1) * NH + h], a);
    a = fmaf(xv.z, w[(k + 2) * NH + h], a);
    a = fmaf(xv.w, w[(k + 3) * NH + h], a);
  }
  a1n[i] = a;
}

// ---------------- node GEMM: nsAll = nft@[W0|W2] bf16; c2n = (ns2.*at2) head-sums ----------------
__global__ __launch_bounds__(256) void k_node_mfma(
    const float* __restrict__ nft, const ushort* __restrict__ WtN,
    const float* __restrict__ at2, ushort* __restrict__ nsAll,
    float* __restrict__ c2n, int N)
{
  __shared__ ushort x[64][136];
  const int t = threadIdx.x;
  const int n0 = blockIdx.x * 64;

  {
    int ei = t >> 2, q = t & 3;
    int n = min(n0 + ei, N - 1);
    const float* xr = nft + (size_t)n * FT;
    #pragma unroll
    for (int j = 0; j < 4; ++j) {
      int c = q * 32 + j * 8;
      float4 u = *(const float4*)&xr[c];
      float4 v = *(const float4*)&xr[c + 4];
      u16x8 pk;
      pk[0] = f2bf(u.x); pk[1] = f2bf(u.y); pk[2] = f2bf(u.z); pk[3] = f2bf(u.w);
      pk[4] = f2bf(v.x); pk[5] = f2bf(v.y); pk[6] = f2bf(v.z); pk[7] = f2bf(v.w);
      *(u16x8*)&x[ei][c] = pk;
    }
  }
  __syncthreads();

  const int w  = t >> 6;
  const int l  = t & 63;
  const int lr = l & 15;
  const int lk = l >> 4;

  bf16x8 breg[4][4];
  const ushort* wb = WtN + ((size_t)(w * 64 + lr) * 128 + lk * 8);
  #pragma unroll
  for (int ntl = 0; ntl < 4; ++ntl)
    #pragma unroll
    for (int ks = 0; ks < 4; ++ks)
      breg[ks][ntl] = *(const bf16x8*)(wb + (size_t)ntl * 16 * 128 + ks * 32);

  f32x4 acc[4][4];
  #pragma unroll
  for (int m = 0; m < 4; ++m)
    #pragma unroll
    for (int ntl = 0; ntl < 4; ++ntl) acc[m][ntl] = 0.0f;

  #pragma unroll
  for (int ks = 0; ks < 4; ++ks) {
    int kb = ks * 32 + lk * 8;
    #pragma unroll
    for (int m = 0; m < 4; ++m) {
      bf16x8 a = *(const bf16x8*)&x[m * 16 + lr][kb];
      #pragma unroll
      for (int ntl = 0; ntl < 4; ++ntl)
        acc[m][ntl] = __builtin_amdgcn_mfma_f32_16x16x32_bf16(a, breg[ks][ntl], acc[m][ntl], 0, 0, 0);
    }
  }

  #pragma unroll
  for (int ntl = 0; ntl < 4; ++ntl) {
    int col = w * 64 + ntl * 16 + lr;
    #pragma unroll
    for (int m = 0; m < 4; ++m) {
      int rb = m * 16 + lk * 4;
      f32x4 c = acc[m][ntl];
      #pragma unroll
      for (int r = 0; r < 4; ++r) {
        int node = n0 + rb + r;
        if (node < N) nsAll[(size_t)node * 256 + col] = f2bf(c[r]);
      }
      if (col >= 128) {   // c2n head-sums for the ns2 half only
        int head = (col & 127) >> 4;
        float a2v = at2[col & 127];
        float s0 = c[0] * a2v, s1 = c[1] * a2v, s2 = c[2] * a2v, s3 = c[3] * a2v;
        #pragma unroll
        for (int off = 1; off < 16; off <<= 1) {
          s0 += __shfl_xor(s0, off);
          s1 += __shfl_xor(s1, off);
          s2 += __shfl_xor(s2, off);
          s3 += __shfl_xor(s3, off);
        }
        if (lr == 0) {
          float sa[4] = {s0, s1, s2, s3};
          #pragma unroll
          for (int r = 0; r < 4; ++r) {
            int node = n0 + rb + r;
            if (node < N) c2n[(size_t)node * NH + head] = sa[r];
          }
        }
      }
    }
  }
}

// ---------------- edge GEMM (sorted order): eps[i] = eft[sorted[i]]@W1 + ns0[srcS[i]] ----------------
// 512 thr = 8 waves; 128 sorted positions/block; wave: cols (w&3)*32..+31, rows (w>>2)*64..+63.
__global__ __launch_bounds__(512) void k_edge_mfma(
    const float* __restrict__ eft, const ushort* __restrict__ Wt1,
    const ushort* __restrict__ nsAll, const int* __restrict__ sorted,
    const int* __restrict__ srcS, ushort* __restrict__ eps, int E)
{
  __shared__ ushort x[128][136];   // A tile bf16; reused for ns0 + C staging

  const int t = threadIdx.x;
  const int i0 = blockIdx.x * 128;

  const int ei = t >> 2, q = t & 3;
  const int ip = min(i0 + ei, E - 1);
  const int e  = sorted[ip];
  const int se = srcS[ip];

  // ---- stage gathered eft rows -> bf16 LDS ----
  {
    const float* ef = eft + (size_t)e * FT;
    #pragma unroll
    for (int j = 0; j < 4; ++j) {
      int c = q * 32 + j * 8;
      float4 u = *(const float4*)&ef[c];
      float4 v = *(const float4*)&ef[c + 4];
      u16x8 pk;
      pk[0] = f2bf(u.x); pk[1] = f2bf(u.y); pk[2] = f2bf(u.z); pk[3] = f2bf(u.w);
      pk[4] = f2bf(v.x); pk[5] = f2bf(v.y); pk[6] = f2bf(v.z); pk[7] = f2bf(v.w);
      *(u16x8*)&x[ei][c] = pk;
    }
  }
  __syncthreads();

  const int w  = t >> 6;
  const int l  = t & 63;
  const int lr = l & 15;
  const int lk = l >> 4;
  const int wc = w & 3;
  const int wm = w >> 2;

  bf16x8 breg[4][2];
  const ushort* wb = Wt1 + ((size_t)(wc * 32 + lr) * 128 + lk * 8);
  #pragma unroll
  for (int ks = 0; ks < 4; ++ks) {
    breg[ks][0] = *(const bf16x8*)(wb + ks * 32);
    breg[ks][1] = *(const bf16x8*)(wb + 16 * 128 + ks * 32);
  }

  f32x4 acc[4][2];
  #pragma unroll
  for (int m = 0; m < 4; ++m) { acc[m][0] = 0.0f; acc[m][1] = 0.0f; }

  #pragma unroll
  for (int ks = 0; ks < 4; ++ks) {
    int kb = ks * 32 + lk * 8;
    #pragma unroll
    for (int m = 0; m < 4; ++m) {
      bf16x8 a = *(const bf16x8*)&x[wm * 64 + m * 16 + lr][kb];
      acc[m][0] = __builtin_amdgcn_mfma_f32_16x16x32_bf16(a, breg[ks][0], acc[m][0], 0, 0, 0);
      acc[m][1] = __builtin_amdgcn_mfma_f32_16x16x32_bf16(a, breg[ks][1], acc[m][1], 0, 0, 0);
    }
  }

  // ---- overwrite x with gathered ns0 rows ----
  __syncthreads();   // all MFMA reads of x done
  {
    const ushort* r0 = nsAll + (size_t)se * 256 + q * 32;
    #pragma unroll
    for (int j = 0; j < 4; ++j)
      *(u16x8*)&x[ei][q * 32 + j * 8] = *(const u16x8*)(r0 + j * 8);
  }
  __syncthreads();

  // ---- C staging: x <- bf16(acc + ns0)  (each cell owned by one thread) ----
  #pragma unroll
  for (int ntl = 0; ntl < 2; ++ntl) {
    int col = wc * 32 + ntl * 16 + lr;
    #pragma unroll
    for (int m = 0; m < 4; ++m) {
      int rb = wm * 64 + m * 16 + lk * 4;
      f32x4 c = acc[m][ntl];
      x[rb + 0][col] = f2bf(c[0] + bf2f(x[rb + 0][col]));
      x[rb + 1][col] = f2bf(c[1] + bf2f(x[rb + 1][col]));
      x[rb + 2][col] = f2bf(c[2] + bf2f(x[rb + 2][col]));
      x[rb + 3][col] = f2bf(c[3] + bf2f(x[rb + 3][col]));
    }
  }
  __syncthreads();

  // ---- coalesced store at SORTED position ----
  {
    int i = i0 + ei;
    if (i < E) {
      #pragma unroll
      for (int j = 0; j < 4; ++j) {
        u16x8 vv = *(const u16x8*)&x[ei][q * 32 + j * 8];
        *(u16x8*)&eps[(size_t)i * FT + q * 32 + j * 8] = vv;
      }
    }
  }
}

// ---------------- aggregate: wave-per-node, sequential eps stream ----------------
__global__ __launch_bounds__(256) void k_aggregate(
    const ushort* __restrict__ eps, const ushort* __restrict__ nsAll,
    const float* __restrict__ a1n, const float* __restrict__ c2n,
    const float* __restrict__ cb, const int* __restrict__ ptr,
    const int* __restrict__ srcS, const float* __restrict__ at2,
    const float* __restrict__ bp, const float* __restrict__ nft,
    float* __restrict__ out, int N)
{
  int wid = (blockIdx.x * 256 + threadIdx.x) >> 6;
  int l = threadIdx.x & 63;
  if (wid >= N) return;
  int beg = ptr[wid], end = ptr[wid + 1];
  int hh = l >> 3;
  float at0 = at2[l * 2], at1 = at2[l * 2 + 1];
  float c2b = c2n[(size_t)wid * NH + hh] + cb[hh];

  float m = -INFINITY, s = 0.0f, a0 = 0.0f, a1 = 0.0f;
  for (int i = beg; i < end; ++i) {
    int se = srcS[i];
    unsigned pe = *(const unsigned*)&eps[(size_t)i * FT + l * 2];
    float e0f = __uint_as_float(pe << 16);
    float e1f = __uint_as_float(pe & 0xFFFF0000u);
    float ce = e0f * at0 + e1f * at1;
    ce += __shfl_xor(ce, 1);
    ce += __shfl_xor(ce, 2);
    ce += __shfl_xor(ce, 4);
    float lin = a1n[(size_t)se * NH + hh] + ce + c2b;
    float lv = lin > 0.0f ? lin : 0.01f * lin;
    float mn = fmaxf(m, lv);
    float corr = __expf(m - mn);
    float ev   = __expf(lv - mn);
    s  = s  * corr + ev;
    a0 = a0 * corr + ev * e0f;
    a1 = a1 * corr + ev * e1f;
    m = mn;
  }

  float2 nv = *(const float2*)&nft[(size_t)wid * FT + l * 2];
  float v0, v1;
  if (s > 0.0f) {
    float inv = 1.0f / s;
    unsigned pn2 = *(const unsigned*)&nsAll[(size_t)wid * 256 + 128 + l * 2];
    float2 bv = *(const float2*)&bp[l * 2];
    v0 = a0 * inv + __uint_as_float(pn2 << 16)         + bv.x + nv.x;
    v1 = a1 * inv + __uint_as_float(pn2 & 0xFFFF0000u) + bv.y + nv.y;
  } else {
    v0 = nv.x; v1 = nv.y;
  }
  float2 ov;
  ov.x = v0 > 0.0f ? v0 : 0.0f;
  ov.y = v1 > 0.0f ? v1 : 0.0f;
  *(float2*)&out[(size_t)wid * FT + l * 2] = ov;
}

extern "C" void kernel_launch(void* const* d_in, const int* in_sizes, int n_in,
                              void* d_out, int out_size, void* d_ws, size_t ws_size,
                              hipStream_t stream) {
  const float* nft = (const float*)d_in[0];
  const float* eft = (const float*)d_in[1];
  const float* Wp  = (const float*)d_in[2];
  const float* bp  = (const float*)d_in[3];
  const float* Wa1 = (const float*)d_in[4];
  const float* at2 = (const float*)d_in[5];
  const int*   src = (const int*)d_in[6];
  const int*   dst = (const int*)d_in[7];
  const int N = in_sizes[0] / FT;
  const int E = in_sizes[6];
  const int nb = (N + 255) / 256;

  char* ws = (char*)d_ws;
  size_t off = 0;
  ushort* eps = (ushort*)(ws + off);   off += (size_t)E * FT * sizeof(ushort);
  off = (off + 255) & ~(size_t)255;
  ushort* Wt1 = (ushort*)(ws + off);   off += (size_t)128 * 128 * sizeof(ushort);
  ushort* WtN = (ushort*)(ws + off);   off += (size_t)256 * 128 * sizeof(ushort);
  off = (off + 255) & ~(size_t)255;
  float* a1n = (float*)(ws + off);     off += (size_t)N * NH * sizeof(float);
  float* c2n = (float*)(ws + off);     off += (size_t)N * NH * sizeof(float);
  float* cb = (float*)(ws + off);      off += 256;
  ushort* nsAll = (ushort*)(ws + off); off += (size_t)N * 256 * sizeof(ushort);
  off = (off + 255) & ~(size_t)255;
  int* cnt = (int*)(ws + off);         off += (size_t)N * sizeof(int);
  int* ptr = (int*)(ws + off);         off += (size_t)(N + 1) * sizeof(int);
  int* cur = (int*)(ws + off);         off += (size_t)N * sizeof(int);
  int* bsum = (int*)(ws + off);        off += (size_t)nb * sizeof(int);
  int* boff = (int*)(ws + off);        off += (size_t)nb * sizeof(int);
  int* sorted = (int*)(ws + off);      off += (size_t)E * sizeof(int);
  int* srcS = (int*)(ws + off);        off += (size_t)E * sizeof(int);

  int setup_n = (256 * 128 > N ? 256 * 128 : N);
  k_setup<<<(setup_n + 255) / 256, 256, 0, stream>>>(Wp, bp, at2, Wt1, WtN, cb, cnt, N);
  k_hist<<<(E + 255) / 256, 256, 0, stream>>>(dst, cnt, E);
  k_scan1<<<nb, 256, 0, stream>>>(cnt, bsum, N);
  k_scan2<<<1, 1024, 0, stream>>>(bsum, boff, ptr, nb, N);
  k_scan3<<<nb, 256, 0, stream>>>(cnt, boff, ptr, cur, N);
  k_fill<<<(E + 255) / 256, 256, 0, stream>>>(dst, src, cur, sorted, srcS, E);

  k_node_mfma<<<(N + 63) / 64, 256, 0, stream>>>(nft, WtN, at2, nsAll, c2n, N);
  k_prep_a1<<<(N * NH + 255) / 256, 256, 0, stream>>>(nft, Wa1, a1n, N);

  k_edge_mfma<<<(E + 127) / 128, 512, 0, stream>>>(eft, Wt1, nsAll, sorted, srcS, eps, E);

  k_aggregate<<<(N * 64 + 255) / 256, 256, 0, stream>>>(eps, nsAll, a1n, c2n, cb,
                                                        ptr, srcS, at2, bp,
                                                        nft, (float*)d_out, N);
}

// Round 9
// 187.505 us; speedup vs baseline: 4.4650x; 1.0453x over previous
//
#include <hip/hip_runtime.h>
#include <hip/hip_bf16.h>

#define FT 128
#define NH 8

typedef short bf16x8 __attribute__((ext_vector_type(8)));
typedef ushort u16x8 __attribute__((ext_vector_type(8)));
typedef float f32x4 __attribute__((ext_vector_type(4)));

__device__ __forceinline__ ushort f2bf(float f) {
  __hip_bfloat16 h = __float2bfloat16(f);
  return *reinterpret_cast<ushort*>(&h);
}
__device__ __forceinline__ float bf2f(ushort u) {
  return __uint_as_float(((unsigned)u) << 16);
}

// ---------------- setup: zero cnt + build Wt1/WtN (bf16 B-layout) + cb ----------------
__global__ void k_setup(const float* __restrict__ Wp, const float* __restrict__ bp,
                        const float* __restrict__ at2, ushort* __restrict__ Wt1,
                        ushort* __restrict__ WtN, float* __restrict__ cb,
                        int* __restrict__ cnt, int N) {
  int i = blockIdx.x * 256 + threadIdx.x;
  if (i < N) cnt[i] = 0;
  if (i < 128 * 128) {
    int c = i >> 7, k = i & 127;
    Wt1[i] = f2bf(Wp[(size_t)(128 + k) * 128 + c]);
  }
  if (i < 256 * 128) {
    int c = i >> 7, k = i & 127;
    float v = (c < 128) ? Wp[(size_t)k * 128 + c]
                        : Wp[(size_t)(256 + k) * 128 + (c - 128)];
    WtN[i] = f2bf(v);
  }
  if (i < NH) {
    float s = 0.0f;
    #pragma unroll
    for (int j = 0; j < 16; ++j) s += bp[i * 16 + j] * at2[i * 16 + j];
    cb[i] = s;
  }
}

// ---------------- CSR: histogram ----------------
__global__ void k_hist(const int* __restrict__ dst, int* __restrict__ cnt, int E) {
  int e = blockIdx.x * 256 + threadIdx.x;
  if (e < E) atomicAdd(&cnt[dst[e]], 1);
}

// ---------------- CSR: hierarchical scan ----------------
__global__ void k_scan1(const int* __restrict__ cnt, int* __restrict__ bsum, int N) {
  int i = blockIdx.x * 256 + threadIdx.x;
  int v = (i < N) ? cnt[i] : 0;
  #pragma unroll
  for (int o = 1; o < 64; o <<= 1) v += __shfl_xor(v, o);
  __shared__ int ws[4];
  if ((threadIdx.x & 63) == 0) ws[threadIdx.x >> 6] = v;
  __syncthreads();
  if (threadIdx.x == 0) bsum[blockIdx.x] = ws[0] + ws[1] + ws[2] + ws[3];
}

__global__ __launch_bounds__(1024) void k_scan2(const int* __restrict__ bsum,
                                                int* __restrict__ boff,
                                                int* __restrict__ ptr, int nb, int N) {
  __shared__ int buf[1024];
  int t = threadIdx.x;
  int v = (t < nb) ? bsum[t] : 0;
  buf[t] = v;
  __syncthreads();
  #pragma unroll
  for (int o = 1; o < 1024; o <<= 1) {
    int x = (t >= o) ? buf[t - o] : 0;
    __syncthreads();
    buf[t] += x;
    __syncthreads();
  }
  if (t < nb) boff[t] = buf[t] - v;
  if (t == nb - 1) ptr[N] = buf[t];
}

__global__ void k_scan3(const int* __restrict__ cnt, const int* __restrict__ boff,
                        int* __restrict__ ptr, int* __restrict__ cur, int N) {
  int i = blockIdx.x * 256 + threadIdx.x;
  int v = (i < N) ? cnt[i] : 0;
  int lane = threadIdx.x & 63, wv = threadIdx.x >> 6;
  int s = v;
  #pragma unroll
  for (int o = 1; o < 64; o <<= 1) {
    int x = __shfl_up(s, o);
    if (lane >= o) s += x;
  }
  __shared__ int wsum[4];
  if (lane == 63) wsum[wv] = s;
  __syncthreads();
  int add = 0;
  for (int k = 0; k < wv; ++k) add += wsum[k];
  int exc = boff[blockIdx.x] + add + s - v;
  if (i < N) { ptr[i] = exc; cur[i] = exc; }
}

// ---------------- CSR: fill inverse permutation pos + sorted src ----------------
__global__ void k_fill(const int* __restrict__ dst, const int* __restrict__ src,
                       int* __restrict__ cur, int* __restrict__ pos,
                       int* __restrict__ srcS, int E) {
  int e = blockIdx.x * 256 + threadIdx.x;
  if (e < E) {
    int p = atomicAdd(&cur[dst[e]], 1);
    pos[e] = p;
    srcS[p] = src[e];
  }
}

// ---------------- prep: a1n[n][h] = nft[n] . Wa1[:,h] ----------------
__global__ __launch_bounds__(256) void k_prep_a1(
    const float* __restrict__ nft, const float* __restrict__ Wa1,
    float* __restrict__ a1n, int N)
{
  __shared__ float w[FT * NH];
  int t = threadIdx.x;
  for (int i = t; i < FT * NH; i += 256) w[i] = Wa1[i];
  __syncthreads();
  int i = blockIdx.x * 256 + t;
  if (i >= N * NH) return;
  int node = i >> 3, h = i & 7;
  const float* xr = nft + (size_t)node * FT;
  float a = 0.0f;
  for (int k = 0; k < FT; k += 4) {
    float4 xv = *(const float4*)&xr[k];
    a = fmaf(xv.x, w[(k + 0) * NH + h], a);
    a = fmaf(xv.y, w[(k + 1) * NH + h], a);
    a = fmaf(xv.z, w[(k + 2) * NH + h], a);
    a = fmaf(xv.w, w[(k + 3) * NH + h], a);
  }
  a1n[i] = a;
}

// ---------------- node GEMM: nsAll = nft@[W0|W2] bf16; c2n = (ns2.*at2) head-sums ----------------
__global__ __launch_bounds__(256) void k_node_mfma(
    const float* __restrict__ nft, const ushort* __restrict__ WtN,
    const float* __restrict__ at2, ushort* __restrict__ nsAll,
    float* __restrict__ c2n, int N)
{
  __shared__ ushort x[64][136];
  const int t = threadIdx.x;
  const int n0 = blockIdx.x * 64;

  {
    int ei = t >> 2, q = t & 3;
    int n = min(n0 + ei, N - 1);
    const float* xr = nft + (size_t)n * FT;
    #pragma unroll
    for (int j = 0; j < 4; ++j) {
      int c = q * 32 + j * 8;
      float4 u = *(const float4*)&xr[c];
      float4 v = *(const float4*)&xr[c + 4];
      u16x8 pk;
      pk[0] = f2bf(u.x); pk[1] = f2bf(u.y); pk[2] = f2bf(u.z); pk[3] = f2bf(u.w);
      pk[4] = f2bf(v.x); pk[5] = f2bf(v.y); pk[6] = f2bf(v.z); pk[7] = f2bf(v.w);
      *(u16x8*)&x[ei][c] = pk;
    }
  }
  __syncthreads();

  const int w  = t >> 6;
  const int l  = t & 63;
  const int lr = l & 15;
  const int lk = l >> 4;

  bf16x8 breg[4][4];
  const ushort* wb = WtN + ((size_t)(w * 64 + lr) * 128 + lk * 8);
  #pragma unroll
  for (int ntl = 0; ntl < 4; ++ntl)
    #pragma unroll
    for (int ks = 0; ks < 4; ++ks)
      breg[ks][ntl] = *(const bf16x8*)(wb + (size_t)ntl * 16 * 128 + ks * 32);

  f32x4 acc[4][4];
  #pragma unroll
  for (int m = 0; m < 4; ++m)
    #pragma unroll
    for (int ntl = 0; ntl < 4; ++ntl) acc[m][ntl] = 0.0f;

  #pragma unroll
  for (int ks = 0; ks < 4; ++ks) {
    int kb = ks * 32 + lk * 8;
    #pragma unroll
    for (int m = 0; m < 4; ++m) {
      bf16x8 a = *(const bf16x8*)&x[m * 16 + lr][kb];
      #pragma unroll
      for (int ntl = 0; ntl < 4; ++ntl)
        acc[m][ntl] = __builtin_amdgcn_mfma_f32_16x16x32_bf16(a, breg[ks][ntl], acc[m][ntl], 0, 0, 0);
    }
  }

  #pragma unroll
  for (int ntl = 0; ntl < 4; ++ntl) {
    int col = w * 64 + ntl * 16 + lr;
    #pragma unroll
    for (int m = 0; m < 4; ++m) {
      int rb = m * 16 + lk * 4;
      f32x4 c = acc[m][ntl];
      #pragma unroll
      for (int r = 0; r < 4; ++r) {
        int node = n0 + rb + r;
        if (node < N) nsAll[(size_t)node * 256 + col] = f2bf(c[r]);
      }
      if (col >= 128) {   // c2n head-sums for the ns2 half only
        int head = (col & 127) >> 4;
        float a2v = at2[col & 127];
        float s0 = c[0] * a2v, s1 = c[1] * a2v, s2 = c[2] * a2v, s3 = c[3] * a2v;
        #pragma unroll
        for (int off = 1; off < 16; off <<= 1) {
          s0 += __shfl_xor(s0, off);
          s1 += __shfl_xor(s1, off);
          s2 += __shfl_xor(s2, off);
          s3 += __shfl_xor(s3, off);
        }
        if (lr == 0) {
          float sa[4] = {s0, s1, s2, s3};
          #pragma unroll
          for (int r = 0; r < 4; ++r) {
            int node = n0 + rb + r;
            if (node < N) c2n[(size_t)node * NH + head] = sa[r];
          }
        }
      }
    }
  }
}

// ---------------- edge GEMM (ORIGINAL order, scatter-store): eps[pos[e]] = eft[e]@W1 + ns0[src[e]] ----------------
// 512 thr = 8 waves; 128 edges/block; wave: cols (w&3)*32..+31, rows (w>>2)*64..+63.
__global__ __launch_bounds__(512) void k_edge_mfma(
    const float* __restrict__ eft, const ushort* __restrict__ Wt1,
    const ushort* __restrict__ nsAll, const int* __restrict__ src,
    const int* __restrict__ pos, ushort* __restrict__ eps, int E)
{
  __shared__ ushort x[128][136];   // A tile bf16; reused for ns0 + C staging

  const int t = threadIdx.x;
  const int e0 = blockIdx.x * 128;

  const int ei = t >> 2, q = t & 3;
  const int eg = e0 + ei;
  const int ec = min(eg, E - 1);
  const int se = src[ec];          // sequential read
  const int pe = pos[ec];          // sequential read

  // ---- stage eft rows -> bf16 LDS (SEQUENTIAL, coalesced stream) ----
  {
    const float* ef = eft + (size_t)ec * FT;
    #pragma unroll
    for (int j = 0; j < 4; ++j) {
      int c = q * 32 + j * 8;
      float4 u = *(const float4*)&ef[c];
      float4 v = *(const float4*)&ef[c + 4];
      u16x8 pk;
      pk[0] = f2bf(u.x); pk[1] = f2bf(u.y); pk[2] = f2bf(u.z); pk[3] = f2bf(u.w);
      pk[4] = f2bf(v.x); pk[5] = f2bf(v.y); pk[6] = f2bf(v.z); pk[7] = f2bf(v.w);
      *(u16x8*)&x[ei][c] = pk;
    }
  }
  __syncthreads();

  const int w  = t >> 6;
  const int l  = t & 63;
  const int lr = l & 15;
  const int lk = l >> 4;
  const int wc = w & 3;
  const int wm = w >> 2;

  bf16x8 breg[4][2];
  const ushort* wb = Wt1 + ((size_t)(wc * 32 + lr) * 128 + lk * 8);
  #pragma unroll
  for (int ks = 0; ks < 4; ++ks) {
    breg[ks][0] = *(const bf16x8*)(wb + ks * 32);
    breg[ks][1] = *(const bf16x8*)(wb + 16 * 128 + ks * 32);
  }

  f32x4 acc[4][2];
  #pragma unroll
  for (int m = 0; m < 4; ++m) { acc[m][0] = 0.0f; acc[m][1] = 0.0f; }

  #pragma unroll
  for (int ks = 0; ks < 4; ++ks) {
    int kb = ks * 32 + lk * 8;
    #pragma unroll
    for (int m = 0; m < 4; ++m) {
      bf16x8 a = *(const bf16x8*)&x[wm * 64 + m * 16 + lr][kb];
      acc[m][0] = __builtin_amdgcn_mfma_f32_16x16x32_bf16(a, breg[ks][0], acc[m][0], 0, 0, 0);
      acc[m][1] = __builtin_amdgcn_mfma_f32_16x16x32_bf16(a, breg[ks][1], acc[m][1], 0, 0, 0);
    }
  }

  // ---- overwrite x with gathered ns0 rows (L2-resident 10 MB table) ----
  __syncthreads();   // all MFMA reads of x done
  {
    const ushort* r0 = nsAll + (size_t)se * 256 + q * 32;
    #pragma unroll
    for (int j = 0; j < 4; ++j)
      *(u16x8*)&x[ei][q * 32 + j * 8] = *(const u16x8*)(r0 + j * 8);
  }
  __syncthreads();

  // ---- C staging: x <- bf16(acc + ns0)  (each cell owned by one thread) ----
  #pragma unroll
  for (int ntl = 0; ntl < 2; ++ntl) {
    int col = wc * 32 + ntl * 16 + lr;
    #pragma unroll
    for (int m = 0; m < 4; ++m) {
      int rb = wm * 64 + m * 16 + lk * 4;
      f32x4 c = acc[m][ntl];
      x[rb + 0][col] = f2bf(c[0] + bf2f(x[rb + 0][col]));
      x[rb + 1][col] = f2bf(c[1] + bf2f(x[rb + 1][col]));
      x[rb + 2][col] = f2bf(c[2] + bf2f(x[rb + 2][col]));
      x[rb + 3][col] = f2bf(c[3] + bf2f(x[rb + 3][col]));
    }
  }
  __syncthreads();

  // ---- scatter store at sorted position pos[e] (fire-and-forget) ----
  if (eg < E) {
    #pragma unroll
    for (int j = 0; j < 4; ++j) {
      u16x8 vv = *(const u16x8*)&x[ei][q * 32 + j * 8];
      *(u16x8*)&eps[(size_t)pe * FT + q * 32 + j * 8] = vv;
    }
  }
}

// ---------------- aggregate: wave-per-node, sequential eps stream ----------------
__global__ __launch_bounds__(256) void k_aggregate(
    const ushort* __restrict__ eps, const ushort* __restrict__ nsAll,
    const float* __restrict__ a1n, const float* __restrict__ c2n,
    const float* __restrict__ cb, const int* __restrict__ ptr,
    const int* __restrict__ srcS, const float* __restrict__ at2,
    const float* __restrict__ bp, const float* __restrict__ nft,
    float* __restrict__ out, int N)
{
  int wid = (blockIdx.x * 256 + threadIdx.x) >> 6;
  int l = threadIdx.x & 63;
  if (wid >= N) return;
  int beg = ptr[wid], end = ptr[wid + 1];
  int hh = l >> 3;
  float at0 = at2[l * 2], at1 = at2[l * 2 + 1];
  float c2b = c2n[(size_t)wid * NH + hh] + cb[hh];

  float m = -INFINITY, s = 0.0f, a0 = 0.0f, a1 = 0.0f;
  for (int i = beg; i < end; ++i) {
    int se = srcS[i];
    unsigned pe = *(const unsigned*)&eps[(size_t)i * FT + l * 2];
    float e0f = __uint_as_float(pe << 16);
    float e1f = __uint_as_float(pe & 0xFFFF0000u);
    float ce = e0f * at0 + e1f * at1;
    ce += __shfl_xor(ce, 1);
    ce += __shfl_xor(ce, 2);
    ce += __shfl_xor(ce, 4);
    float lin = a1n[(size_t)se * NH + hh] + ce + c2b;
    float lv = lin > 0.0f ? lin : 0.01f * lin;
    float mn = fmaxf(m, lv);
    float corr = __expf(m - mn);
    float ev   = __expf(lv - mn);
    s  = s  * corr + ev;
    a0 = a0 * corr + ev * e0f;
    a1 = a1 * corr + ev * e1f;
    m = mn;
  }

  float2 nv = *(const float2*)&nft[(size_t)wid * FT + l * 2];
  float v0, v1;
  if (s > 0.0f) {
    float inv = 1.0f / s;
    unsigned pn2 = *(const unsigned*)&nsAll[(size_t)wid * 256 + 128 + l * 2];
    float2 bv = *(const float2*)&bp[l * 2];
    v0 = a0 * inv + __uint_as_float(pn2 << 16)         + bv.x + nv.x;
    v1 = a1 * inv + __uint_as_float(pn2 & 0xFFFF0000u) + bv.y + nv.y;
  } else {
    v0 = nv.x; v1 = nv.y;
  }
  float2 ov;
  ov.x = v0 > 0.0f ? v0 : 0.0f;
  ov.y = v1 > 0.0f ? v1 : 0.0f;
  *(float2*)&out[(size_t)wid * FT + l * 2] = ov;
}

extern "C" void kernel_launch(void* const* d_in, const int* in_sizes, int n_in,
                              void* d_out, int out_size, void* d_ws, size_t ws_size,
                              hipStream_t stream) {
  const float* nft = (const float*)d_in[0];
  const float* eft = (const float*)d_in[1];
  const float* Wp  = (const float*)d_in[2];
  const float* bp  = (const float*)d_in[3];
  const float* Wa1 = (const float*)d_in[4];
  const float* at2 = (const float*)d_in[5];
  const int*   src = (const int*)d_in[6];
  const int*   dst = (const int*)d_in[7];
  const int N = in_sizes[0] / FT;
  const int E = in_sizes[6];
  const int nb = (N + 255) / 256;

  char* ws = (char*)d_ws;
  size_t off = 0;
  ushort* eps = (ushort*)(ws + off);   off += (size_t)E * FT * sizeof(ushort);
  off = (off + 255) & ~(size_t)255;
  ushort* Wt1 = (ushort*)(ws + off);   off += (size_t)128 * 128 * sizeof(ushort);
  ushort* WtN = (ushort*)(ws + off);   off += (size_t)256 * 128 * sizeof(ushort);
  off = (off + 255) & ~(size_t)255;
  float* a1n = (float*)(ws + off);     off += (size_t)N * NH * sizeof(float);
  float* c2n = (float*)(ws + off);     off += (size_t)N * NH * sizeof(float);
  float* cb = (float*)(ws + off);      off += 256;
  ushort* nsAll = (ushort*)(ws + off); off += (size_t)N * 256 * sizeof(ushort);
  off = (off + 255) & ~(size_t)255;
  int* cnt = (int*)(ws + off);         off += (size_t)N * sizeof(int);
  int* ptr = (int*)(ws + off);         off += (size_t)(N + 1) * sizeof(int);
  int* cur = (int*)(ws + off);         off += (size_t)N * sizeof(int);
  int* bsum = (int*)(ws + off);        off += (size_t)nb * sizeof(int);
  int* boff = (int*)(ws + off);        off += (size_t)nb * sizeof(int);
  int* pos = (int*)(ws + off);         off += (size_t)E * sizeof(int);
  int* srcS = (int*)(ws + off);        off += (size_t)E * sizeof(int);

  int setup_n = (256 * 128 > N ? 256 * 128 : N);
  k_setup<<<(setup_n + 255) / 256, 256, 0, stream>>>(Wp, bp, at2, Wt1, WtN, cb, cnt, N);
  k_hist<<<(E + 255) / 256, 256, 0, stream>>>(dst, cnt, E);
  k_scan1<<<nb, 256, 0, stream>>>(cnt, bsum, N);
  k_scan2<<<1, 1024, 0, stream>>>(bsum, boff, ptr, nb, N);
  k_scan3<<<nb, 256, 0, stream>>>(cnt, boff, ptr, cur, N);
  k_fill<<<(E + 255) / 256, 256, 0, stream>>>(dst, src, cur, pos, srcS, E);

  k_node_mfma<<<(N + 63) / 64, 256, 0, stream>>>(nft, WtN, at2, nsAll, c2n, N);
  k_prep_a1<<<(N * NH + 255) / 256, 256, 0, stream>>>(nft, Wa1, a1n, N);

  k_edge_mfma<<<(E + 127) / 128, 512, 0, stream>>>(eft, Wt1, nsAll, src, pos, eps, E);

  k_aggregate<<<(N * 64 + 255) / 256, 256, 0, stream>>>(eps, nsAll, a1n, c2n, cb,
                                                        ptr, srcS, at2, bp,
                                                        nft, (float*)d_out, N);
}

// Round 10
// 187.328 us; speedup vs baseline: 4.4692x; 1.0009x over previous
//
#include <hip/hip_runtime.h>
#include <hip/hip_bf16.h>

#define FT 128
#define NH 8

typedef short bf16x8 __attribute__((ext_vector_type(8)));
typedef ushort u16x8 __attribute__((ext_vector_type(8)));
typedef float f32x4 __attribute__((ext_vector_type(4)));

__device__ __forceinline__ ushort f2bf(float f) {
  __hip_bfloat16 h = __float2bfloat16(f);
  return *reinterpret_cast<ushort*>(&h);
}
__device__ __forceinline__ float bf2f(ushort u) {
  return __uint_as_float(((unsigned)u) << 16);
}

// ---------------- setup: zero cnt + build Wt1/WtN (bf16 B-layout) + cb ----------------
__global__ void k_setup(const float* __restrict__ Wp, const float* __restrict__ bp,
                        const float* __restrict__ at2, ushort* __restrict__ Wt1,
                        ushort* __restrict__ WtN, float* __restrict__ cb,
                        int* __restrict__ cnt, int N) {
  int i = blockIdx.x * 256 + threadIdx.x;
  if (i < N) cnt[i] = 0;
  if (i < 128 * 128) {
    int c = i >> 7, k = i & 127;
    Wt1[i] = f2bf(Wp[(size_t)(128 + k) * 128 + c]);
  }
  if (i < 256 * 128) {
    int c = i >> 7, k = i & 127;
    float v = (c < 128) ? Wp[(size_t)k * 128 + c]
                        : Wp[(size_t)(256 + k) * 128 + (c - 128)];
    WtN[i] = f2bf(v);
  }
  if (i < NH) {
    float s = 0.0f;
    #pragma unroll
    for (int j = 0; j < 16; ++j) s += bp[i * 16 + j] * at2[i * 16 + j];
    cb[i] = s;
  }
}

// ---------------- CSR: histogram ----------------
__global__ void k_hist(const int* __restrict__ dst, int* __restrict__ cnt, int E) {
  int e = blockIdx.x * 256 + threadIdx.x;
  if (e < E) atomicAdd(&cnt[dst[e]], 1);
}

// ---------------- CSR: hierarchical scan ----------------
__global__ void k_scan1(const int* __restrict__ cnt, int* __restrict__ bsum, int N) {
  int i = blockIdx.x * 256 + threadIdx.x;
  int v = (i < N) ? cnt[i] : 0;
  #pragma unroll
  for (int o = 1; o < 64; o <<= 1) v += __shfl_xor(v, o);
  __shared__ int ws[4];
  if ((threadIdx.x & 63) == 0) ws[threadIdx.x >> 6] = v;
  __syncthreads();
  if (threadIdx.x == 0) bsum[blockIdx.x] = ws[0] + ws[1] + ws[2] + ws[3];
}

__global__ __launch_bounds__(1024) void k_scan2(const int* __restrict__ bsum,
                                                int* __restrict__ boff,
                                                int* __restrict__ ptr, int nb, int N) {
  __shared__ int buf[1024];
  int t = threadIdx.x;
  int v = (t < nb) ? bsum[t] : 0;
  buf[t] = v;
  __syncthreads();
  #pragma unroll
  for (int o = 1; o < 1024; o <<= 1) {
    int x = (t >= o) ? buf[t - o] : 0;
    __syncthreads();
    buf[t] += x;
    __syncthreads();
  }
  if (t < nb) boff[t] = buf[t] - v;
  if (t == nb - 1) ptr[N] = buf[t];
}

__global__ void k_scan3(const int* __restrict__ cnt, const int* __restrict__ boff,
                        int* __restrict__ ptr, int* __restrict__ cur, int N) {
  int i = blockIdx.x * 256 + threadIdx.x;
  int v = (i < N) ? cnt[i] : 0;
  int lane = threadIdx.x & 63, wv = threadIdx.x >> 6;
  int s = v;
  #pragma unroll
  for (int o = 1; o < 64; o <<= 1) {
    int x = __shfl_up(s, o);
    if (lane >= o) s += x;
  }
  __shared__ int wsum[4];
  if (lane == 63) wsum[wv] = s;
  __syncthreads();
  int add = 0;
  for (int k = 0; k < wv; ++k) add += wsum[k];
  int exc = boff[blockIdx.x] + add + s - v;
  if (i < N) { ptr[i] = exc; cur[i] = exc; }
}

// ---------------- CSR: fill inverse permutation pos + sorted src ----------------
__global__ void k_fill(const int* __restrict__ dst, const int* __restrict__ src,
                       int* __restrict__ cur, int* __restrict__ pos,
                       int* __restrict__ srcS, int E) {
  int e = blockIdx.x * 256 + threadIdx.x;
  if (e < E) {
    int p = atomicAdd(&cur[dst[e]], 1);
    pos[e] = p;
    srcS[p] = src[e];
  }
}

// ---------------- prep: a1n[n][h] = nft[n] . Wa1[:,h] ----------------
__global__ __launch_bounds__(256) void k_prep_a1(
    const float* __restrict__ nft, const float* __restrict__ Wa1,
    float* __restrict__ a1n, int N)
{
  __shared__ float w[FT * NH];
  int t = threadIdx.x;
  for (int i = t; i < FT * NH; i += 256) w[i] = Wa1[i];
  __syncthreads();
  int i = blockIdx.x * 256 + t;
  if (i >= N * NH) return;
  int node = i >> 3, h = i & 7;
  const float* xr = nft + (size_t)node * FT;
  float a = 0.0f;
  for (int k = 0; k < FT; k += 4) {
    float4 xv = *(const float4*)&xr[k];
    a = fmaf(xv.x, w[(k + 0) * NH + h], a);
    a = fmaf(xv.y, w[(k + 1) * NH + h], a);
    a = fmaf(xv.z, w[(k + 2) * NH + h], a);
    a = fmaf(xv.w, w[(k + 3) * NH + h], a);
  }
  a1n[i] = a;
}

// ---------------- node GEMM: nsAll = nft@[W0|W2] bf16; c2n = (ns2.*at2) head-sums ----------------
__global__ __launch_bounds__(256) void k_node_mfma(
    const float* __restrict__ nft, const ushort* __restrict__ WtN,
    const float* __restrict__ at2, ushort* __restrict__ nsAll,
    float* __restrict__ c2n, int N)
{
  __shared__ ushort x[64][136];
  const int t = threadIdx.x;
  const int n0 = blockIdx.x * 64;

  {
    int ei = t >> 2, q = t & 3;
    int n = min(n0 + ei, N - 1);
    const float* xr = nft + (size_t)n * FT;
    #pragma unroll
    for (int j = 0; j < 4; ++j) {
      int c = q * 32 + j * 8;
      float4 u = *(const float4*)&xr[c];
      float4 v = *(const float4*)&xr[c + 4];
      u16x8 pk;
      pk[0] = f2bf(u.x); pk[1] = f2bf(u.y); pk[2] = f2bf(u.z); pk[3] = f2bf(u.w);
      pk[4] = f2bf(v.x); pk[5] = f2bf(v.y); pk[6] = f2bf(v.z); pk[7] = f2bf(v.w);
      *(u16x8*)&x[ei][c] = pk;
    }
  }
  __syncthreads();

  const int w  = t >> 6;
  const int l  = t & 63;
  const int lr = l & 15;
  const int lk = l >> 4;

  bf16x8 breg[4][4];
  const ushort* wb = WtN + ((size_t)(w * 64 + lr) * 128 + lk * 8);
  #pragma unroll
  for (int ntl = 0; ntl < 4; ++ntl)
    #pragma unroll
    for (int ks = 0; ks < 4; ++ks)
      breg[ks][ntl] = *(const bf16x8*)(wb + (size_t)ntl * 16 * 128 + ks * 32);

  f32x4 acc[4][4];
  #pragma unroll
  for (int m = 0; m < 4; ++m)
    #pragma unroll
    for (int ntl = 0; ntl < 4; ++ntl) acc[m][ntl] = 0.0f;

  #pragma unroll
  for (int ks = 0; ks < 4; ++ks) {
    int kb = ks * 32 + lk * 8;
    #pragma unroll
    for (int m = 0; m < 4; ++m) {
      bf16x8 a = *(const bf16x8*)&x[m * 16 + lr][kb];
      #pragma unroll
      for (int ntl = 0; ntl < 4; ++ntl)
        acc[m][ntl] = __builtin_amdgcn_mfma_f32_16x16x32_bf16(a, breg[ks][ntl], acc[m][ntl], 0, 0, 0);
    }
  }

  #pragma unroll
  for (int ntl = 0; ntl < 4; ++ntl) {
    int col = w * 64 + ntl * 16 + lr;
    #pragma unroll
    for (int m = 0; m < 4; ++m) {
      int rb = m * 16 + lk * 4;
      f32x4 c = acc[m][ntl];
      #pragma unroll
      for (int r = 0; r < 4; ++r) {
        int node = n0 + rb + r;
        if (node < N) nsAll[(size_t)node * 256 + col] = f2bf(c[r]);
      }
      if (col >= 128) {   // c2n head-sums for the ns2 half only
        int head = (col & 127) >> 4;
        float a2v = at2[col & 127];
        float s0 = c[0] * a2v, s1 = c[1] * a2v, s2 = c[2] * a2v, s3 = c[3] * a2v;
        #pragma unroll
        for (int off = 1; off < 16; off <<= 1) {
          s0 += __shfl_xor(s0, off);
          s1 += __shfl_xor(s1, off);
          s2 += __shfl_xor(s2, off);
          s3 += __shfl_xor(s3, off);
        }
        if (lr == 0) {
          float sa[4] = {s0, s1, s2, s3};
          #pragma unroll
          for (int r = 0; r < 4; ++r) {
            int node = n0 + rb + r;
            if (node < N) c2n[(size_t)node * NH + head] = sa[r];
          }
        }
      }
    }
  }
}

// ---------------- edge GEMM: pure stream, eps[pos[e]] = eft[e]@W1 ----------------
// 256 thr = 4 waves; 64 edges/block; wave w -> cols w*32..+31 (2 ntl), all 64 edges.
__global__ __launch_bounds__(256) void k_edge_mfma(
    const float* __restrict__ eft, const ushort* __restrict__ Wt1,
    const int* __restrict__ pos, ushort* __restrict__ eps, int E)
{
  __shared__ ushort x[64][136];   // A tile bf16; reused for C staging

  const int t = threadIdx.x;
  const int e0 = blockIdx.x * 64;
  const int ei = t >> 2, q = t & 3;
  const int eg = e0 + ei;
  const int ec = min(eg, E - 1);
  const int pe = pos[ec];          // sequential read

  // ---- stage eft rows -> bf16 LDS (sequential, coalesced) ----
  {
    const float* ef = eft + (size_t)ec * FT;
    #pragma unroll
    for (int j = 0; j < 4; ++j) {
      int c = q * 32 + j * 8;
      float4 u = *(const float4*)&ef[c];
      float4 v = *(const float4*)&ef[c + 4];
      u16x8 pk;
      pk[0] = f2bf(u.x); pk[1] = f2bf(u.y); pk[2] = f2bf(u.z); pk[3] = f2bf(u.w);
      pk[4] = f2bf(v.x); pk[5] = f2bf(v.y); pk[6] = f2bf(v.z); pk[7] = f2bf(v.w);
      *(u16x8*)&x[ei][c] = pk;
    }
  }
  __syncthreads();

  const int w  = t >> 6;
  const int l  = t & 63;
  const int lr = l & 15;
  const int lk = l >> 4;

  bf16x8 breg[4][2];
  const ushort* wb = Wt1 + ((size_t)(w * 32 + lr) * 128 + lk * 8);
  #pragma unroll
  for (int ks = 0; ks < 4; ++ks) {
    breg[ks][0] = *(const bf16x8*)(wb + ks * 32);
    breg[ks][1] = *(const bf16x8*)(wb + 16 * 128 + ks * 32);
  }

  f32x4 acc[4][2];
  #pragma unroll
  for (int m = 0; m < 4; ++m) { acc[m][0] = 0.0f; acc[m][1] = 0.0f; }

  #pragma unroll
  for (int ks = 0; ks < 4; ++ks) {
    int kb = ks * 32 + lk * 8;
    #pragma unroll
    for (int m = 0; m < 4; ++m) {
      bf16x8 a = *(const bf16x8*)&x[m * 16 + lr][kb];
      acc[m][0] = __builtin_amdgcn_mfma_f32_16x16x32_bf16(a, breg[ks][0], acc[m][0], 0, 0, 0);
      acc[m][1] = __builtin_amdgcn_mfma_f32_16x16x32_bf16(a, breg[ks][1], acc[m][1], 0, 0, 0);
    }
  }

  // ---- C staging into x (reuse) ----
  __syncthreads();   // all MFMA reads of x done
  #pragma unroll
  for (int ntl = 0; ntl < 2; ++ntl) {
    int col = w * 32 + ntl * 16 + lr;
    #pragma unroll
    for (int m = 0; m < 4; ++m) {
      int rb = m * 16 + lk * 4;
      f32x4 c = acc[m][ntl];
      x[rb + 0][col] = f2bf(c[0]);
      x[rb + 1][col] = f2bf(c[1]);
      x[rb + 2][col] = f2bf(c[2]);
      x[rb + 3][col] = f2bf(c[3]);
    }
  }
  __syncthreads();

  // ---- scatter store at sorted position pos[e] (fire-and-forget) ----
  if (eg < E) {
    #pragma unroll
    for (int j = 0; j < 4; ++j) {
      u16x8 vv = *(const u16x8*)&x[ei][q * 32 + j * 8];
      *(u16x8*)&eps[(size_t)pe * FT + q * 32 + j * 8] = vv;
    }
  }
}

// ---------------- aggregate: wave-per-node, sequential eps + L2 ns0 gather ----------------
__global__ __launch_bounds__(256) void k_aggregate(
    const ushort* __restrict__ eps, const ushort* __restrict__ nsAll,
    const float* __restrict__ a1n, const float* __restrict__ c2n,
    const float* __restrict__ cb, const int* __restrict__ ptr,
    const int* __restrict__ srcS, const float* __restrict__ at2,
    const float* __restrict__ bp, const float* __restrict__ nft,
    float* __restrict__ out, int N)
{
  int wid = (blockIdx.x * 256 + threadIdx.x) >> 6;
  int l = threadIdx.x & 63;
  if (wid >= N) return;
  int beg = ptr[wid], end = ptr[wid + 1];
  int hh = l >> 3;
  float at0 = at2[l * 2], at1 = at2[l * 2 + 1];
  float c2b = c2n[(size_t)wid * NH + hh] + cb[hh];

  float m = -INFINITY, s = 0.0f, a0 = 0.0f, a1 = 0.0f;
  for (int i = beg; i < end; ++i) {
    int se = srcS[i];
    unsigned pe = *(const unsigned*)&eps[(size_t)i * FT + l * 2];        // sequential
    unsigned pn = *(const unsigned*)&nsAll[(size_t)se * 256 + l * 2];    // L2 gather
    float p0 = __uint_as_float(pe << 16)         + __uint_as_float(pn << 16);
    float p1 = __uint_as_float(pe & 0xFFFF0000u) + __uint_as_float(pn & 0xFFFF0000u);
    float ce = p0 * at0 + p1 * at1;
    ce += __shfl_xor(ce, 1);
    ce += __shfl_xor(ce, 2);
    ce += __shfl_xor(ce, 4);
    float lin = a1n[(size_t)se * NH + hh] + ce + c2b;
    float lv = lin > 0.0f ? lin : 0.01f * lin;
    float mn = fmaxf(m, lv);
    float corr = __expf(m - mn);
    float ev   = __expf(lv - mn);
    s  = s  * corr + ev;
    a0 = a0 * corr + ev * p0;
    a1 = a1 * corr + ev * p1;
    m = mn;
  }

  float2 nv = *(const float2*)&nft[(size_t)wid * FT + l * 2];
  float v0, v1;
  if (s > 0.0f) {
    float inv = 1.0f / s;
    unsigned pn2 = *(const unsigned*)&nsAll[(size_t)wid * 256 + 128 + l * 2];
    float2 bv = *(const float2*)&bp[l * 2];
    v0 = a0 * inv + __uint_as_float(pn2 << 16)         + bv.x + nv.x;
    v1 = a1 * inv + __uint_as_float(pn2 & 0xFFFF0000u) + bv.y + nv.y;
  } else {
    v0 = nv.x; v1 = nv.y;
  }
  float2 ov;
  ov.x = v0 > 0.0f ? v0 : 0.0f;
  ov.y = v1 > 0.0f ? v1 : 0.0f;
  *(float2*)&out[(size_t)wid * FT + l * 2] = ov;
}

extern "C" void kernel_launch(void* const* d_in, const int* in_sizes, int n_in,
                              void* d_out, int out_size, void* d_ws, size_t ws_size,
                              hipStream_t stream) {
  const float* nft = (const float*)d_in[0];
  const float* eft = (const float*)d_in[1];
  const float* Wp  = (const float*)d_in[2];
  const float* bp  = (const float*)d_in[3];
  const float* Wa1 = (const float*)d_in[4];
  const float* at2 = (const float*)d_in[5];
  const int*   src = (const int*)d_in[6];
  const int*   dst = (const int*)d_in[7];
  const int N = in_sizes[0] / FT;
  const int E = in_sizes[6];
  const int nb = (N + 255) / 256;

  char* ws = (char*)d_ws;
  size_t off = 0;
  ushort* eps = (ushort*)(ws + off);   off += (size_t)E * FT * sizeof(ushort);
  off = (off + 255) & ~(size_t)255;
  ushort* Wt1 = (ushort*)(ws + off);   off += (size_t)128 * 128 * sizeof(ushort);
  ushort* WtN = (ushort*)(ws + off);   off += (size_t)256 * 128 * sizeof(ushort);
  off = (off + 255) & ~(size_t)255;
  float* a1n = (float*)(ws + off);     off += (size_t)N * NH * sizeof(float);
  float* c2n = (float*)(ws + off);     off += (size_t)N * NH * sizeof(float);
  float* cb = (float*)(ws + off);      off += 256;
  ushort* nsAll = (ushort*)(ws + off); off += (size_t)N * 256 * sizeof(ushort);
  off = (off + 255) & ~(size_t)255;
  int* cnt = (int*)(ws + off);         off += (size_t)N * sizeof(int);
  int* ptr = (int*)(ws + off);         off += (size_t)(N + 1) * sizeof(int);
  int* cur = (int*)(ws + off);         off += (size_t)N * sizeof(int);
  int* bsum = (int*)(ws + off);        off += (size_t)nb * sizeof(int);
  int* boff = (int*)(ws + off);        off += (size_t)nb * sizeof(int);
  int* pos = (int*)(ws + off);         off += (size_t)E * sizeof(int);
  int* srcS = (int*)(ws + off);        off += (size_t)E * sizeof(int);

  int setup_n = (256 * 128 > N ? 256 * 128 : N);
  k_setup<<<(setup_n + 255) / 256, 256, 0, stream>>>(Wp, bp, at2, Wt1, WtN, cb, cnt, N);
  k_hist<<<(E + 255) / 256, 256, 0, stream>>>(dst, cnt, E);
  k_scan1<<<nb, 256, 0, stream>>>(cnt, bsum, N);
  k_scan2<<<1, 1024, 0, stream>>>(bsum, boff, ptr, nb, N);
  k_scan3<<<nb, 256, 0, stream>>>(cnt, boff, ptr, cur, N);
  k_fill<<<(E + 255) / 256, 256, 0, stream>>>(dst, src, cur, pos, srcS, E);

  k_node_mfma<<<(N + 63) / 64, 256, 0, stream>>>(nft, WtN, at2, nsAll, c2n, N);
  k_prep_a1<<<(N * NH + 255) / 256, 256, 0, stream>>>(nft, Wa1, a1n, N);

  k_edge_mfma<<<(E + 63) / 64, 256, 0, stream>>>(eft, Wt1, pos, eps, E);

  k_aggregate<<<(N * 64 + 255) / 256, 256, 0, stream>>>(eps, nsAll, a1n, c2n, cb,
                                                        ptr, srcS, at2, bp,
                                                        nft, (float*)d_out, N);
}

// Round 11
// 171.783 us; speedup vs baseline: 4.8736x; 1.0905x over previous
//
#include <hip/hip_runtime.h>
#include <hip/hip_bf16.h>

#define FT 128
#define NH 8

typedef short bf16x8 __attribute__((ext_vector_type(8)));
typedef ushort u16x8 __attribute__((ext_vector_type(8)));
typedef float f32x4 __attribute__((ext_vector_type(4)));

__device__ __forceinline__ ushort f2bf(float f) {
  __hip_bfloat16 h = __float2bfloat16(f);
  return *reinterpret_cast<ushort*>(&h);
}
__device__ __forceinline__ float bf2f(ushort u) {
  return __uint_as_float(((unsigned)u) << 16);
}

// ---------------- setup: zero cnt + build Wt1/WtN (bf16 B-layout) + cb ----------------
__global__ void k_setup(const float* __restrict__ Wp, const float* __restrict__ bp,
                        const float* __restrict__ at2, ushort* __restrict__ Wt1,
                        ushort* __restrict__ WtN, float* __restrict__ cb,
                        int* __restrict__ cnt, int N) {
  int i = blockIdx.x * 256 + threadIdx.x;
  if (i < N) cnt[i] = 0;
  if (i < 128 * 128) {
    int c = i >> 7, k = i & 127;
    Wt1[i] = f2bf(Wp[(size_t)(128 + k) * 128 + c]);
  }
  if (i < 256 * 128) {
    int c = i >> 7, k = i & 127;
    float v = (c < 128) ? Wp[(size_t)k * 128 + c]
                        : Wp[(size_t)(256 + k) * 128 + (c - 128)];
    WtN[i] = f2bf(v);
  }
  if (i < NH) {
    float s = 0.0f;
    #pragma unroll
    for (int j = 0; j < 16; ++j) s += bp[i * 16 + j] * at2[i * 16 + j];
    cb[i] = s;
  }
}

// ---------------- CSR: histogram ----------------
__global__ void k_hist(const int* __restrict__ dst, int* __restrict__ cnt, int E) {
  int e = blockIdx.x * 256 + threadIdx.x;
  if (e < E) atomicAdd(&cnt[dst[e]], 1);
}

// ---------------- CSR: hierarchical scan ----------------
__global__ void k_scan1(const int* __restrict__ cnt, int* __restrict__ bsum, int N) {
  int i = blockIdx.x * 256 + threadIdx.x;
  int v = (i < N) ? cnt[i] : 0;
  #pragma unroll
  for (int o = 1; o < 64; o <<= 1) v += __shfl_xor(v, o);
  __shared__ int ws[4];
  if ((threadIdx.x & 63) == 0) ws[threadIdx.x >> 6] = v;
  __syncthreads();
  if (threadIdx.x == 0) bsum[blockIdx.x] = ws[0] + ws[1] + ws[2] + ws[3];
}

__global__ __launch_bounds__(1024) void k_scan2(const int* __restrict__ bsum,
                                                int* __restrict__ boff,
                                                int* __restrict__ ptr, int nb, int N) {
  __shared__ int buf[1024];
  int t = threadIdx.x;
  int v = (t < nb) ? bsum[t] : 0;
  buf[t] = v;
  __syncthreads();
  #pragma unroll
  for (int o = 1; o < 1024; o <<= 1) {
    int x = (t >= o) ? buf[t - o] : 0;
    __syncthreads();
    buf[t] += x;
    __syncthreads();
  }
  if (t < nb) boff[t] = buf[t] - v;
  if (t == nb - 1) ptr[N] = buf[t];
}

__global__ void k_scan3(const int* __restrict__ cnt, const int* __restrict__ boff,
                        int* __restrict__ ptr, int* __restrict__ cur, int N) {
  int i = blockIdx.x * 256 + threadIdx.x;
  int v = (i < N) ? cnt[i] : 0;
  int lane = threadIdx.x & 63, wv = threadIdx.x >> 6;
  int s = v;
  #pragma unroll
  for (int o = 1; o < 64; o <<= 1) {
    int x = __shfl_up(s, o);
    if (lane >= o) s += x;
  }
  __shared__ int wsum[4];
  if (lane == 63) wsum[wv] = s;
  __syncthreads();
  int add = 0;
  for (int k = 0; k < wv; ++k) add += wsum[k];
  int exc = boff[blockIdx.x] + add + s - v;
  if (i < N) { ptr[i] = exc; cur[i] = exc; }
}

// ---------------- CSR: fill inverse permutation pos + sorted src ----------------
__global__ void k_fill(const int* __restrict__ dst, const int* __restrict__ src,
                       int* __restrict__ cur, int* __restrict__ pos,
                       int* __restrict__ srcS, int E) {
  int e = blockIdx.x * 256 + threadIdx.x;
  if (e < E) {
    int p = atomicAdd(&cur[dst[e]], 1);
    pos[e] = p;
    srcS[p] = src[e];
  }
}

// ---------------- node GEMM: nsAll = nft@[W0|W2] bf16; c2n head-sums; a1n fused ----------------
__global__ __launch_bounds__(256) void k_node_mfma(
    const float* __restrict__ nft, const ushort* __restrict__ WtN,
    const float* __restrict__ at2, const float* __restrict__ Wa1,
    ushort* __restrict__ nsAll, float* __restrict__ c2n,
    float* __restrict__ a1n, int N)
{
  __shared__ ushort x[64][136];
  const int t = threadIdx.x;
  const int n0 = blockIdx.x * 64;

  // stage nft -> bf16 LDS, contiguous per-lane (8 floats each, 4 iters)
  #pragma unroll
  for (int r = 0; r < 4; ++r) {
    int idx = r * 2048 + t * 8;
    int ei = idx >> 7, c = idx & 127;
    const float* xr = nft + (size_t)min(n0 + ei, N - 1) * FT + c;
    float4 u = *(const float4*)xr;
    float4 v = *(const float4*)(xr + 4);
    u16x8 pk;
    pk[0] = f2bf(u.x); pk[1] = f2bf(u.y); pk[2] = f2bf(u.z); pk[3] = f2bf(u.w);
    pk[4] = f2bf(v.x); pk[5] = f2bf(v.y); pk[6] = f2bf(v.z); pk[7] = f2bf(v.w);
    *(u16x8*)&x[ei][c] = pk;
  }
  __syncthreads();

  const int w  = t >> 6;
  const int l  = t & 63;
  const int lr = l & 15;
  const int lk = l >> 4;

  bf16x8 breg[4][4];
  const ushort* wb = WtN + ((size_t)(w * 64 + lr) * 128 + lk * 8);
  #pragma unroll
  for (int ntl = 0; ntl < 4; ++ntl)
    #pragma unroll
    for (int ks = 0; ks < 4; ++ks)
      breg[ks][ntl] = *(const bf16x8*)(wb + (size_t)ntl * 16 * 128 + ks * 32);

  f32x4 acc[4][4];
  #pragma unroll
  for (int m = 0; m < 4; ++m)
    #pragma unroll
    for (int ntl = 0; ntl < 4; ++ntl) acc[m][ntl] = 0.0f;

  #pragma unroll
  for (int ks = 0; ks < 4; ++ks) {
    int kb = ks * 32 + lk * 8;
    #pragma unroll
    for (int m = 0; m < 4; ++m) {
      bf16x8 a = *(const bf16x8*)&x[m * 16 + lr][kb];
      #pragma unroll
      for (int ntl = 0; ntl < 4; ++ntl)
        acc[m][ntl] = __builtin_amdgcn_mfma_f32_16x16x32_bf16(a, breg[ks][ntl], acc[m][ntl], 0, 0, 0);
    }
  }

  #pragma unroll
  for (int ntl = 0; ntl < 4; ++ntl) {
    int col = w * 64 + ntl * 16 + lr;
    #pragma unroll
    for (int m = 0; m < 4; ++m) {
      int rb = m * 16 + lk * 4;
      f32x4 c = acc[m][ntl];
      #pragma unroll
      for (int r = 0; r < 4; ++r) {
        int node = n0 + rb + r;
        if (node < N) nsAll[(size_t)node * 256 + col] = f2bf(c[r]);
      }
      if (col >= 128) {   // c2n head-sums for the ns2 half only
        int head = (col & 127) >> 4;
        float a2v = at2[col & 127];
        float s0 = c[0] * a2v, s1 = c[1] * a2v, s2 = c[2] * a2v, s3 = c[3] * a2v;
        #pragma unroll
        for (int off = 1; off < 16; off <<= 1) {
          s0 += __shfl_xor(s0, off);
          s1 += __shfl_xor(s1, off);
          s2 += __shfl_xor(s2, off);
          s3 += __shfl_xor(s3, off);
        }
        if (lr == 0) {
          float sa[4] = {s0, s1, s2, s3};
          #pragma unroll
          for (int r = 0; r < 4; ++r) {
            int node = n0 + rb + r;
            if (node < N) c2n[(size_t)node * NH + head] = sa[r];
          }
        }
      }
    }
  }

  // fused a1n: node ei = t>>2, heads 2q, 2q+1 (from bf16-staged x)
  {
    int ei = t >> 2, q = t & 3;
    int node = n0 + ei;
    if (node < N) {
      float a0 = 0.0f, a1 = 0.0f;
      for (int k = 0; k < FT; ++k) {
        float xv = bf2f(x[ei][k]);
        a0 = fmaf(xv, Wa1[k * NH + 2 * q], a0);
        a1 = fmaf(xv, Wa1[k * NH + 2 * q + 1], a1);
      }
      a1n[(size_t)node * NH + 2 * q]     = a0;
      a1n[(size_t)node * NH + 2 * q + 1] = a1;
    }
  }
}

// ---------------- edge GEMM: pure stream, contiguous lane layout, eps[pos[e]] = eft[e]@W1 ----------------
// 256 thr = 4 waves; 64 edges/block; wave w -> cols w*32..+31 (2 ntl), all 64 edges.
__global__ __launch_bounds__(256) void k_edge_mfma(
    const float* __restrict__ eft, const ushort* __restrict__ Wt1,
    const int* __restrict__ pos, ushort* __restrict__ eps, int E)
{
  __shared__ ushort x[64][136];   // A tile bf16
  __shared__ ushort y[64][136];   // C staging
  __shared__ int sPos[64];

  const int t = threadIdx.x;
  const int e0 = blockIdx.x * 64;

  if (t < 64) {
    int e = e0 + t;
    sPos[t] = (e < E) ? pos[e] : -1;
  }

  // ---- stage eft -> bf16 LDS: each lane 8 CONSECUTIVE floats (full-line requests) ----
  #pragma unroll
  for (int r = 0; r < 4; ++r) {
    int idx = r * 2048 + t * 8;
    int ei = idx >> 7, c = idx & 127;
    const float* ef = eft + (size_t)min(e0 + ei, E - 1) * FT + c;
    float4 u = *(const float4*)ef;
    float4 v = *(const float4*)(ef + 4);
    u16x8 pk;
    pk[0] = f2bf(u.x); pk[1] = f2bf(u.y); pk[2] = f2bf(u.z); pk[3] = f2bf(u.w);
    pk[4] = f2bf(v.x); pk[5] = f2bf(v.y); pk[6] = f2bf(v.z); pk[7] = f2bf(v.w);
    *(u16x8*)&x[ei][c] = pk;
  }
  __syncthreads();

  const int w  = t >> 6;
  const int l  = t & 63;
  const int lr = l & 15;
  const int lk = l >> 4;

  bf16x8 breg[4][2];
  const ushort* wb = Wt1 + ((size_t)(w * 32 + lr) * 128 + lk * 8);
  #pragma unroll
  for (int ks = 0; ks < 4; ++ks) {
    breg[ks][0] = *(const bf16x8*)(wb + ks * 32);
    breg[ks][1] = *(const bf16x8*)(wb + 16 * 128 + ks * 32);
  }

  f32x4 acc[4][2];
  #pragma unroll
  for (int m = 0; m < 4; ++m) { acc[m][0] = 0.0f; acc[m][1] = 0.0f; }

  #pragma unroll
  for (int ks = 0; ks < 4; ++ks) {
    int kb = ks * 32 + lk * 8;
    #pragma unroll
    for (int m = 0; m < 4; ++m) {
      bf16x8 a = *(const bf16x8*)&x[m * 16 + lr][kb];
      acc[m][0] = __builtin_amdgcn_mfma_f32_16x16x32_bf16(a, breg[ks][0], acc[m][0], 0, 0, 0);
      acc[m][1] = __builtin_amdgcn_mfma_f32_16x16x32_bf16(a, breg[ks][1], acc[m][1], 0, 0, 0);
    }
  }

  // ---- C-stage into y (own data only -> no barrier needed before writes) ----
  #pragma unroll
  for (int ntl = 0; ntl < 2; ++ntl) {
    int col = w * 32 + ntl * 16 + lr;
    #pragma unroll
    for (int m = 0; m < 4; ++m) {
      int rb = m * 16 + lk * 4;
      f32x4 c = acc[m][ntl];
      y[rb + 0][col] = f2bf(c[0]);
      y[rb + 1][col] = f2bf(c[1]);
      y[rb + 2][col] = f2bf(c[2]);
      y[rb + 3][col] = f2bf(c[3]);
    }
  }
  __syncthreads();

  // ---- scatter store: 16 lanes cover one 256B row contiguously ----
  #pragma unroll
  for (int r = 0; r < 4; ++r) {
    int idx = r * 2048 + t * 8;
    int ei = idx >> 7, c = idx & 127;
    int pe = sPos[ei];
    if (pe >= 0) {
      u16x8 vv = *(const u16x8*)&y[ei][c];
      *(u16x8*)&eps[(size_t)pe * FT + c] = vv;
    }
  }
}

// ---------------- aggregate: wave-per-node, sequential eps + L2 ns0 gather ----------------
__global__ __launch_bounds__(256) void k_aggregate(
    const ushort* __restrict__ eps, const ushort* __restrict__ nsAll,
    const float* __restrict__ a1n, const float* __restrict__ c2n,
    const float* __restrict__ cb, const int* __restrict__ ptr,
    const int* __restrict__ srcS, const float* __restrict__ at2,
    const float* __restrict__ bp, const float* __restrict__ nft,
    float* __restrict__ out, int N)
{
  int wid = (blockIdx.x * 256 + threadIdx.x) >> 6;
  int l = threadIdx.x & 63;
  if (wid >= N) return;
  int beg = ptr[wid], end = ptr[wid + 1];
  int hh = l >> 3;
  float at0 = at2[l * 2], at1 = at2[l * 2 + 1];
  float c2b = c2n[(size_t)wid * NH + hh] + cb[hh];

  float m = -INFINITY, s = 0.0f, a0 = 0.0f, a1 = 0.0f;
  for (int i = beg; i < end; ++i) {
    int se = srcS[i];
    unsigned pe = *(const unsigned*)&eps[(size_t)i * FT + l * 2];        // sequential
    unsigned pn = *(const unsigned*)&nsAll[(size_t)se * 256 + l * 2];    // L2 gather
    float p0 = __uint_as_float(pe << 16)         + __uint_as_float(pn << 16);
    float p1 = __uint_as_float(pe & 0xFFFF0000u) + __uint_as_float(pn & 0xFFFF0000u);
    float ce = p0 * at0 + p1 * at1;
    ce += __shfl_xor(ce, 1);
    ce += __shfl_xor(ce, 2);
    ce += __shfl_xor(ce, 4);
    float lin = a1n[(size_t)se * NH + hh] + ce + c2b;
    float lv = lin > 0.0f ? lin : 0.01f * lin;
    float mn = fmaxf(m, lv);
    float corr = __expf(m - mn);
    float ev   = __expf(lv - mn);
    s  = s  * corr + ev;
    a0 = a0 * corr + ev * p0;
    a1 = a1 * corr + ev * p1;
    m = mn;
  }

  float2 nv = *(const float2*)&nft[(size_t)wid * FT + l * 2];
  float v0, v1;
  if (s > 0.0f) {
    float inv = 1.0f / s;
    unsigned pn2 = *(const unsigned*)&nsAll[(size_t)wid * 256 + 128 + l * 2];
    float2 bv = *(const float2*)&bp[l * 2];
    v0 = a0 * inv + __uint_as_float(pn2 << 16)         + bv.x + nv.x;
    v1 = a1 * inv + __uint_as_float(pn2 & 0xFFFF0000u) + bv.y + nv.y;
  } else {
    v0 = nv.x; v1 = nv.y;
  }
  float2 ov;
  ov.x = v0 > 0.0f ? v0 : 0.0f;
  ov.y = v1 > 0.0f ? v1 : 0.0f;
  *(float2*)&out[(size_t)wid * FT + l * 2] = ov;
}

extern "C" void kernel_launch(void* const* d_in, const int* in_sizes, int n_in,
                              void* d_out, int out_size, void* d_ws, size_t ws_size,
                              hipStream_t stream) {
  const float* nft = (const float*)d_in[0];
  const float* eft = (const float*)d_in[1];
  const float* Wp  = (const float*)d_in[2];
  const float* bp  = (const float*)d_in[3];
  const float* Wa1 = (const float*)d_in[4];
  const float* at2 = (const float*)d_in[5];
  const int*   src = (const int*)d_in[6];
  const int*   dst = (const int*)d_in[7];
  const int N = in_sizes[0] / FT;
  const int E = in_sizes[6];
  const int nb = (N + 255) / 256;

  char* ws = (char*)d_ws;
  size_t off = 0;
  ushort* eps = (ushort*)(ws + off);   off += (size_t)E * FT * sizeof(ushort);
  off = (off + 255) & ~(size_t)255;
  ushort* Wt1 = (ushort*)(ws + off);   off += (size_t)128 * 128 * sizeof(ushort);
  ushort* WtN = (ushort*)(ws + off);   off += (size_t)256 * 128 * sizeof(ushort);
  off = (off + 255) & ~(size_t)255;
  float* a1n = (float*)(ws + off);     off += (size_t)N * NH * sizeof(float);
  float* c2n = (float*)(ws + off);     off += (size_t)N * NH * sizeof(float);
  float* cb = (float*)(ws + off);      off += 256;
  ushort* nsAll = (ushort*)(ws + off); off += (size_t)N * 256 * sizeof(ushort);
  off = (off + 255) & ~(size_t)255;
  int* cnt = (int*)(ws + off);         off += (size_t)N * sizeof(int);
  int* ptr = (int*)(ws + off);         off += (size_t)(N + 1) * sizeof(int);
  int* cur = (int*)(ws + off);         off += (size_t)N * sizeof(int);
  int* bsum = (int*)(ws + off);        off += (size_t)nb * sizeof(int);
  int* boff = (int*)(ws + off);        off += (size_t)nb * sizeof(int);
  int* pos = (int*)(ws + off);         off += (size_t)E * sizeof(int);
  int* srcS = (int*)(ws + off);        off += (size_t)E * sizeof(int);

  int setup_n = (256 * 128 > N ? 256 * 128 : N);
  k_setup<<<(setup_n + 255) / 256, 256, 0, stream>>>(Wp, bp, at2, Wt1, WtN, cb, cnt, N);
  k_hist<<<(E + 255) / 256, 256, 0, stream>>>(dst, cnt, E);
  k_scan1<<<nb, 256, 0, stream>>>(cnt, bsum, N);
  k_scan2<<<1, 1024, 0, stream>>>(bsum, boff, ptr, nb, N);
  k_scan3<<<nb, 256, 0, stream>>>(cnt, boff, ptr, cur, N);
  k_fill<<<(E + 255) / 256, 256, 0, stream>>>(dst, src, cur, pos, srcS, E);

  k_node_mfma<<<(N + 63) / 64, 256, 0, stream>>>(nft, WtN, at2, Wa1, nsAll, c2n,
                                                 a1n, N);

  k_edge_mfma<<<(E + 63) / 64, 256, 0, stream>>>(eft, Wt1, pos, eps, E);

  k_aggregate<<<(N * 64 + 255) / 256, 256, 0, stream>>>(eps, nsAll, a1n, c2n, cb,
                                                        ptr, srcS, at2, bp,
                                                        nft, (float*)d_out, N);
}

// Round 12
// 157.001 us; speedup vs baseline: 5.3325x; 1.0942x over previous
//
#include <hip/hip_runtime.h>
#include <hip/hip_bf16.h>

#define FT 128
#define NH 8

typedef short bf16x8 __attribute__((ext_vector_type(8)));
typedef ushort u16x8 __attribute__((ext_vector_type(8)));
typedef float f32x4 __attribute__((ext_vector_type(4)));

__device__ __forceinline__ ushort f2bf(float f) {
  __hip_bfloat16 h = __float2bfloat16(f);
  return *reinterpret_cast<ushort*>(&h);
}
__device__ __forceinline__ float bf2f(ushort u) {
  return __uint_as_float(((unsigned)u) << 16);
}

// ---------------- setup: zero cnt + build Wt1/WtN (bf16 B-layout) + cb ----------------
__global__ void k_setup(const float* __restrict__ Wp, const float* __restrict__ bp,
                        const float* __restrict__ at2, ushort* __restrict__ Wt1,
                        ushort* __restrict__ WtN, float* __restrict__ cb,
                        int* __restrict__ cnt, int N) {
  int i = blockIdx.x * 256 + threadIdx.x;
  if (i < N) cnt[i] = 0;
  if (i < 128 * 128) {
    int c = i >> 7, k = i & 127;
    Wt1[i] = f2bf(Wp[(size_t)(128 + k) * 128 + c]);
  }
  if (i < 256 * 128) {
    int c = i >> 7, k = i & 127;
    float v = (c < 128) ? Wp[(size_t)k * 128 + c]
                        : Wp[(size_t)(256 + k) * 128 + (c - 128)];
    WtN[i] = f2bf(v);
  }
  if (i < NH) {
    float s = 0.0f;
    #pragma unroll
    for (int j = 0; j < 16; ++j) s += bp[i * 16 + j] * at2[i * 16 + j];
    cb[i] = s;
  }
}

// ---------------- CSR: histogram ----------------
__global__ void k_hist(const int* __restrict__ dst, int* __restrict__ cnt, int E) {
  int e = blockIdx.x * 256 + threadIdx.x;
  if (e < E) atomicAdd(&cnt[dst[e]], 1);
}

// ---------------- CSR: hierarchical scan ----------------
__global__ void k_scan1(const int* __restrict__ cnt, int* __restrict__ bsum, int N) {
  int i = blockIdx.x * 256 + threadIdx.x;
  int v = (i < N) ? cnt[i] : 0;
  #pragma unroll
  for (int o = 1; o < 64; o <<= 1) v += __shfl_xor(v, o);
  __shared__ int ws[4];
  if ((threadIdx.x & 63) == 0) ws[threadIdx.x >> 6] = v;
  __syncthreads();
  if (threadIdx.x == 0) bsum[blockIdx.x] = ws[0] + ws[1] + ws[2] + ws[3];
}

__global__ __launch_bounds__(1024) void k_scan2(const int* __restrict__ bsum,
                                                int* __restrict__ boff,
                                                int* __restrict__ ptr, int nb, int N) {
  __shared__ int buf[1024];
  int t = threadIdx.x;
  int v = (t < nb) ? bsum[t] : 0;
  buf[t] = v;
  __syncthreads();
  #pragma unroll
  for (int o = 1; o < 1024; o <<= 1) {
    int x = (t >= o) ? buf[t - o] : 0;
    __syncthreads();
    buf[t] += x;
    __syncthreads();
  }
  if (t < nb) boff[t] = buf[t] - v;
  if (t == nb - 1) ptr[N] = buf[t];
}

__global__ void k_scan3(const int* __restrict__ cnt, const int* __restrict__ boff,
                        int* __restrict__ ptr, int* __restrict__ cur, int N) {
  int i = blockIdx.x * 256 + threadIdx.x;
  int v = (i < N) ? cnt[i] : 0;
  int lane = threadIdx.x & 63, wv = threadIdx.x >> 6;
  int s = v;
  #pragma unroll
  for (int o = 1; o < 64; o <<= 1) {
    int x = __shfl_up(s, o);
    if (lane >= o) s += x;
  }
  __shared__ int wsum[4];
  if (lane == 63) wsum[wv] = s;
  __syncthreads();
  int add = 0;
  for (int k = 0; k < wv; ++k) add += wsum[k];
  int exc = boff[blockIdx.x] + add + s - v;
  if (i < N) { ptr[i] = exc; cur[i] = exc; }
}

// ---------------- CSR: fill inverse permutation pos + sorted src ----------------
__global__ void k_fill(const int* __restrict__ dst, const int* __restrict__ src,
                       int* __restrict__ cur, int* __restrict__ pos,
                       int* __restrict__ srcS, int E) {
  int e = blockIdx.x * 256 + threadIdx.x;
  if (e < E) {
    int p = atomicAdd(&cur[dst[e]], 1);
    pos[e] = p;
    srcS[p] = src[e];
  }
}

// ---------------- node GEMM: nsAll = nft@[W0|W2] bf16; c2n head-sums; a1n fused ----------------
__global__ __launch_bounds__(256) void k_node_mfma(
    const float* __restrict__ nft, const ushort* __restrict__ WtN,
    const float* __restrict__ at2, const float* __restrict__ Wa1,
    ushort* __restrict__ nsAll, float* __restrict__ c2n,
    float* __restrict__ a1n, int N)
{
  __shared__ ushort x[64][136];
  const int t = threadIdx.x;
  const int n0 = blockIdx.x * 64;

  // stage nft -> bf16 LDS, contiguous per-lane (8 floats each, 4 iters)
  #pragma unroll
  for (int r = 0; r < 4; ++r) {
    int idx = r * 2048 + t * 8;
    int ei = idx >> 7, c = idx & 127;
    const float* xr = nft + (size_t)min(n0 + ei, N - 1) * FT + c;
    float4 u = *(const float4*)xr;
    float4 v = *(const float4*)(xr + 4);
    u16x8 pk;
    pk[0] = f2bf(u.x); pk[1] = f2bf(u.y); pk[2] = f2bf(u.z); pk[3] = f2bf(u.w);
    pk[4] = f2bf(v.x); pk[5] = f2bf(v.y); pk[6] = f2bf(v.z); pk[7] = f2bf(v.w);
    *(u16x8*)&x[ei][c] = pk;
  }
  __syncthreads();

  const int w  = t >> 6;
  const int l  = t & 63;
  const int lr = l & 15;
  const int lk = l >> 4;

  bf16x8 breg[4][4];
  const ushort* wb = WtN + ((size_t)(w * 64 + lr) * 128 + lk * 8);
  #pragma unroll
  for (int ntl = 0; ntl < 4; ++ntl)
    #pragma unroll
    for (int ks = 0; ks < 4; ++ks)
      breg[ks][ntl] = *(const bf16x8*)(wb + (size_t)ntl * 16 * 128 + ks * 32);

  f32x4 acc[4][4];
  #pragma unroll
  for (int m = 0; m < 4; ++m)
    #pragma unroll
    for (int ntl = 0; ntl < 4; ++ntl) acc[m][ntl] = 0.0f;

  #pragma unroll
  for (int ks = 0; ks < 4; ++ks) {
    int kb = ks * 32 + lk * 8;
    #pragma unroll
    for (int m = 0; m < 4; ++m) {
      bf16x8 a = *(const bf16x8*)&x[m * 16 + lr][kb];
      #pragma unroll
      for (int ntl = 0; ntl < 4; ++ntl)
        acc[m][ntl] = __builtin_amdgcn_mfma_f32_16x16x32_bf16(a, breg[ks][ntl], acc[m][ntl], 0, 0, 0);
    }
  }

  #pragma unroll
  for (int ntl = 0; ntl < 4; ++ntl) {
    int col = w * 64 + ntl * 16 + lr;
    #pragma unroll
    for (int m = 0; m < 4; ++m) {
      int rb = m * 16 + lk * 4;
      f32x4 c = acc[m][ntl];
      #pragma unroll
      for (int r = 0; r < 4; ++r) {
        int node = n0 + rb + r;
        if (node < N) nsAll[(size_t)node * 256 + col] = f2bf(c[r]);
      }
      if (col >= 128) {   // c2n head-sums for the ns2 half only
        int head = (col & 127) >> 4;
        float a2v = at2[col & 127];
        float s0 = c[0] * a2v, s1 = c[1] * a2v, s2 = c[2] * a2v, s3 = c[3] * a2v;
        #pragma unroll
        for (int off = 1; off < 16; off <<= 1) {
          s0 += __shfl_xor(s0, off);
          s1 += __shfl_xor(s1, off);
          s2 += __shfl_xor(s2, off);
          s3 += __shfl_xor(s3, off);
        }
        if (lr == 0) {
          float sa[4] = {s0, s1, s2, s3};
          #pragma unroll
          for (int r = 0; r < 4; ++r) {
            int node = n0 + rb + r;
            if (node < N) c2n[(size_t)node * NH + head] = sa[r];
          }
        }
      }
    }
  }

  // fused a1n: node ei = t>>2, heads 2q, 2q+1 (from bf16-staged x)
  {
    int ei = t >> 2, q = t & 3;
    int node = n0 + ei;
    if (node < N) {
      float a0 = 0.0f, a1 = 0.0f;
      for (int k = 0; k < FT; ++k) {
        float xv = bf2f(x[ei][k]);
        a0 = fmaf(xv, Wa1[k * NH + 2 * q], a0);
        a1 = fmaf(xv, Wa1[k * NH + 2 * q + 1], a1);
      }
      a1n[(size_t)node * NH + 2 * q]     = a0;
      a1n[(size_t)node * NH + 2 * q + 1] = a1;
    }
  }
}

// ---------------- edge GEMM: pure stream, contiguous lane layout, eps[pos[e]] = eft[e]@W1 ----------------
__global__ __launch_bounds__(256) void k_edge_mfma(
    const float* __restrict__ eft, const ushort* __restrict__ Wt1,
    const int* __restrict__ pos, ushort* __restrict__ eps, int E)
{
  __shared__ ushort x[64][136];   // A tile bf16
  __shared__ ushort y[64][136];   // C staging
  __shared__ int sPos[64];

  const int t = threadIdx.x;
  const int e0 = blockIdx.x * 64;

  if (t < 64) {
    int e = e0 + t;
    sPos[t] = (e < E) ? pos[e] : -1;
  }

  // ---- stage eft -> bf16 LDS: each lane 8 CONSECUTIVE floats (full-line requests) ----
  #pragma unroll
  for (int r = 0; r < 4; ++r) {
    int idx = r * 2048 + t * 8;
    int ei = idx >> 7, c = idx & 127;
    const float* ef = eft + (size_t)min(e0 + ei, E - 1) * FT + c;
    float4 u = *(const float4*)ef;
    float4 v = *(const float4*)(ef + 4);
    u16x8 pk;
    pk[0] = f2bf(u.x); pk[1] = f2bf(u.y); pk[2] = f2bf(u.z); pk[3] = f2bf(u.w);
    pk[4] = f2bf(v.x); pk[5] = f2bf(v.y); pk[6] = f2bf(v.z); pk[7] = f2bf(v.w);
    *(u16x8*)&x[ei][c] = pk;
  }
  __syncthreads();

  const int w  = t >> 6;
  const int l  = t & 63;
  const int lr = l & 15;
  const int lk = l >> 4;

  bf16x8 breg[4][2];
  const ushort* wb = Wt1 + ((size_t)(w * 32 + lr) * 128 + lk * 8);
  #pragma unroll
  for (int ks = 0; ks < 4; ++ks) {
    breg[ks][0] = *(const bf16x8*)(wb + ks * 32);
    breg[ks][1] = *(const bf16x8*)(wb + 16 * 128 + ks * 32);
  }

  f32x4 acc[4][2];
  #pragma unroll
  for (int m = 0; m < 4; ++m) { acc[m][0] = 0.0f; acc[m][1] = 0.0f; }

  #pragma unroll
  for (int ks = 0; ks < 4; ++ks) {
    int kb = ks * 32 + lk * 8;
    #pragma unroll
    for (int m = 0; m < 4; ++m) {
      bf16x8 a = *(const bf16x8*)&x[m * 16 + lr][kb];
      acc[m][0] = __builtin_amdgcn_mfma_f32_16x16x32_bf16(a, breg[ks][0], acc[m][0], 0, 0, 0);
      acc[m][1] = __builtin_amdgcn_mfma_f32_16x16x32_bf16(a, breg[ks][1], acc[m][1], 0, 0, 0);
    }
  }

  // ---- C-stage into y (own data only -> no barrier needed before writes) ----
  #pragma unroll
  for (int ntl = 0; ntl < 2; ++ntl) {
    int col = w * 32 + ntl * 16 + lr;
    #pragma unroll
    for (int m = 0; m < 4; ++m) {
      int rb = m * 16 + lk * 4;
      f32x4 c = acc[m][ntl];
      y[rb + 0][col] = f2bf(c[0]);
      y[rb + 1][col] = f2bf(c[1]);
      y[rb + 2][col] = f2bf(c[2]);
      y[rb + 3][col] = f2bf(c[3]);
    }
  }
  __syncthreads();

  // ---- scatter store: 16 lanes cover one 256B row contiguously ----
  #pragma unroll
  for (int r = 0; r < 4; ++r) {
    int idx = r * 2048 + t * 8;
    int ei = idx >> 7, c = idx & 127;
    int pe = sPos[ei];
    if (pe >= 0) {
      u16x8 vv = *(const u16x8*)&y[ei][c];
      *(u16x8*)&eps[(size_t)pe * FT + c] = vv;
    }
  }
}

// ---------------- aggregate: wave-per-node, 2x-unrolled online softmax ----------------
__global__ __launch_bounds__(256) void k_aggregate(
    const ushort* __restrict__ eps, const ushort* __restrict__ nsAll,
    const float* __restrict__ a1n, const float* __restrict__ c2n,
    const float* __restrict__ cb, const int* __restrict__ ptr,
    const int* __restrict__ srcS, const float* __restrict__ at2,
    const float* __restrict__ bp, const float* __restrict__ nft,
    float* __restrict__ out, int N)
{
  int wid = (blockIdx.x * 256 + threadIdx.x) >> 6;
  int l = threadIdx.x & 63;
  if (wid >= N) return;
  int beg = ptr[wid], end = ptr[wid + 1];
  int hh = l >> 3;
  float at0 = at2[l * 2], at1 = at2[l * 2 + 1];
  float c2b = c2n[(size_t)wid * NH + hh] + cb[hh];

  float m = -INFINITY, s = 0.0f, a0 = 0.0f, a1 = 0.0f;
  int i = beg;

  // 2x unrolled: one joint max + one corr per pair; 2x gather MLP
  for (; i + 1 < end; i += 2) {
    int se0 = srcS[i];
    int se1 = srcS[i + 1];
    unsigned pe0 = *(const unsigned*)&eps[(size_t)i * FT + l * 2];
    unsigned pe1 = *(const unsigned*)&eps[(size_t)(i + 1) * FT + l * 2];
    unsigned pn0 = *(const unsigned*)&nsAll[(size_t)se0 * 256 + l * 2];
    unsigned pn1 = *(const unsigned*)&nsAll[(size_t)se1 * 256 + l * 2];
    float p00 = __uint_as_float(pe0 << 16)         + __uint_as_float(pn0 << 16);
    float p01 = __uint_as_float(pe0 & 0xFFFF0000u) + __uint_as_float(pn0 & 0xFFFF0000u);
    float p10 = __uint_as_float(pe1 << 16)         + __uint_as_float(pn1 << 16);
    float p11 = __uint_as_float(pe1 & 0xFFFF0000u) + __uint_as_float(pn1 & 0xFFFF0000u);
    float ce0 = p00 * at0 + p01 * at1;
    float ce1 = p10 * at0 + p11 * at1;
    ce0 += __shfl_xor(ce0, 1); ce1 += __shfl_xor(ce1, 1);
    ce0 += __shfl_xor(ce0, 2); ce1 += __shfl_xor(ce1, 2);
    ce0 += __shfl_xor(ce0, 4); ce1 += __shfl_xor(ce1, 4);
    float lin0 = a1n[(size_t)se0 * NH + hh] + ce0 + c2b;
    float lin1 = a1n[(size_t)se1 * NH + hh] + ce1 + c2b;
    float lv0 = lin0 > 0.0f ? lin0 : 0.01f * lin0;
    float lv1 = lin1 > 0.0f ? lin1 : 0.01f * lin1;
    float mn = fmaxf(m, fmaxf(lv0, lv1));       // v_max3
    float corr = __expf(m - mn);
    float e0 = __expf(lv0 - mn);
    float e1 = __expf(lv1 - mn);
    s  = s  * corr + e0 + e1;
    a0 = a0 * corr + e0 * p00 + e1 * p10;
    a1 = a1 * corr + e0 * p01 + e1 * p11;
    m = mn;
  }
  // tail (odd degree)
  if (i < end) {
    int se = srcS[i];
    unsigned pe = *(const unsigned*)&eps[(size_t)i * FT + l * 2];
    unsigned pn = *(const unsigned*)&nsAll[(size_t)se * 256 + l * 2];
    float p0 = __uint_as_float(pe << 16)         + __uint_as_float(pn << 16);
    float p1 = __uint_as_float(pe & 0xFFFF0000u) + __uint_as_float(pn & 0xFFFF0000u);
    float ce = p0 * at0 + p1 * at1;
    ce += __shfl_xor(ce, 1);
    ce += __shfl_xor(ce, 2);
    ce += __shfl_xor(ce, 4);
    float lin = a1n[(size_t)se * NH + hh] + ce + c2b;
    float lv = lin > 0.0f ? lin : 0.01f * lin;
    float mn = fmaxf(m, lv);
    float corr = __expf(m - mn);
    float ev   = __expf(lv - mn);
    s  = s  * corr + ev;
    a0 = a0 * corr + ev * p0;
    a1 = a1 * corr + ev * p1;
    m = mn;
  }

  float2 nv = *(const float2*)&nft[(size_t)wid * FT + l * 2];
  float v0, v1;
  if (s > 0.0f) {
    float inv = 1.0f / s;
    unsigned pn2 = *(const unsigned*)&nsAll[(size_t)wid * 256 + 128 + l * 2];
    float2 bv = *(const float2*)&bp[l * 2];
    v0 = a0 * inv + __uint_as_float(pn2 << 16)         + bv.x + nv.x;
    v1 = a1 * inv + __uint_as_float(pn2 & 0xFFFF0000u) + bv.y + nv.y;
  } else {
    v0 = nv.x; v1 = nv.y;
  }
  float2 ov;
  ov.x = v0 > 0.0f ? v0 : 0.0f;
  ov.y = v1 > 0.0f ? v1 : 0.0f;
  *(float2*)&out[(size_t)wid * FT + l * 2] = ov;
}

extern "C" void kernel_launch(void* const* d_in, const int* in_sizes, int n_in,
                              void* d_out, int out_size, void* d_ws, size_t ws_size,
                              hipStream_t stream) {
  const float* nft = (const float*)d_in[0];
  const float* eft = (const float*)d_in[1];
  const float* Wp  = (const float*)d_in[2];
  const float* bp  = (const float*)d_in[3];
  const float* Wa1 = (const float*)d_in[4];
  const float* at2 = (const float*)d_in[5];
  const int*   src = (const int*)d_in[6];
  const int*   dst = (const int*)d_in[7];
  const int N = in_sizes[0] / FT;
  const int E = in_sizes[6];
  const int nb = (N + 255) / 256;

  char* ws = (char*)d_ws;
  size_t off = 0;
  ushort* eps = (ushort*)(ws + off);   off += (size_t)E * FT * sizeof(ushort);
  off = (off + 255) & ~(size_t)255;
  ushort* Wt1 = (ushort*)(ws + off);   off += (size_t)128 * 128 * sizeof(ushort);
  ushort* WtN = (ushort*)(ws + off);   off += (size_t)256 * 128 * sizeof(ushort);
  off = (off + 255) & ~(size_t)255;
  float* a1n = (float*)(ws + off);     off += (size_t)N * NH * sizeof(float);
  float* c2n = (float*)(ws + off);     off += (size_t)N * NH * sizeof(float);
  float* cb = (float*)(ws + off);      off += 256;
  ushort* nsAll = (ushort*)(ws + off); off += (size_t)N * 256 * sizeof(ushort);
  off = (off + 255) & ~(size_t)255;
  int* cnt = (int*)(ws + off);         off += (size_t)N * sizeof(int);
  int* ptr = (int*)(ws + off);         off += (size_t)(N + 1) * sizeof(int);
  int* cur = (int*)(ws + off);         off += (size_t)N * sizeof(int);
  int* bsum = (int*)(ws + off);        off += (size_t)nb * sizeof(int);
  int* boff = (int*)(ws + off);        off += (size_t)nb * sizeof(int);
  int* pos = (int*)(ws + off);         off += (size_t)E * sizeof(int);
  int* srcS = (int*)(ws + off);        off += (size_t)E * sizeof(int);

  int setup_n = (256 * 128 > N ? 256 * 128 : N);
  k_setup<<<(setup_n + 255) / 256, 256, 0, stream>>>(Wp, bp, at2, Wt1, WtN, cb, cnt, N);
  k_hist<<<(E + 255) / 256, 256, 0, stream>>>(dst, cnt, E);
  k_scan1<<<nb, 256, 0, stream>>>(cnt, bsum, N);
  k_scan2<<<1, 1024, 0, stream>>>(bsum, boff, ptr, nb, N);
  k_scan3<<<nb, 256, 0, stream>>>(cnt, boff, ptr, cur, N);
  k_fill<<<(E + 255) / 256, 256, 0, stream>>>(dst, src, cur, pos, srcS, E);

  k_node_mfma<<<(N + 63) / 64, 256, 0, stream>>>(nft, WtN, at2, Wa1, nsAll, c2n,
                                                 a1n, N);

  k_edge_mfma<<<(E + 63) / 64, 256, 0, stream>>>(eft, Wt1, pos, eps, E);

  k_aggregate<<<(N * 64 + 255) / 256, 256, 0, stream>>>(eps, nsAll, a1n, c2n, cb,
                                                        ptr, srcS, at2, bp,
                                                        nft, (float*)d_out, N);
}

// Round 14
// 150.429 us; speedup vs baseline: 5.5655x; 1.0437x over previous
//
#include <hip/hip_runtime.h>
#include <hip/hip_bf16.h>

#define FT 128
#define NH 8

typedef short bf16x8 __attribute__((ext_vector_type(8)));
typedef ushort u16x8 __attribute__((ext_vector_type(8)));
typedef float f32x4 __attribute__((ext_vector_type(4)));

__device__ __forceinline__ ushort f2bf(float f) {
  __hip_bfloat16 h = __float2bfloat16(f);
  return *reinterpret_cast<ushort*>(&h);
}
__device__ __forceinline__ float bf2f(ushort u) {
  return __uint_as_float(((unsigned)u) << 16);
}

// ---------------- setup: zero cnt + build Wt1/WtN (bf16 B-layout) + cb ----------------
__global__ void k_setup(const float* __restrict__ Wp, const float* __restrict__ bp,
                        const float* __restrict__ at2, ushort* __restrict__ Wt1,
                        ushort* __restrict__ WtN, float* __restrict__ cb,
                        int* __restrict__ cnt, int N) {
  int i = blockIdx.x * 256 + threadIdx.x;
  if (i < N) cnt[i] = 0;
  if (i < 128 * 128) {
    int c = i >> 7, k = i & 127;
    Wt1[i] = f2bf(Wp[(size_t)(128 + k) * 128 + c]);
  }
  if (i < 256 * 128) {
    int c = i >> 7, k = i & 127;
    float v = (c < 128) ? Wp[(size_t)k * 128 + c]
                        : Wp[(size_t)(256 + k) * 128 + (c - 128)];
    WtN[i] = f2bf(v);
  }
  if (i < NH) {
    float s = 0.0f;
    #pragma unroll
    for (int j = 0; j < 16; ++j) s += bp[i * 16 + j] * at2[i * 16 + j];
    cb[i] = s;
  }
}

// ---------------- CSR: histogram ----------------
__global__ void k_hist(const int* __restrict__ dst, int* __restrict__ cnt, int E) {
  int e = blockIdx.x * 256 + threadIdx.x;
  if (e < E) atomicAdd(&cnt[dst[e]], 1);
}

// ---------------- CSR: hierarchical scan ----------------
__global__ void k_scan1(const int* __restrict__ cnt, int* __restrict__ bsum, int N) {
  int i = blockIdx.x * 256 + threadIdx.x;
  int v = (i < N) ? cnt[i] : 0;
  #pragma unroll
  for (int o = 1; o < 64; o <<= 1) v += __shfl_xor(v, o);
  __shared__ int ws[4];
  if ((threadIdx.x & 63) == 0) ws[threadIdx.x >> 6] = v;
  __syncthreads();
  if (threadIdx.x == 0) bsum[blockIdx.x] = ws[0] + ws[1] + ws[2] + ws[3];
}

__global__ __launch_bounds__(1024) void k_scan2(const int* __restrict__ bsum,
                                                int* __restrict__ boff,
                                                int* __restrict__ ptr, int nb, int N) {
  __shared__ int buf[1024];
  int t = threadIdx.x;
  int v = (t < nb) ? bsum[t] : 0;
  buf[t] = v;
  __syncthreads();
  #pragma unroll
  for (int o = 1; o < 1024; o <<= 1) {
    int x = (t >= o) ? buf[t - o] : 0;
    __syncthreads();
    buf[t] += x;
    __syncthreads();
  }
  if (t < nb) boff[t] = buf[t] - v;
  if (t == nb - 1) ptr[N] = buf[t];
}

__global__ void k_scan3(const int* __restrict__ cnt, const int* __restrict__ boff,
                        int* __restrict__ ptr, int* __restrict__ cur, int N) {
  int i = blockIdx.x * 256 + threadIdx.x;
  int v = (i < N) ? cnt[i] : 0;
  int lane = threadIdx.x & 63, wv = threadIdx.x >> 6;
  int s = v;
  #pragma unroll
  for (int o = 1; o < 64; o <<= 1) {
    int x = __shfl_up(s, o);
    if (lane >= o) s += x;
  }
  __shared__ int wsum[4];
  if (lane == 63) wsum[wv] = s;
  __syncthreads();
  int add = 0;
  for (int k = 0; k < wv; ++k) add += wsum[k];
  int exc = boff[blockIdx.x] + add + s - v;
  if (i < N) { ptr[i] = exc; cur[i] = exc; }
}

// ---------------- CSR: fill inverse permutation pos + sorted src ----------------
__global__ void k_fill(const int* __restrict__ dst, const int* __restrict__ src,
                       int* __restrict__ cur, int* __restrict__ pos,
                       int* __restrict__ srcS, int E) {
  int e = blockIdx.x * 256 + threadIdx.x;
  if (e < E) {
    int p = atomicAdd(&cur[dst[e]], 1);
    pos[e] = p;
    srcS[p] = src[e];
  }
}

// ---------------- node GEMM: nsAll = nft@[W0|W2] bf16; c2n head-sums; a1n fused ----------------
__global__ __launch_bounds__(256) void k_node_mfma(
    const float* __restrict__ nft, const ushort* __restrict__ WtN,
    const float* __restrict__ at2, const float* __restrict__ Wa1,
    ushort* __restrict__ nsAll, float* __restrict__ c2n,
    float* __restrict__ a1n, int N)
{
  __shared__ ushort x[64][136];
  const int t = threadIdx.x;
  const int n0 = blockIdx.x * 64;

  // stage nft -> bf16 LDS, contiguous per-lane (8 floats each, 4 iters)
  #pragma unroll
  for (int r = 0; r < 4; ++r) {
    int idx = r * 2048 + t * 8;
    int ei = idx >> 7, c = idx & 127;
    const float* xr = nft + (size_t)min(n0 + ei, N - 1) * FT + c;
    float4 u = *(const float4*)xr;
    float4 v = *(const float4*)(xr + 4);
    u16x8 pk;
    pk[0] = f2bf(u.x); pk[1] = f2bf(u.y); pk[2] = f2bf(u.z); pk[3] = f2bf(u.w);
    pk[4] = f2bf(v.x); pk[5] = f2bf(v.y); pk[6] = f2bf(v.z); pk[7] = f2bf(v.w);
    *(u16x8*)&x[ei][c] = pk;
  }
  __syncthreads();

  const int w  = t >> 6;
  const int l  = t & 63;
  const int lr = l & 15;
  const int lk = l >> 4;

  bf16x8 breg[4][4];
  const ushort* wb = WtN + ((size_t)(w * 64 + lr) * 128 + lk * 8);
  #pragma unroll
  for (int ntl = 0; ntl < 4; ++ntl)
    #pragma unroll
    for (int ks = 0; ks < 4; ++ks)
      breg[ks][ntl] = *(const bf16x8*)(wb + (size_t)ntl * 16 * 128 + ks * 32);

  f32x4 acc[4][4];
  #pragma unroll
  for (int m = 0; m < 4; ++m)
    #pragma unroll
    for (int ntl = 0; ntl < 4; ++ntl) acc[m][ntl] = 0.0f;

  #pragma unroll
  for (int ks = 0; ks < 4; ++ks) {
    int kb = ks * 32 + lk * 8;
    #pragma unroll
    for (int m = 0; m < 4; ++m) {
      bf16x8 a = *(const bf16x8*)&x[m * 16 + lr][kb];
      #pragma unroll
      for (int ntl = 0; ntl < 4; ++ntl)
        acc[m][ntl] = __builtin_amdgcn_mfma_f32_16x16x32_bf16(a, breg[ks][ntl], acc[m][ntl], 0, 0, 0);
    }
  }

  #pragma unroll
  for (int ntl = 0; ntl < 4; ++ntl) {
    int col = w * 64 + ntl * 16 + lr;
    #pragma unroll
    for (int m = 0; m < 4; ++m) {
      int rb = m * 16 + lk * 4;
      f32x4 c = acc[m][ntl];
      #pragma unroll
      for (int r = 0; r < 4; ++r) {
        int node = n0 + rb + r;
        if (node < N) nsAll[(size_t)node * 256 + col] = f2bf(c[r]);
      }
      if (col >= 128) {   // c2n head-sums for the ns2 half only
        int head = (col & 127) >> 4;
        float a2v = at2[col & 127];
        float s0 = c[0] * a2v, s1 = c[1] * a2v, s2 = c[2] * a2v, s3 = c[3] * a2v;
        #pragma unroll
        for (int off = 1; off < 16; off <<= 1) {
          s0 += __shfl_xor(s0, off);
          s1 += __shfl_xor(s1, off);
          s2 += __shfl_xor(s2, off);
          s3 += __shfl_xor(s3, off);
        }
        if (lr == 0) {
          float sa[4] = {s0, s1, s2, s3};
          #pragma unroll
          for (int r = 0; r < 4; ++r) {
            int node = n0 + rb + r;
            if (node < N) c2n[(size_t)node * NH + head] = sa[r];
          }
        }
      }
    }
  }

  // fused a1n: node ei = t>>2, heads 2q, 2q+1 (from bf16-staged x)
  {
    int ei = t >> 2, q = t & 3;
    int node = n0 + ei;
    if (node < N) {
      float a0 = 0.0f, a1 = 0.0f;
      for (int k = 0; k < FT; ++k) {
        float xv = bf2f(x[ei][k]);
        a0 = fmaf(xv, Wa1[k * NH + 2 * q], a0);
        a1 = fmaf(xv, Wa1[k * NH + 2 * q + 1], a1);
      }
      a1n[(size_t)node * NH + 2 * q]     = a0;
      a1n[(size_t)node * NH + 2 * q + 1] = a1;
    }
  }
}

// ---------------- edge GEMM: 2 tiles/block, R12 data path (x + separate y), reg pos ----------------
__global__ __launch_bounds__(256) void k_edge_mfma(
    const float* __restrict__ eft, const ushort* __restrict__ Wt1,
    const int* __restrict__ pos, ushort* __restrict__ eps, int E)
{
  __shared__ ushort x[64][136];   // A tile bf16
  __shared__ ushort y[64][136];   // C staging (separate buffer: proven race-free path)

  const int t = threadIdx.x;
  const int w  = t >> 6;
  const int l  = t & 63;
  const int lr = l & 15;
  const int lk = l >> 4;
  const int erow = t >> 4;        // 0..15 (row sub-index for stage/store mapping)
  const int ccol = (t & 15) * 8;  // col block for stage/store mapping

  // B fragments: loaded ONCE for both tiles
  bf16x8 breg[4][2];
  const ushort* wb = Wt1 + ((size_t)(w * 32 + lr) * 128 + lk * 8);
  #pragma unroll
  for (int ks = 0; ks < 4; ++ks) {
    breg[ks][0] = *(const bf16x8*)(wb + ks * 32);
    breg[ks][1] = *(const bf16x8*)(wb + 16 * 128 + ks * 32);
  }

  #pragma unroll
  for (int tile = 0; tile < 2; ++tile) {
    const int e0 = (blockIdx.x * 2 + tile) * 64;

    // per-thread pos registers for the 4 rows this thread stores (broadcast loads)
    int pe[4];
    #pragma unroll
    for (int r = 0; r < 4; ++r) {
      int e = e0 + r * 16 + erow;
      pe[r] = (e < E) ? pos[e] : -1;
    }

    // ---- stage eft -> bf16 LDS: each lane 8 CONSECUTIVE floats ----
    #pragma unroll
    for (int r = 0; r < 4; ++r) {
      int ei = r * 16 + erow;
      const float* ef = eft + (size_t)min(e0 + ei, E - 1) * FT + ccol;
      float4 u = *(const float4*)ef;
      float4 v = *(const float4*)(ef + 4);
      u16x8 pk;
      pk[0] = f2bf(u.x); pk[1] = f2bf(u.y); pk[2] = f2bf(u.z); pk[3] = f2bf(u.w);
      pk[4] = f2bf(v.x); pk[5] = f2bf(v.y); pk[6] = f2bf(v.z); pk[7] = f2bf(v.w);
      *(u16x8*)&x[ei][ccol] = pk;
    }
    __syncthreads();   // bar1: x (tile) visible; also orders vs prev tile's y store-reads

    f32x4 acc[4][2];
    #pragma unroll
    for (int m = 0; m < 4; ++m) { acc[m][0] = 0.0f; acc[m][1] = 0.0f; }

    #pragma unroll
    for (int ks = 0; ks < 4; ++ks) {
      int kb = ks * 32 + lk * 8;
      #pragma unroll
      for (int m = 0; m < 4; ++m) {
        bf16x8 a = *(const bf16x8*)&x[m * 16 + lr][kb];
        acc[m][0] = __builtin_amdgcn_mfma_f32_16x16x32_bf16(a, breg[ks][0], acc[m][0], 0, 0, 0);
        acc[m][1] = __builtin_amdgcn_mfma_f32_16x16x32_bf16(a, breg[ks][1], acc[m][1], 0, 0, 0);
      }
    }

    // ---- C-stage into y (own data only; no barrier needed before writes) ----
    #pragma unroll
    for (int ntl = 0; ntl < 2; ++ntl) {
      int col = w * 32 + ntl * 16 + lr;
      #pragma unroll
      for (int m = 0; m < 4; ++m) {
        int rb = m * 16 + lk * 4;
        f32x4 c = acc[m][ntl];
        y[rb + 0][col] = f2bf(c[0]);
        y[rb + 1][col] = f2bf(c[1]);
        y[rb + 2][col] = f2bf(c[2]);
        y[rb + 3][col] = f2bf(c[3]);
      }
    }
    __syncthreads();   // bar2: y visible; all waves' MFMA x-reads complete

    // ---- scatter store: 16 lanes cover one 256B row contiguously ----
    #pragma unroll
    for (int r = 0; r < 4; ++r) {
      int ei = r * 16 + erow;
      if (pe[r] >= 0) {
        u16x8 vv = *(const u16x8*)&y[ei][ccol];
        *(u16x8*)&eps[(size_t)pe[r] * FT + ccol] = vv;
      }
    }
    // no barrier here: next tile's stage writes x (reads done at bar2),
    // next y writes happen only after next bar1.
  }
}

// ---------------- aggregate: wave-per-node, 2x-unrolled online softmax ----------------
__global__ __launch_bounds__(256) void k_aggregate(
    const ushort* __restrict__ eps, const ushort* __restrict__ nsAll,
    const float* __restrict__ a1n, const float* __restrict__ c2n,
    const float* __restrict__ cb, const int* __restrict__ ptr,
    const int* __restrict__ srcS, const float* __restrict__ at2,
    const float* __restrict__ bp, const float* __restrict__ nft,
    float* __restrict__ out, int N)
{
  int wid = (blockIdx.x * 256 + threadIdx.x) >> 6;
  int l = threadIdx.x & 63;
  if (wid >= N) return;
  int beg = ptr[wid], end = ptr[wid + 1];
  int hh = l >> 3;
  float at0 = at2[l * 2], at1 = at2[l * 2 + 1];
  float c2b = c2n[(size_t)wid * NH + hh] + cb[hh];

  float m = -INFINITY, s = 0.0f, a0 = 0.0f, a1 = 0.0f;
  int i = beg;

  for (; i + 1 < end; i += 2) {
    int se0 = srcS[i];
    int se1 = srcS[i + 1];
    unsigned pe0 = *(const unsigned*)&eps[(size_t)i * FT + l * 2];
    unsigned pe1 = *(const unsigned*)&eps[(size_t)(i + 1) * FT + l * 2];
    unsigned pn0 = *(const unsigned*)&nsAll[(size_t)se0 * 256 + l * 2];
    unsigned pn1 = *(const unsigned*)&nsAll[(size_t)se1 * 256 + l * 2];
    float p00 = __uint_as_float(pe0 << 16)         + __uint_as_float(pn0 << 16);
    float p01 = __uint_as_float(pe0 & 0xFFFF0000u) + __uint_as_float(pn0 & 0xFFFF0000u);
    float p10 = __uint_as_float(pe1 << 16)         + __uint_as_float(pn1 << 16);
    float p11 = __uint_as_float(pe1 & 0xFFFF0000u) + __uint_as_float(pn1 & 0xFFFF0000u);
    float ce0 = p00 * at0 + p01 * at1;
    float ce1 = p10 * at0 + p11 * at1;
    ce0 += __shfl_xor(ce0, 1); ce1 += __shfl_xor(ce1, 1);
    ce0 += __shfl_xor(ce0, 2); ce1 += __shfl_xor(ce1, 2);
    ce0 += __shfl_xor(ce0, 4); ce1 += __shfl_xor(ce1, 4);
    float lin0 = a1n[(size_t)se0 * NH + hh] + ce0 + c2b;
    float lin1 = a1n[(size_t)se1 * NH + hh] + ce1 + c2b;
    float lv0 = lin0 > 0.0f ? lin0 : 0.01f * lin0;
    float lv1 = lin1 > 0.0f ? lin1 : 0.01f * lin1;
    float mn = fmaxf(m, fmaxf(lv0, lv1));
    float corr = __expf(m - mn);
    float e0 = __expf(lv0 - mn);
    float e1 = __expf(lv1 - mn);
    s  = s  * corr + e0 + e1;
    a0 = a0 * corr + e0 * p00 + e1 * p10;
    a1 = a1 * corr + e0 * p01 + e1 * p11;
    m = mn;
  }
  if (i < end) {
    int se = srcS[i];
    unsigned pe = *(const unsigned*)&eps[(size_t)i * FT + l * 2];
    unsigned pn = *(const unsigned*)&nsAll[(size_t)se * 256 + l * 2];
    float p0 = __uint_as_float(pe << 16)         + __uint_as_float(pn << 16);
    float p1 = __uint_as_float(pe & 0xFFFF0000u) + __uint_as_float(pn & 0xFFFF0000u);
    float ce = p0 * at0 + p1 * at1;
    ce += __shfl_xor(ce, 1);
    ce += __shfl_xor(ce, 2);
    ce += __shfl_xor(ce, 4);
    float lin = a1n[(size_t)se * NH + hh] + ce + c2b;
    float lv = lin > 0.0f ? lin : 0.01f * lin;
    float mn = fmaxf(m, lv);
    float corr = __expf(m - mn);
    float ev   = __expf(lv - mn);
    s  = s  * corr + ev;
    a0 = a0 * corr + ev * p0;
    a1 = a1 * corr + ev * p1;
    m = mn;
  }

  float2 nv = *(const float2*)&nft[(size_t)wid * FT + l * 2];
  float v0, v1;
  if (s > 0.0f) {
    float inv = 1.0f / s;
    unsigned pn2 = *(const unsigned*)&nsAll[(size_t)wid * 256 + 128 + l * 2];
    float2 bv = *(const float2*)&bp[l * 2];
    v0 = a0 * inv + __uint_as_float(pn2 << 16)         + bv.x + nv.x;
    v1 = a1 * inv + __uint_as_float(pn2 & 0xFFFF0000u) + bv.y + nv.y;
  } else {
    v0 = nv.x; v1 = nv.y;
  }
  float2 ov;
  ov.x = v0 > 0.0f ? v0 : 0.0f;
  ov.y = v1 > 0.0f ? v1 : 0.0f;
  *(float2*)&out[(size_t)wid * FT + l * 2] = ov;
}

extern "C" void kernel_launch(void* const* d_in, const int* in_sizes, int n_in,
                              void* d_out, int out_size, void* d_ws, size_t ws_size,
                              hipStream_t stream) {
  const float* nft = (const float*)d_in[0];
  const float* eft = (const float*)d_in[1];
  const float* Wp  = (const float*)d_in[2];
  const float* bp  = (const float*)d_in[3];
  const float* Wa1 = (const float*)d_in[4];
  const float* at2 = (const float*)d_in[5];
  const int*   src = (const int*)d_in[6];
  const int*   dst = (const int*)d_in[7];
  const int N = in_sizes[0] / FT;
  const int E = in_sizes[6];
  const int nb = (N + 255) / 256;

  char* ws = (char*)d_ws;
  size_t off = 0;
  ushort* eps = (ushort*)(ws + off);   off += (size_t)E * FT * sizeof(ushort);
  off = (off + 255) & ~(size_t)255;
  ushort* Wt1 = (ushort*)(ws + off);   off += (size_t)128 * 128 * sizeof(ushort);
  ushort* WtN = (ushort*)(ws + off);   off += (size_t)256 * 128 * sizeof(ushort);
  off = (off + 255) & ~(size_t)255;
  float* a1n = (float*)(ws + off);     off += (size_t)N * NH * sizeof(float);
  float* c2n = (float*)(ws + off);     off += (size_t)N * NH * sizeof(float);
  float* cb = (float*)(ws + off);      off += 256;
  ushort* nsAll = (ushort*)(ws + off); off += (size_t)N * 256 * sizeof(ushort);
  off = (off + 255) & ~(size_t)255;
  int* cnt = (int*)(ws + off);         off += (size_t)N * sizeof(int);
  int* ptr = (int*)(ws + off);         off += (size_t)(N + 1) * sizeof(int);
  int* cur = (int*)(ws + off);         off += (size_t)N * sizeof(int);
  int* bsum = (int*)(ws + off);        off += (size_t)nb * sizeof(int);
  int* boff = (int*)(ws + off);        off += (size_t)nb * sizeof(int);
  int* pos = (int*)(ws + off);         off += (size_t)E * sizeof(int);
  int* srcS = (int*)(ws + off);        off += (size_t)E * sizeof(int);

  int setup_n = (256 * 128 > N ? 256 * 128 : N);
  k_setup<<<(setup_n + 255) / 256, 256, 0, stream>>>(Wp, bp, at2, Wt1, WtN, cb, cnt, N);
  k_hist<<<(E + 255) / 256, 256, 0, stream>>>(dst, cnt, E);
  k_scan1<<<nb, 256, 0, stream>>>(cnt, bsum, N);
  k_scan2<<<1, 1024, 0, stream>>>(bsum, boff, ptr, nb, N);
  k_scan3<<<nb, 256, 0, stream>>>(cnt, boff, ptr, cur, N);
  k_fill<<<(E + 255) / 256, 256, 0, stream>>>(dst, src, cur, pos, srcS, E);

  k_node_mfma<<<(N + 63) / 64, 256, 0, stream>>>(nft, WtN, at2, Wa1, nsAll, c2n,
                                                 a1n, N);

  k_edge_mfma<<<(E + 127) / 128, 256, 0, stream>>>(eft, Wt1, pos, eps, E);

  k_aggregate<<<(N * 64 + 255) / 256, 256, 0, stream>>>(eps, nsAll, a1n, c2n, cb,
                                                        ptr, srcS, at2, bp,
                                                        nft, (float*)d_out, N);
}

// Round 15
// 149.754 us; speedup vs baseline: 5.5905x; 1.0045x over previous
//
#include <hip/hip_runtime.h>
#include <hip/hip_bf16.h>

#define FT 128
#define NH 8

typedef short bf16x8 __attribute__((ext_vector_type(8)));
typedef ushort u16x8 __attribute__((ext_vector_type(8)));
typedef float f32x4 __attribute__((ext_vector_type(4)));

__device__ __forceinline__ ushort f2bf(float f) {
  __hip_bfloat16 h = __float2bfloat16(f);
  return *reinterpret_cast<ushort*>(&h);
}
__device__ __forceinline__ float bf2f(ushort u) {
  return __uint_as_float(((unsigned)u) << 16);
}

// ---------------- setup: zero cnt + build Wt1/WtN (bf16 B-layout) + cb ----------------
__global__ void k_setup(const float* __restrict__ Wp, const float* __restrict__ bp,
                        const float* __restrict__ at2, ushort* __restrict__ Wt1,
                        ushort* __restrict__ WtN, float* __restrict__ cb,
                        int* __restrict__ cnt, int N) {
  int i = blockIdx.x * 256 + threadIdx.x;
  if (i < N) cnt[i] = 0;
  if (i < 128 * 128) {
    int c = i >> 7, k = i & 127;
    Wt1[i] = f2bf(Wp[(size_t)(128 + k) * 128 + c]);
  }
  if (i < 256 * 128) {
    int c = i >> 7, k = i & 127;
    float v = (c < 128) ? Wp[(size_t)k * 128 + c]
                        : Wp[(size_t)(256 + k) * 128 + (c - 128)];
    WtN[i] = f2bf(v);
  }
  if (i < NH) {
    float s = 0.0f;
    #pragma unroll
    for (int j = 0; j < 16; ++j) s += bp[i * 16 + j] * at2[i * 16 + j];
    cb[i] = s;
  }
}

// ---------------- CSR: histogram ----------------
__global__ void k_hist(const int* __restrict__ dst, int* __restrict__ cnt, int E) {
  int e = blockIdx.x * 256 + threadIdx.x;
  if (e < E) atomicAdd(&cnt[dst[e]], 1);
}

// ---------------- CSR: hierarchical scan ----------------
__global__ void k_scan1(const int* __restrict__ cnt, int* __restrict__ bsum, int N) {
  int i = blockIdx.x * 256 + threadIdx.x;
  int v = (i < N) ? cnt[i] : 0;
  #pragma unroll
  for (int o = 1; o < 64; o <<= 1) v += __shfl_xor(v, o);
  __shared__ int ws[4];
  if ((threadIdx.x & 63) == 0) ws[threadIdx.x >> 6] = v;
  __syncthreads();
  if (threadIdx.x == 0) bsum[blockIdx.x] = ws[0] + ws[1] + ws[2] + ws[3];
}

__global__ __launch_bounds__(1024) void k_scan2(const int* __restrict__ bsum,
                                                int* __restrict__ boff,
                                                int* __restrict__ ptr, int nb, int N) {
  __shared__ int buf[1024];
  int t = threadIdx.x;
  int v = (t < nb) ? bsum[t] : 0;
  buf[t] = v;
  __syncthreads();
  #pragma unroll
  for (int o = 1; o < 1024; o <<= 1) {
    int x = (t >= o) ? buf[t - o] : 0;
    __syncthreads();
    buf[t] += x;
    __syncthreads();
  }
  if (t < nb) boff[t] = buf[t] - v;
  if (t == nb - 1) ptr[N] = buf[t];
}

__global__ void k_scan3(const int* __restrict__ cnt, const int* __restrict__ boff,
                        int* __restrict__ ptr, int* __restrict__ cur, int N) {
  int i = blockIdx.x * 256 + threadIdx.x;
  int v = (i < N) ? cnt[i] : 0;
  int lane = threadIdx.x & 63, wv = threadIdx.x >> 6;
  int s = v;
  #pragma unroll
  for (int o = 1; o < 64; o <<= 1) {
    int x = __shfl_up(s, o);
    if (lane >= o) s += x;
  }
  __shared__ int wsum[4];
  if (lane == 63) wsum[wv] = s;
  __syncthreads();
  int add = 0;
  for (int k = 0; k < wv; ++k) add += wsum[k];
  int exc = boff[blockIdx.x] + add + s - v;
  if (i < N) { ptr[i] = exc; cur[i] = exc; }
}

// ---------------- CSR: fill inverse permutation pos + sorted src ----------------
__global__ void k_fill(const int* __restrict__ dst, const int* __restrict__ src,
                       int* __restrict__ cur, int* __restrict__ pos,
                       int* __restrict__ srcS, int E) {
  int e = blockIdx.x * 256 + threadIdx.x;
  if (e < E) {
    int p = atomicAdd(&cur[dst[e]], 1);
    pos[e] = p;
    srcS[p] = src[e];
  }
}

// ---------------- node GEMM: nsAll = nft@[W0|W2] bf16; c2n head-sums; a1n fused ----------------
__global__ __launch_bounds__(256) void k_node_mfma(
    const float* __restrict__ nft, const ushort* __restrict__ WtN,
    const float* __restrict__ at2, const float* __restrict__ Wa1,
    ushort* __restrict__ nsAll, float* __restrict__ c2n,
    float* __restrict__ a1n, int N)
{
  __shared__ ushort x[64][136];
  const int t = threadIdx.x;
  const int n0 = blockIdx.x * 64;

  // stage nft -> bf16 LDS, contiguous per-lane (8 floats each, 4 iters)
  #pragma unroll
  for (int r = 0; r < 4; ++r) {
    int idx = r * 2048 + t * 8;
    int ei = idx >> 7, c = idx & 127;
    const float* xr = nft + (size_t)min(n0 + ei, N - 1) * FT + c;
    float4 u = *(const float4*)xr;
    float4 v = *(const float4*)(xr + 4);
    u16x8 pk;
    pk[0] = f2bf(u.x); pk[1] = f2bf(u.y); pk[2] = f2bf(u.z); pk[3] = f2bf(u.w);
    pk[4] = f2bf(v.x); pk[5] = f2bf(v.y); pk[6] = f2bf(v.z); pk[7] = f2bf(v.w);
    *(u16x8*)&x[ei][c] = pk;
  }
  __syncthreads();

  const int w  = t >> 6;
  const int l  = t & 63;
  const int lr = l & 15;
  const int lk = l >> 4;

  bf16x8 breg[4][4];
  const ushort* wb = WtN + ((size_t)(w * 64 + lr) * 128 + lk * 8);
  #pragma unroll
  for (int ntl = 0; ntl < 4; ++ntl)
    #pragma unroll
    for (int ks = 0; ks < 4; ++ks)
      breg[ks][ntl] = *(const bf16x8*)(wb + (size_t)ntl * 16 * 128 + ks * 32);

  f32x4 acc[4][4];
  #pragma unroll
  for (int m = 0; m < 4; ++m)
    #pragma unroll
    for (int ntl = 0; ntl < 4; ++ntl) acc[m][ntl] = 0.0f;

  #pragma unroll
  for (int ks = 0; ks < 4; ++ks) {
    int kb = ks * 32 + lk * 8;
    #pragma unroll
    for (int m = 0; m < 4; ++m) {
      bf16x8 a = *(const bf16x8*)&x[m * 16 + lr][kb];
      #pragma unroll
      for (int ntl = 0; ntl < 4; ++ntl)
        acc[m][ntl] = __builtin_amdgcn_mfma_f32_16x16x32_bf16(a, breg[ks][ntl], acc[m][ntl], 0, 0, 0);
    }
  }

  #pragma unroll
  for (int ntl = 0; ntl < 4; ++ntl) {
    int col = w * 64 + ntl * 16 + lr;
    #pragma unroll
    for (int m = 0; m < 4; ++m) {
      int rb = m * 16 + lk * 4;
      f32x4 c = acc[m][ntl];
      #pragma unroll
      for (int r = 0; r < 4; ++r) {
        int node = n0 + rb + r;
        if (node < N) nsAll[(size_t)node * 256 + col] = f2bf(c[r]);
      }
      if (col >= 128) {   // c2n head-sums for the ns2 half only
        int head = (col & 127) >> 4;
        float a2v = at2[col & 127];
        float s0 = c[0] * a2v, s1 = c[1] * a2v, s2 = c[2] * a2v, s3 = c[3] * a2v;
        #pragma unroll
        for (int off = 1; off < 16; off <<= 1) {
          s0 += __shfl_xor(s0, off);
          s1 += __shfl_xor(s1, off);
          s2 += __shfl_xor(s2, off);
          s3 += __shfl_xor(s3, off);
        }
        if (lr == 0) {
          float sa[4] = {s0, s1, s2, s3};
          #pragma unroll
          for (int r = 0; r < 4; ++r) {
            int node = n0 + rb + r;
            if (node < N) c2n[(size_t)node * NH + head] = sa[r];
          }
        }
      }
    }
  }

  // fused a1n: node ei = t>>2, heads 2q, 2q+1 — vectorized LDS reads (u16x8)
  {
    int ei = t >> 2, q = t & 3;
    int node = n0 + ei;
    if (node < N) {
      float a0 = 0.0f, a1 = 0.0f;
      for (int kb = 0; kb < FT; kb += 8) {
        u16x8 xv8 = *(const u16x8*)&x[ei][kb];
        #pragma unroll
        for (int j = 0; j < 8; ++j) {
          float xv = bf2f(xv8[j]);
          a0 = fmaf(xv, Wa1[(kb + j) * NH + 2 * q], a0);
          a1 = fmaf(xv, Wa1[(kb + j) * NH + 2 * q + 1], a1);
        }
      }
      a1n[(size_t)node * NH + 2 * q]     = a0;
      a1n[(size_t)node * NH + 2 * q + 1] = a1;
    }
  }
}

// ---------------- edge GEMM: 4 tiles/block, R12/R14 data path (x + separate y), reg pos ----------------
__global__ __launch_bounds__(256) void k_edge_mfma(
    const float* __restrict__ eft, const ushort* __restrict__ Wt1,
    const int* __restrict__ pos, ushort* __restrict__ eps, int E)
{
  __shared__ ushort x[64][136];   // A tile bf16
  __shared__ ushort y[64][136];   // C staging (separate buffer: proven race-free path)

  const int t = threadIdx.x;
  const int w  = t >> 6;
  const int l  = t & 63;
  const int lr = l & 15;
  const int lk = l >> 4;
  const int erow = t >> 4;        // 0..15
  const int ccol = (t & 15) * 8;  // col block

  // B fragments: loaded ONCE for all 4 tiles
  bf16x8 breg[4][2];
  const ushort* wb = Wt1 + ((size_t)(w * 32 + lr) * 128 + lk * 8);
  #pragma unroll
  for (int ks = 0; ks < 4; ++ks) {
    breg[ks][0] = *(const bf16x8*)(wb + ks * 32);
    breg[ks][1] = *(const bf16x8*)(wb + 16 * 128 + ks * 32);
  }

  #pragma unroll
  for (int tile = 0; tile < 4; ++tile) {
    const int e0 = (blockIdx.x * 4 + tile) * 64;

    int pe[4];
    #pragma unroll
    for (int r = 0; r < 4; ++r) {
      int e = e0 + r * 16 + erow;
      pe[r] = (e < E) ? pos[e] : -1;
    }

    // ---- stage eft -> bf16 LDS: each lane 8 CONSECUTIVE floats ----
    #pragma unroll
    for (int r = 0; r < 4; ++r) {
      int ei = r * 16 + erow;
      const float* ef = eft + (size_t)min(e0 + ei, E - 1) * FT + ccol;
      float4 u = *(const float4*)ef;
      float4 v = *(const float4*)(ef + 4);
      u16x8 pk;
      pk[0] = f2bf(u.x); pk[1] = f2bf(u.y); pk[2] = f2bf(u.z); pk[3] = f2bf(u.w);
      pk[4] = f2bf(v.x); pk[5] = f2bf(v.y); pk[6] = f2bf(v.z); pk[7] = f2bf(v.w);
      *(u16x8*)&x[ei][ccol] = pk;
    }
    __syncthreads();   // bar1: x visible; orders vs prev tile's y store-reads

    f32x4 acc[4][2];
    #pragma unroll
    for (int m = 0; m < 4; ++m) { acc[m][0] = 0.0f; acc[m][1] = 0.0f; }

    #pragma unroll
    for (int ks = 0; ks < 4; ++ks) {
      int kb = ks * 32 + lk * 8;
      #pragma unroll
      for (int m = 0; m < 4; ++m) {
        bf16x8 a = *(const bf16x8*)&x[m * 16 + lr][kb];
        acc[m][0] = __builtin_amdgcn_mfma_f32_16x16x32_bf16(a, breg[ks][0], acc[m][0], 0, 0, 0);
        acc[m][1] = __builtin_amdgcn_mfma_f32_16x16x32_bf16(a, breg[ks][1], acc[m][1], 0, 0, 0);
      }
    }

    // ---- C-stage into y (own data only) ----
    #pragma unroll
    for (int ntl = 0; ntl < 2; ++ntl) {
      int col = w * 32 + ntl * 16 + lr;
      #pragma unroll
      for (int m = 0; m < 4; ++m) {
        int rb = m * 16 + lk * 4;
        f32x4 c = acc[m][ntl];
        y[rb + 0][col] = f2bf(c[0]);
        y[rb + 1][col] = f2bf(c[1]);
        y[rb + 2][col] = f2bf(c[2]);
        y[rb + 3][col] = f2bf(c[3]);
      }
    }
    __syncthreads();   // bar2: y visible; all waves' MFMA x-reads complete

    // ---- scatter store: 16 lanes cover one 256B row contiguously ----
    #pragma unroll
    for (int r = 0; r < 4; ++r) {
      int ei = r * 16 + erow;
      if (pe[r] >= 0) {
        u16x8 vv = *(const u16x8*)&y[ei][ccol];
        *(u16x8*)&eps[(size_t)pe[r] * FT + ccol] = vv;
      }
    }
  }
}

// ---------------- aggregate: wave-per-node, 4x-unrolled online softmax ----------------
__global__ __launch_bounds__(256) void k_aggregate(
    const ushort* __restrict__ eps, const ushort* __restrict__ nsAll,
    const float* __restrict__ a1n, const float* __restrict__ c2n,
    const float* __restrict__ cb, const int* __restrict__ ptr,
    const int* __restrict__ srcS, const float* __restrict__ at2,
    const float* __restrict__ bp, const float* __restrict__ nft,
    float* __restrict__ out, int N)
{
  int wid = (blockIdx.x * 256 + threadIdx.x) >> 6;
  int l = threadIdx.x & 63;
  if (wid >= N) return;
  int beg = ptr[wid], end = ptr[wid + 1];
  int hh = l >> 3;
  float at0 = at2[l * 2], at1 = at2[l * 2 + 1];
  float c2b = c2n[(size_t)wid * NH + hh] + cb[hh];

  float m = -INFINITY, s = 0.0f, a0 = 0.0f, a1 = 0.0f;
  int i = beg;

  // 4x unrolled: 4 independent gathers in flight, one corr per 4 edges
  for (; i + 3 < end; i += 4) {
    int se0 = srcS[i],     se1 = srcS[i + 1];
    int se2 = srcS[i + 2], se3 = srcS[i + 3];
    unsigned pe0 = *(const unsigned*)&eps[(size_t)i * FT + l * 2];
    unsigned pe1 = *(const unsigned*)&eps[(size_t)(i + 1) * FT + l * 2];
    unsigned pe2 = *(const unsigned*)&eps[(size_t)(i + 2) * FT + l * 2];
    unsigned pe3 = *(const unsigned*)&eps[(size_t)(i + 3) * FT + l * 2];
    unsigned pn0 = *(const unsigned*)&nsAll[(size_t)se0 * 256 + l * 2];
    unsigned pn1 = *(const unsigned*)&nsAll[(size_t)se1 * 256 + l * 2];
    unsigned pn2 = *(const unsigned*)&nsAll[(size_t)se2 * 256 + l * 2];
    unsigned pn3 = *(const unsigned*)&nsAll[(size_t)se3 * 256 + l * 2];
    float p00 = __uint_as_float(pe0 << 16)         + __uint_as_float(pn0 << 16);
    float p01 = __uint_as_float(pe0 & 0xFFFF0000u) + __uint_as_float(pn0 & 0xFFFF0000u);
    float p10 = __uint_as_float(pe1 << 16)         + __uint_as_float(pn1 << 16);
    float p11 = __uint_as_float(pe1 & 0xFFFF0000u) + __uint_as_float(pn1 & 0xFFFF0000u);
    float p20 = __uint_as_float(pe2 << 16)         + __uint_as_float(pn2 << 16);
    float p21 = __uint_as_float(pe2 & 0xFFFF0000u) + __uint_as_float(pn2 & 0xFFFF0000u);
    float p30 = __uint_as_float(pe3 << 16)         + __uint_as_float(pn3 << 16);
    float p31 = __uint_as_float(pe3 & 0xFFFF0000u) + __uint_as_float(pn3 & 0xFFFF0000u);
    float ce0 = p00 * at0 + p01 * at1;
    float ce1 = p10 * at0 + p11 * at1;
    float ce2 = p20 * at0 + p21 * at1;
    float ce3 = p30 * at0 + p31 * at1;
    ce0 += __shfl_xor(ce0, 1); ce1 += __shfl_xor(ce1, 1);
    ce2 += __shfl_xor(ce2, 1); ce3 += __shfl_xor(ce3, 1);
    ce0 += __shfl_xor(ce0, 2); ce1 += __shfl_xor(ce1, 2);
    ce2 += __shfl_xor(ce2, 2); ce3 += __shfl_xor(ce3, 2);
    ce0 += __shfl_xor(ce0, 4); ce1 += __shfl_xor(ce1, 4);
    ce2 += __shfl_xor(ce2, 4); ce3 += __shfl_xor(ce3, 4);
    float lin0 = a1n[(size_t)se0 * NH + hh] + ce0 + c2b;
    float lin1 = a1n[(size_t)se1 * NH + hh] + ce1 + c2b;
    float lin2 = a1n[(size_t)se2 * NH + hh] + ce2 + c2b;
    float lin3 = a1n[(size_t)se3 * NH + hh] + ce3 + c2b;
    float lv0 = lin0 > 0.0f ? lin0 : 0.01f * lin0;
    float lv1 = lin1 > 0.0f ? lin1 : 0.01f * lin1;
    float lv2 = lin2 > 0.0f ? lin2 : 0.01f * lin2;
    float lv3 = lin3 > 0.0f ? lin3 : 0.01f * lin3;
    float mn = fmaxf(fmaxf(m, fmaxf(lv0, lv1)), fmaxf(lv2, lv3));
    float corr = __expf(m - mn);
    float e0 = __expf(lv0 - mn);
    float e1 = __expf(lv1 - mn);
    float e2 = __expf(lv2 - mn);
    float e3 = __expf(lv3 - mn);
    s  = s  * corr + e0 + e1 + e2 + e3;
    a0 = a0 * corr + e0 * p00 + e1 * p10 + e2 * p20 + e3 * p30;
    a1 = a1 * corr + e0 * p01 + e1 * p11 + e2 * p21 + e3 * p31;
    m = mn;
  }
  // 2-wide mid-tail
  for (; i + 1 < end; i += 2) {
    int se0 = srcS[i];
    int se1 = srcS[i + 1];
    unsigned pe0 = *(const unsigned*)&eps[(size_t)i * FT + l * 2];
    unsigned pe1 = *(const unsigned*)&eps[(size_t)(i + 1) * FT + l * 2];
    unsigned pn0 = *(const unsigned*)&nsAll[(size_t)se0 * 256 + l * 2];
    unsigned pn1 = *(const unsigned*)&nsAll[(size_t)se1 * 256 + l * 2];
    float p00 = __uint_as_float(pe0 << 16)         + __uint_as_float(pn0 << 16);
    float p01 = __uint_as_float(pe0 & 0xFFFF0000u) + __uint_as_float(pn0 & 0xFFFF0000u);
    float p10 = __uint_as_float(pe1 << 16)         + __uint_as_float(pn1 << 16);
    float p11 = __uint_as_float(pe1 & 0xFFFF0000u) + __uint_as_float(pn1 & 0xFFFF0000u);
    float ce0 = p00 * at0 + p01 * at1;
    float ce1 = p10 * at0 + p11 * at1;
    ce0 += __shfl_xor(ce0, 1); ce1 += __shfl_xor(ce1, 1);
    ce0 += __shfl_xor(ce0, 2); ce1 += __shfl_xor(ce1, 2);
    ce0 += __shfl_xor(ce0, 4); ce1 += __shfl_xor(ce1, 4);
    float lin0 = a1n[(size_t)se0 * NH + hh] + ce0 + c2b;
    float lin1 = a1n[(size_t)se1 * NH + hh] + ce1 + c2b;
    float lv0 = lin0 > 0.0f ? lin0 : 0.01f * lin0;
    float lv1 = lin1 > 0.0f ? lin1 : 0.01f * lin1;
    float mn = fmaxf(m, fmaxf(lv0, lv1));
    float corr = __expf(m - mn);
    float e0 = __expf(lv0 - mn);
    float e1 = __expf(lv1 - mn);
    s  = s  * corr + e0 + e1;
    a0 = a0 * corr + e0 * p00 + e1 * p10;
    a1 = a1 * corr + e0 * p01 + e1 * p11;
    m = mn;
  }
  if (i < end) {
    int se = srcS[i];
    unsigned pe = *(const unsigned*)&eps[(size_t)i * FT + l * 2];
    unsigned pn = *(const unsigned*)&nsAll[(size_t)se * 256 + l * 2];
    float p0 = __uint_as_float(pe << 16)         + __uint_as_float(pn << 16);
    float p1 = __uint_as_float(pe & 0xFFFF0000u) + __uint_as_float(pn & 0xFFFF0000u);
    float ce = p0 * at0 + p1 * at1;
    ce += __shfl_xor(ce, 1);
    ce += __shfl_xor(ce, 2);
    ce += __shfl_xor(ce, 4);
    float lin = a1n[(size_t)se * NH + hh] + ce + c2b;
    float lv = lin > 0.0f ? lin : 0.01f * lin;
    float mn = fmaxf(m, lv);
    float corr = __expf(m - mn);
    float ev   = __expf(lv - mn);
    s  = s  * corr + ev;
    a0 = a0 * corr + ev * p0;
    a1 = a1 * corr + ev * p1;
    m = mn;
  }

  float2 nv = *(const float2*)&nft[(size_t)wid * FT + l * 2];
  float v0, v1;
  if (s > 0.0f) {
    float inv = 1.0f / s;
    unsigned pn2 = *(const unsigned*)&nsAll[(size_t)wid * 256 + 128 + l * 2];
    float2 bv = *(const float2*)&bp[l * 2];
    v0 = a0 * inv + __uint_as_float(pn2 << 16)         + bv.x + nv.x;
    v1 = a1 * inv + __uint_as_float(pn2 & 0xFFFF0000u) + bv.y + nv.y;
  } else {
    v0 = nv.x; v1 = nv.y;
  }
  float2 ov;
  ov.x = v0 > 0.0f ? v0 : 0.0f;
  ov.y = v1 > 0.0f ? v1 : 0.0f;
  *(float2*)&out[(size_t)wid * FT + l * 2] = ov;
}

extern "C" void kernel_launch(void* const* d_in, const int* in_sizes, int n_in,
                              void* d_out, int out_size, void* d_ws, size_t ws_size,
                              hipStream_t stream) {
  const float* nft = (const float*)d_in[0];
  const float* eft = (const float*)d_in[1];
  const float* Wp  = (const float*)d_in[2];
  const float* bp  = (const float*)d_in[3];
  const float* Wa1 = (const float*)d_in[4];
  const float* at2 = (const float*)d_in[5];
  const int*   src = (const int*)d_in[6];
  const int*   dst = (const int*)d_in[7];
  const int N = in_sizes[0] / FT;
  const int E = in_sizes[6];
  const int nb = (N + 255) / 256;

  char* ws = (char*)d_ws;
  size_t off = 0;
  ushort* eps = (ushort*)(ws + off);   off += (size_t)E * FT * sizeof(ushort);
  off = (off + 255) & ~(size_t)255;
  ushort* Wt1 = (ushort*)(ws + off);   off += (size_t)128 * 128 * sizeof(ushort);
  ushort* WtN = (ushort*)(ws + off);   off += (size_t)256 * 128 * sizeof(ushort);
  off = (off + 255) & ~(size_t)255;
  float* a1n = (float*)(ws + off);     off += (size_t)N * NH * sizeof(float);
  float* c2n = (float*)(ws + off);     off += (size_t)N * NH * sizeof(float);
  float* cb = (float*)(ws + off);      off += 256;
  ushort* nsAll = (ushort*)(ws + off); off += (size_t)N * 256 * sizeof(ushort);
  off = (off + 255) & ~(size_t)255;
  int* cnt = (int*)(ws + off);         off += (size_t)N * sizeof(int);
  int* ptr = (int*)(ws + off);         off += (size_t)(N + 1) * sizeof(int);
  int* cur = (int*)(ws + off);         off += (size_t)N * sizeof(int);
  int* bsum = (int*)(ws + off);        off += (size_t)nb * sizeof(int);
  int* boff = (int*)(ws + off);        off += (size_t)nb * sizeof(int);
  int* pos = (int*)(ws + off);         off += (size_t)E * sizeof(int);
  int* srcS = (int*)(ws + off);        off += (size_t)E * sizeof(int);

  int setup_n = (256 * 128 > N ? 256 * 128 : N);
  k_setup<<<(setup_n + 255) / 256, 256, 0, stream>>>(Wp, bp, at2, Wt1, WtN, cb, cnt, N);
  k_hist<<<(E + 255) / 256, 256, 0, stream>>>(dst, cnt, E);
  k_scan1<<<nb, 256, 0, stream>>>(cnt, bsum, N);
  k_scan2<<<1, 1024, 0, stream>>>(bsum, boff, ptr, nb, N);
  k_scan3<<<nb, 256, 0, stream>>>(cnt, boff, ptr, cur, N);
  k_fill<<<(E + 255) / 256, 256, 0, stream>>>(dst, src, cur, pos, srcS, E);

  k_node_mfma<<<(N + 63) / 64, 256, 0, stream>>>(nft, WtN, at2, Wa1, nsAll, c2n,
                                                 a1n, N);

  k_edge_mfma<<<(E + 255) / 256, 256, 0, stream>>>(eft, Wt1, pos, eps, E);

  k_aggregate<<<(N * 64 + 255) / 256, 256, 0, stream>>>(eps, nsAll, a1n, c2n, cb,
                                                        ptr, srcS, at2, bp,
                                                        nft, (float*)d_out, N);
}